// Round 4
// baseline (337.283 us; speedup 1.0000x reference)
//
#include <hip/hip_runtime.h>
#include <math.h>

#define D_MODEL 1024
#define NHEAD 16
#define HD 64
#define SEQ 2048
#define BATCH 2
#define MTOT (BATCH * SEQ)  // 4096

typedef __attribute__((ext_vector_type(8))) short bf16x8;
typedef __attribute__((ext_vector_type(4))) float f32x4;

__device__ __forceinline__ unsigned short f2bf(float f) {
    unsigned int u = __float_as_uint(f);
    u += 0x7FFF + ((u >> 16) & 1);  // round-to-nearest-even
    return (unsigned short)(u >> 16);
}

// packed f32x2 -> bf16x2 via HW cvt (RNE, bit-identical to f2bf for normals)
__device__ __forceinline__ unsigned int pk2bf(float a, float b) {
    unsigned int r;
    asm("v_cvt_pk_bf16_f32 %0, %1, %2" : "=v"(r) : "v"(a), "v"(b));
    return r;
}

// async global->LDS, 16B per lane. lds must be the wave-uniform chunk base:
// HW writes lane's 16B to base + lane*16 (guide §5 caveat).
__device__ __forceinline__ void async16(unsigned short* lds, const unsigned short* g) {
    __builtin_amdgcn_global_load_lds(
        (const __attribute__((address_space(1))) unsigned int*)g,
        (__attribute__((address_space(3))) unsigned int*)lds, 16, 0, 0);
}

// raw barrier with compiler memory fence (no vmcnt drain, unlike __syncthreads)
__device__ __forceinline__ void BAR() {
    asm volatile("" ::: "memory");
    __builtin_amdgcn_s_barrier();
    asm volatile("" ::: "memory");
}

// ---------------------------------------------------------------------------
// Fused prep: blocks [0,4096) convert x fp32->bf16; blocks [4096,8192)
// transpose the 4 weights W[k][n] fp32 -> Wt[n][k] bf16.
// ---------------------------------------------------------------------------
__global__ __launch_bounds__(256) void prep(const float* __restrict__ x,
                                            unsigned short* __restrict__ xb,
                                            const float* __restrict__ W0,
                                            const float* __restrict__ W1,
                                            const float* __restrict__ W2,
                                            const float* __restrict__ W3,
                                            unsigned short* __restrict__ Wt) {
    const int bid = blockIdx.x;
    const int tid = threadIdx.x;
    if (bid < 4096) {
        const int i = (bid * 256 + tid) * 4;
        float4 v = *(const float4*)(x + i);
        uint2 pk;
        pk.x = pk2bf(v.x, v.y);
        pk.y = pk2bf(v.z, v.w);
        *(uint2*)(xb + i) = pk;
    } else {
        __shared__ float T[32][33];
        const int t = bid - 4096;
        const int z = t >> 10, rem = t & 1023;
        const int n0 = (rem & 31) * 32, k0 = (rem >> 5) * 32;
        const float* W = (z == 0) ? W0 : (z == 1) ? W1 : (z == 2) ? W2 : W3;
        unsigned short* out = Wt + (size_t)z * D_MODEL * D_MODEL;
        const int tx = tid & 31, ty = tid >> 5;
#pragma unroll
        for (int i = 0; i < 4; ++i)
            T[ty + 8 * i][tx] = W[(size_t)(k0 + ty + 8 * i) * D_MODEL + n0 + tx];
        __syncthreads();
#pragma unroll
        for (int i = 0; i < 4; ++i)
            out[(size_t)(n0 + ty + 8 * i) * D_MODEL + k0 + tx] = f2bf(T[tx][ty + 8 * i]);
    }
}

// ---------------------------------------------------------------------------
// Fused QKV GEMM: 256x256 tile, 8-phase schedule (T2+T3+T4+T5 per guide §5.5).
// M=4096 (tokens), N=3072 (Wq|Wk|Wv), K=1024. Grid 192 blocks x 512 thr
// (8 waves, 2M x 4N, per-wave 128x64 output). BK=64 per K-tile, staged as
// 4 half-tiles {A,B} x {K-half}; double-buffered 128 KB LDS; counted
// vmcnt(4) at phases 2/4 only (never drained in-loop); setprio around MFMA.
// LDS swizzle: chunk c of row r at slot r*4 + (c ^ ((r+(r>>2))&3)) ->
// 2-way (free) banks on ds_read_b128; implemented as pre-swizzled GLOBAL
// source + swizzled read (global_load_lds dest stays linear, rule #21).
// Epilogues: Q (x0.125*log2e) / K -> [B,H,N,64]; V -> V^T [B,H,64,N];
// LDS-staged, fully-coalesced uint4 stores.
// ---------------------------------------------------------------------------
__global__ __launch_bounds__(512, 2) void qkv_mfma(const unsigned short* __restrict__ A,
                                                   const unsigned short* __restrict__ Wt,
                                                   unsigned short* __restrict__ q,
                                                   unsigned short* __restrict__ k,
                                                   unsigned short* __restrict__ vt) {
    __shared__ unsigned short SM[65536];  // 128 KB: [dbuf][op][ks][1024 slots x 16B]
    const int tid = threadIdx.x;
    const int wave = tid >> 6, lane = tid & 63;
    const int quad = lane >> 4, l16 = lane & 15;
    const int wm = wave >> 2, wn = wave & 3;

    // XCD-chunked block swizzle (192 % 8 == 0 -> bijective simple form)
    const int bid = blockIdx.x;
    const int swz = (bid & 7) * 24 + (bid >> 3);
    const int by = swz / 12, bx = swz % 12;
    const int m0 = by * 256;
    const int z = bx >> 2, c0 = (bx & 3) * 256;  // weight id, col base within z
    const unsigned short* Bz = Wt + (size_t)z * D_MODEL * D_MODEL;

    // ---- staging descriptors: thread covers slots {tid, 512+tid} of each
    //      16KB half-tile region; source chunk pre-swizzled ----
    const unsigned short* aptr[2];
    const unsigned short* bptr[2];
    int ldsoff[2];  // ushort units
#pragma unroll
    for (int j = 0; j < 2; ++j) {
        const int s = j * 512 + tid;
        const int r = s >> 2;
        const int cg = (s & 3) ^ ((r + (r >> 2)) & 3);
        aptr[j] = A + (size_t)(m0 + r) * D_MODEL + cg * 8;
        bptr[j] = Bz + (size_t)(c0 + r) * D_MODEL + cg * 8;
        ldsoff[j] = (j * 512 + wave * 64) * 8;
    }

    // ---- fragment read offsets (swizzled; key matches staging) ----
    const int key = (l16 + (l16 >> 2)) & 3;
    const int chunk = quad ^ key;
    int aoff[8], boff[4];  // ushort units within [ks] region / [op] region
#pragma unroll
    for (int mt = 0; mt < 8; ++mt)
        aoff[mt] = ((wm * 128 + mt * 16 + l16) * 4 + chunk) * 8;
#pragma unroll
    for (int nt = 0; nt < 4; ++nt)
        boff[nt] = 16384 + ((wn * 64 + nt * 16 + l16) * 4 + chunk) * 8;

    f32x4 acc[8][4];
#pragma unroll
    for (int mt = 0; mt < 8; ++mt)
#pragma unroll
        for (int nt = 0; nt < 4; ++nt)
            acc[mt][nt] = (f32x4){0.f, 0.f, 0.f, 0.f};

    auto stage = [&](int d, int op, int ks, int T) {
        const int base = d * 32768 + op * 16384 + ks * 8192;
#pragma unroll
        for (int j = 0; j < 2; ++j)
            async16(SM + base + ldsoff[j],
                    (op ? bptr[j] : aptr[j]) + T * 64 + ks * 32);
    };
    auto dsA = [&](bf16x8* af, int mh, int d, int ks) {
        const int base = d * 32768 + ks * 8192;
#pragma unroll
        for (int i = 0; i < 4; ++i)
            af[i] = *(const bf16x8*)&SM[base + aoff[mh * 4 + i]];
    };
    auto dsB = [&](bf16x8* bf, int d, int ks) {
        const int base = d * 32768 + ks * 8192;
#pragma unroll
        for (int i = 0; i < 4; ++i)
            bf[i] = *(const bf16x8*)&SM[base + boff[i]];
    };
    auto mfma16 = [&](bf16x8* af, bf16x8* bf, int mh) {
        __builtin_amdgcn_s_setprio(1);
#pragma unroll
        for (int i = 0; i < 4; ++i)
#pragma unroll
            for (int nt = 0; nt < 4; ++nt)
                acc[mh * 4 + i][nt] = __builtin_amdgcn_mfma_f32_16x16x32_bf16(
                    af[i], bf[nt], acc[mh * 4 + i][nt], 0, 0, 0);
        __builtin_amdgcn_s_setprio(0);
    };

    // ---- prologue: stage tile 0 (A0,B0,A1,B1), retire A0+B0, sync ----
    stage(0, 0, 0, 0);
    stage(0, 1, 0, 0);
    stage(0, 0, 1, 0);
    stage(0, 1, 1, 0);
    asm volatile("s_waitcnt vmcnt(4)" ::: "memory");
    BAR();

    const int NT = D_MODEL / 64;  // 16
    for (int T = 0; T < NT; ++T) {
        const int d = T & 1, dn = d ^ 1;
        const bool nx = (T + 1 < NT);
        bf16x8 af[4], bf[4];
        // ph1: quadrant (mh=0, ks=0); issue A-half0(T+1)
        if (nx) stage(dn, 0, 0, T + 1);
        dsA(af, 0, d, 0);
        dsB(bf, d, 0);
        mfma16(af, bf, 0);
        BAR();
        // ph2: (mh=1, ks=0) reusing bf; issue B-half0(T+1); retire A1,B1(T)
        if (nx) stage(dn, 1, 0, T + 1);
        dsA(af, 1, d, 0);
        mfma16(af, bf, 1);
        if (nx) asm volatile("s_waitcnt vmcnt(4)" ::: "memory");
        else    asm volatile("s_waitcnt vmcnt(0)" ::: "memory");
        BAR();
        // ph3: (mh=0, ks=1); issue A-half1(T+1)
        if (nx) stage(dn, 0, 1, T + 1);
        dsA(af, 0, d, 1);
        dsB(bf, d, 1);
        mfma16(af, bf, 0);
        BAR();
        // ph4: (mh=1, ks=1); issue B-half1(T+1); retire A0,B0(T+1)
        if (nx) stage(dn, 1, 1, T + 1);
        dsA(af, 1, d, 1);
        mfma16(af, bf, 1);
        if (nx) asm volatile("s_waitcnt vmcnt(4)" ::: "memory");
        else    asm volatile("s_waitcnt vmcnt(0)" ::: "memory");
        BAR();
    }

    // ---- epilogues (LDS re-staged, coalesced 16B stores) ----
    __syncthreads();
    const int bb = m0 >> 11, tok0 = m0 & (SEQ - 1), h0 = c0 >> 6;  // 4 heads/block
    if (z < 2) {
        const float qsc = (z == 0) ? 0.18033688011112042f : 1.0f;  // 0.125*log2(e)
        unsigned short* dst = (z == 0) ? q : k;
#pragma unroll
        for (int pass = 0; pass < 2; ++pass) {
            if (pass) __syncthreads();
            if (wm == pass) {
#pragma unroll
                for (int mt = 0; mt < 8; ++mt)
#pragma unroll
                    for (int nt = 0; nt < 4; ++nt)
#pragma unroll
                        for (int reg = 0; reg < 4; ++reg) {
                            const int rr = mt * 16 + quad * 4 + reg;
                            const int cc = wn * 64 + nt * 16 + l16;
                            SM[rr * 264 + cc] = f2bf(acc[mt][nt][reg] * qsc);
                        }
            }
            __syncthreads();
#pragma unroll
            for (int it = 0; it < 8; ++it) {
                const int g = it * 512 + tid;
                const int r = g >> 5, gg = g & 31;
                uint4 val = *(const uint4*)&SM[r * 264 + gg * 8];
                *(uint4*)(dst + (((size_t)bb * NHEAD + h0 + (gg >> 3)) * SEQ +
                                 tok0 + pass * 128 + r) * HD + (gg & 7) * 8) = val;
            }
        }
    } else {
        // V^T: stage [d 0..255][tok 0..127] (pad 136), coalesced stores.
#pragma unroll
        for (int pass = 0; pass < 2; ++pass) {
            if (pass) __syncthreads();
            if (wm == pass) {
#pragma unroll
                for (int mt = 0; mt < 8; ++mt)
#pragma unroll
                    for (int nt = 0; nt < 4; ++nt) {
                        const int dd = wn * 64 + nt * 16 + l16;
                        const int m = mt * 16 + quad * 4;
                        uint2 w;
                        w.x = pk2bf(acc[mt][nt][0], acc[mt][nt][1]);
                        w.y = pk2bf(acc[mt][nt][2], acc[mt][nt][3]);
                        *(uint2*)&SM[dd * 136 + m] = w;
                    }
            }
            __syncthreads();
#pragma unroll
            for (int it = 0; it < 8; ++it) {
                const int g = it * 512 + tid;
                const int dd = g >> 4, tg = (g & 15) * 8;
                uint4 val = *(const uint4*)&SM[dd * 136 + tg];
                *(uint4*)(vt + (((size_t)bb * NHEAD + h0 + (dd >> 6)) * HD + (dd & 63)) * SEQ +
                          tok0 + pass * 128 + tg) = val;
            }
        }
    }
}

// ---------------------------------------------------------------------------
// bf16 MFMA GEMM (output projection only): 128x128 tile, BK=64, 4 waves,
// global_load_lds staging, fp32 row-major output.
// ---------------------------------------------------------------------------
__global__ __launch_bounds__(256) void gemm_out(const unsigned short* __restrict__ A,
                                                const unsigned short* __restrict__ Bw,
                                                float* __restrict__ outf) {
    __shared__ unsigned short SM[16384];  // As = SM[0:8192), Bs = SM[8192:16384)
    const int tid = threadIdx.x;
    const int m0 = blockIdx.y * 128, n0 = blockIdx.x * 128;
    const int wave = tid >> 6, lane = tid & 63;
    const int quad = lane >> 4, l16 = lane & 15;
    const int wm = wave & 1, wn = wave >> 1;

    f32x4 acc[4][4];
#pragma unroll
    for (int mt = 0; mt < 4; ++mt)
#pragma unroll
        for (int nt = 0; nt < 4; ++nt)
            acc[mt][nt] = (f32x4){0.f, 0.f, 0.f, 0.f};

    for (int k0 = 0; k0 < D_MODEL; k0 += 64) {
        __syncthreads();
#pragma unroll
        for (int i = 0; i < 4; ++i) {
            const int c = i * 256 + tid;
            const int r = c >> 3, cc = (c & 7) * 8;
            const int cbase = i * 256 + wave * 64;  // wave-uniform chunk base
            async16(SM + cbase * 8, A + (size_t)(m0 + r) * D_MODEL + k0 + cc);
            async16(SM + 8192 + cbase * 8, Bw + (size_t)(n0 + r) * D_MODEL + k0 + cc);
        }
        __syncthreads();
#pragma unroll
        for (int ks = 0; ks < 2; ++ks) {
            bf16x8 af[4], bfr[4];
#pragma unroll
            for (int mt = 0; mt < 4; ++mt)
                af[mt] = *(const bf16x8*)&SM[(wm * 64 + mt * 16 + l16) * 64 + ks * 32 + quad * 8];
#pragma unroll
            for (int nt = 0; nt < 4; ++nt)
                bfr[nt] = *(const bf16x8*)&SM[8192 + (wn * 64 + nt * 16 + l16) * 64 + ks * 32 + quad * 8];
#pragma unroll
            for (int mt = 0; mt < 4; ++mt)
#pragma unroll
                for (int nt = 0; nt < 4; ++nt)
                    acc[mt][nt] = __builtin_amdgcn_mfma_f32_16x16x32_bf16(
                        af[mt], bfr[nt], acc[mt][nt], 0, 0, 0);
        }
    }

#pragma unroll
    for (int mt = 0; mt < 4; ++mt)
#pragma unroll
        for (int nt = 0; nt < 4; ++nt)
#pragma unroll
            for (int reg = 0; reg < 4; ++reg) {
                const int m = m0 + wm * 64 + mt * 16 + quad * 4 + reg;
                const int n = n0 + wn * 64 + nt * 16 + l16;
                outf[(size_t)m * D_MODEL + n] = acc[mt][nt][reg];
            }
}

// ---------------------------------------------------------------------------
// MFMA flash attention (causal), 64-row PAIRED q-tiles + 8-way kt-SPLIT.
// Grid (NHEAD, 16, BATCH) = 512 blocks, 512 thr = 8 waves. Block y handles
// q-tiles {31-y, y}: 33 kt-iterations total, split kt ≡ wave (mod 8) ->
// ~4-5 serial iterations per wave. 2 blocks/CU x 8 waves = 4 waves/SIMD
// (2x the round-1 latency hiding; VGPR capped at 128 by launch_bounds).
// SAME 64-row tile as the proven 52µs version: full MFMA work per K/V load
// (round-2's 32-row split halved flops/load and regressed).
// Fixed-shift additive softmax -> order-free partial accumulation; no
// barriers in the kt loop. Cross-wave combine: 8->4->1 LDS tree (regions
// overlay the per-wave Ps scratch). Ps is XOR-swizzled unpadded [64][64].
// ---------------------------------------------------------------------------
__global__ __launch_bounds__(512, 4) void attn_mfma(const unsigned short* __restrict__ Q,
                                                    const unsigned short* __restrict__ K,
                                                    const unsigned short* __restrict__ VT,
                                                    unsigned short* __restrict__ ctx) {
    // Union LDS (70.7 KB):
    //   loop phase:    Ps = ushort[8][4096] (8 KB per wave) = bytes [0,65536)
    //   combine phase: R[i] = floats [i*4352, i*4352+4352), i=0..3 (64x68 pad)
    //                  Ls = floats [17408,17664) = 4x64 row-sum slots
    __shared__ float CMB[17664];
    const int tid = threadIdx.x;
    const int wave = tid >> 6, lane = tid & 63;
    const int quad = lane >> 4, l16 = lane & 15;
    const int h = blockIdx.x, b = blockIdx.z;
    const int y = blockIdx.y;  // 0..15
    const unsigned short* Qp = Q + ((size_t)b * NHEAD + h) * SEQ * HD;
    const unsigned short* Kp = K + ((size_t)b * NHEAD + h) * SEQ * HD;
    const unsigned short* Vp = VT + ((size_t)b * NHEAD + h) * HD * SEQ;
    unsigned short* Pw = (unsigned short*)CMB + wave * 4096;
    const int sw8 = l16 & 7;  // swizzle key (row & 7)

#pragma unroll 1
    for (int half = 0; half < 2; ++half) {
        const int p = half ? y : (31 - y);  // heavy tile first
        const int row0 = p * 64;
        if (half) __syncthreads();  // previous combine's LDS reads done

        bf16x8 bQ[4][2];  // Q as B-operand: [q-frag][ks]
#pragma unroll
        for (int f = 0; f < 4; ++f)
#pragma unroll
            for (int ks = 0; ks < 2; ++ks)
                bQ[f][ks] = *(const bf16x8*)(Qp +
                    (size_t)(row0 + f * 16 + l16) * HD + ks * 32 + quad * 8);

        f32x4 o[4][4];    // O^T accumulators: [d-tile][q-frag]
        float ps[4] = {0.f, 0.f, 0.f, 0.f};
#pragma unroll
        for (int nt = 0; nt < 4; ++nt)
#pragma unroll
            for (int f = 0; f < 4; ++f)
                o[nt][f] = (f32x4){0.f, 0.f, 0.f, 0.f};

        for (int kt = wave; kt <= p; kt += 8) {
            // ---- K fragments (direct global; no loop barriers) ----
            bf16x8 aK[4][2];
#pragma unroll
            for (int mt = 0; mt < 4; ++mt)
#pragma unroll
                for (int ks = 0; ks < 2; ++ks)
                    aK[mt][ks] = *(const bf16x8*)(Kp +
                        (size_t)(kt * 64 + mt * 16 + l16) * HD + ks * 32 + quad * 8);

            // ---- S^T = K Q^T ----
            f32x4 sT[4][4];
            __builtin_amdgcn_s_setprio(1);
#pragma unroll
            for (int mt = 0; mt < 4; ++mt)
#pragma unroll
                for (int f = 0; f < 4; ++f) {
                    sT[mt][f] = __builtin_amdgcn_mfma_f32_16x16x32_bf16(
                        aK[mt][0], bQ[f][0], (f32x4){0.f, 0.f, 0.f, 0.f}, 0, 0, 0);
                    sT[mt][f] = __builtin_amdgcn_mfma_f32_16x16x32_bf16(
                        aK[mt][1], bQ[f][1], sT[mt][f], 0, 0, 0);
                }
            __builtin_amdgcn_s_setprio(0);

            // ---- exp2 + causal mask (diag tile only) + swizzled P write ----
            const bool diag = (kt == p);
#pragma unroll
            for (int mt = 0; mt < 4; ++mt)
#pragma unroll
                for (int f = 0; f < 4; ++f) {
                    float pv[4];
#pragma unroll
                    for (int reg = 0; reg < 4; ++reg)
                        pv[reg] = exp2f(sT[mt][f][reg]);
                    if (diag) {
                        const int kb = kt * 64 + mt * 16 + quad * 4;
                        const int qg = row0 + f * 16 + l16;
#pragma unroll
                        for (int reg = 0; reg < 4; ++reg)
                            pv[reg] = (kb + reg > qg) ? 0.f : pv[reg];
                    }
                    ps[f] += (pv[0] + pv[1]) + (pv[2] + pv[3]);
                    uint2 w;
                    w.x = pk2bf(pv[0], pv[1]);
                    w.y = pk2bf(pv[2], pv[3]);
                    const int gph = ((mt * 2 + (quad >> 1)) ^ sw8);
                    *(uint2*)&Pw[(f * 16 + l16) * 64 + gph * 8 + (quad & 1) * 4] = w;
                }

            // ---- P back in B-layout (wave-private; same-wave DS order) ----
            bf16x8 bP[4][2];
#pragma unroll
            for (int f = 0; f < 4; ++f)
#pragma unroll
                for (int ks = 0; ks < 2; ++ks)
                    bP[f][ks] = *(const bf16x8*)&Pw[(f * 16 + l16) * 64 +
                                                    ((ks * 4 + quad) ^ sw8) * 8];

            // ---- V fragments (after aK dies: keeps peak VGPR in bound) ----
            bf16x8 aV[4][2];
#pragma unroll
            for (int nt = 0; nt < 4; ++nt)
#pragma unroll
                for (int ks = 0; ks < 2; ++ks)
                    aV[nt][ks] = *(const bf16x8*)(Vp +
                        (size_t)(nt * 16 + l16) * SEQ + kt * 64 + ks * 32 + quad * 8);

            // ---- O^T += V^T P^T ----
            __builtin_amdgcn_s_setprio(1);
#pragma unroll
            for (int nt = 0; nt < 4; ++nt)
#pragma unroll
                for (int f = 0; f < 4; ++f) {
                    o[nt][f] = __builtin_amdgcn_mfma_f32_16x16x32_bf16(
                        aV[nt][0], bP[f][0], o[nt][f], 0, 0, 0);
                    o[nt][f] = __builtin_amdgcn_mfma_f32_16x16x32_bf16(
                        aV[nt][1], bP[f][1], o[nt][f], 0, 0, 0);
                }
            __builtin_amdgcn_s_setprio(0);
        }

        // ---- reduce ps across quads (q-row lives in l16; partials in quads) --
#pragma unroll
        for (int f = 0; f < 4; ++f) {
            ps[f] += __shfl_xor(ps[f], 16);
            ps[f] += __shfl_xor(ps[f], 32);
        }

        // ---- cross-wave combine tree: {4..7}->{0..3}, {1,2,3}->0 ----
        __syncthreads();  // all waves done with Pw (regions overlay it)
        if (wave >= 4) {
            float* Rg = CMB + (wave - 4) * 4352;
#pragma unroll
            for (int nt = 0; nt < 4; ++nt)
#pragma unroll
                for (int f = 0; f < 4; ++f)
                    *(f32x4*)&Rg[(f * 16 + l16) * 68 + nt * 16 + quad * 4] = o[nt][f];
            if (quad == 0)
#pragma unroll
                for (int f = 0; f < 4; ++f)
                    CMB[17408 + (wave - 4) * 64 + f * 16 + l16] = ps[f];
        }
        __syncthreads();
        if (wave < 4) {
            float* Rg = CMB + wave * 4352;
#pragma unroll
            for (int nt = 0; nt < 4; ++nt)
#pragma unroll
                for (int f = 0; f < 4; ++f)
                    o[nt][f] += *(const f32x4*)&Rg[(f * 16 + l16) * 68 + nt * 16 + quad * 4];
#pragma unroll
            for (int f = 0; f < 4; ++f)
                ps[f] += CMB[17408 + wave * 64 + f * 16 + l16];
        }
        __syncthreads();
        if (wave >= 1 && wave < 4) {
            float* Rg = CMB + (wave - 1) * 4352;
#pragma unroll
            for (int nt = 0; nt < 4; ++nt)
#pragma unroll
                for (int f = 0; f < 4; ++f)
                    *(f32x4*)&Rg[(f * 16 + l16) * 68 + nt * 16 + quad * 4] = o[nt][f];
            if (quad == 0)
#pragma unroll
                for (int f = 0; f < 4; ++f)
                    CMB[17408 + (wave - 1) * 64 + f * 16 + l16] = ps[f];
        }
        __syncthreads();
        if (wave == 0) {
#pragma unroll
            for (int r = 0; r < 3; ++r) {
                float* Rg = CMB + r * 4352;
#pragma unroll
                for (int nt = 0; nt < 4; ++nt)
#pragma unroll
                    for (int f = 0; f < 4; ++f)
                        o[nt][f] += *(const f32x4*)&Rg[(f * 16 + l16) * 68 + nt * 16 + quad * 4];
#pragma unroll
                for (int f = 0; f < 4; ++f)
                    ps[f] += CMB[17408 + r * 64 + f * 16 + l16];
            }
            float inv[4];
#pragma unroll
            for (int f = 0; f < 4; ++f)
                inv[f] = 1.f / ps[f];
#pragma unroll
            for (int nt = 0; nt < 4; ++nt)
#pragma unroll
                for (int f = 0; f < 4; ++f) {
                    const int tok = row0 + f * 16 + l16;
                    const int col = h * HD + nt * 16 + quad * 4;
                    uint2 w;
                    w.x = pk2bf(o[nt][f][0] * inv[f], o[nt][f][1] * inv[f]);
                    w.y = pk2bf(o[nt][f][2] * inv[f], o[nt][f][3] * inv[f]);
                    *(uint2*)(ctx + ((size_t)b * SEQ + tok) * D_MODEL + col) = w;
                }
        }
    }
}

extern "C" void kernel_launch(void* const* d_in, const int* in_sizes, int n_in,
                              void* d_out, int out_size, void* d_ws, size_t ws_size,
                              hipStream_t stream) {
    const float* x  = (const float*)d_in[0];
    const float* Wq = (const float*)d_in[1];
    const float* Wk = (const float*)d_in[2];
    const float* Wv = (const float*)d_in[3];
    const float* Wo = (const float*)d_in[4];
    float* out = (float*)d_out;

    unsigned short* ws = (unsigned short*)d_ws;
    const size_t T = (size_t)MTOT * D_MODEL;  // 4,194,304 elements
    unsigned short* xb  = ws;                 // [4096,1024] bf16
    unsigned short* Wt  = ws + T;             // 4 x [1024,1024] bf16 (W^T)
    unsigned short* q   = ws + 2 * T;         // [B,H,N,64]  (pre-scaled)
    unsigned short* k   = ws + 3 * T;         // [B,H,N,64]
    unsigned short* vt  = ws + 4 * T;         // [B,H,64,N]
    unsigned short* ctx = ws + 5 * T;         // [4096,1024]

    prep<<<dim3(8192), dim3(256), 0, stream>>>(x, xb, Wq, Wk, Wv, Wo, Wt);

    qkv_mfma<<<dim3(192), dim3(512), 0, stream>>>(xb, Wt, q, k, vt);

    attn_mfma<<<dim3(NHEAD, 16, BATCH), dim3(512), 0, stream>>>(q, k, vt, ctx);

    gemm_out<<<dim3(8, 32), dim3(256), 0, stream>>>(ctx, Wt + 3 * (size_t)D_MODEL * D_MODEL, out);
}

// Round 5
// 217.352 us; speedup vs baseline: 1.5518x; 1.5518x over previous
//
#include <hip/hip_runtime.h>
#include <math.h>

#define D_MODEL 1024
#define NHEAD 16
#define HD 64
#define SEQ 2048
#define BATCH 2
#define MTOT (BATCH * SEQ)  // 4096

typedef __attribute__((ext_vector_type(8))) short bf16x8;
typedef __attribute__((ext_vector_type(4))) float f32x4;

__device__ __forceinline__ unsigned short f2bf(float f) {
    unsigned int u = __float_as_uint(f);
    u += 0x7FFF + ((u >> 16) & 1);  // round-to-nearest-even
    return (unsigned short)(u >> 16);
}

// packed f32x2 -> bf16x2 via HW cvt (RNE, bit-identical to f2bf for normals)
__device__ __forceinline__ unsigned int pk2bf(float a, float b) {
    unsigned int r;
    asm("v_cvt_pk_bf16_f32 %0, %1, %2" : "=v"(r) : "v"(a), "v"(b));
    return r;
}

// async global->LDS, 16B per lane. lds must be the wave-uniform chunk base:
// HW writes lane's 16B to base + lane*16 (guide §5 caveat).
__device__ __forceinline__ void async16(unsigned short* lds, const unsigned short* g) {
    __builtin_amdgcn_global_load_lds(
        (const __attribute__((address_space(1))) unsigned int*)g,
        (__attribute__((address_space(3))) unsigned int*)lds, 16, 0, 0);
}

// raw barrier with compiler memory fence (no vmcnt drain, unlike __syncthreads)
__device__ __forceinline__ void BAR() {
    asm volatile("" ::: "memory");
    __builtin_amdgcn_s_barrier();
    asm volatile("" ::: "memory");
}

// ---------------------------------------------------------------------------
// Fused prep: blocks [0,4096) convert x fp32->bf16; blocks [4096,8192)
// transpose the 4 weights W[k][n] fp32 -> Wt[n][k] bf16.
// ---------------------------------------------------------------------------
__global__ __launch_bounds__(256) void prep(const float* __restrict__ x,
                                            unsigned short* __restrict__ xb,
                                            const float* __restrict__ W0,
                                            const float* __restrict__ W1,
                                            const float* __restrict__ W2,
                                            const float* __restrict__ W3,
                                            unsigned short* __restrict__ Wt) {
    const int bid = blockIdx.x;
    const int tid = threadIdx.x;
    if (bid < 4096) {
        const int i = (bid * 256 + tid) * 4;
        float4 v = *(const float4*)(x + i);
        uint2 pk;
        pk.x = pk2bf(v.x, v.y);
        pk.y = pk2bf(v.z, v.w);
        *(uint2*)(xb + i) = pk;
    } else {
        __shared__ float T[32][33];
        const int t = bid - 4096;
        const int z = t >> 10, rem = t & 1023;
        const int n0 = (rem & 31) * 32, k0 = (rem >> 5) * 32;
        const float* W = (z == 0) ? W0 : (z == 1) ? W1 : (z == 2) ? W2 : W3;
        unsigned short* out = Wt + (size_t)z * D_MODEL * D_MODEL;
        const int tx = tid & 31, ty = tid >> 5;
#pragma unroll
        for (int i = 0; i < 4; ++i)
            T[ty + 8 * i][tx] = W[(size_t)(k0 + ty + 8 * i) * D_MODEL + n0 + tx];
        __syncthreads();
#pragma unroll
        for (int i = 0; i < 4; ++i)
            out[(size_t)(n0 + ty + 8 * i) * D_MODEL + k0 + tx] = f2bf(T[tx][ty + 8 * i]);
    }
}

// ---------------------------------------------------------------------------
// Fused QKV GEMM: 256x256 tile, 8-phase schedule (T2+T3+T4+T5 per guide §5.5).
// M=4096 (tokens), N=3072 (Wq|Wk|Wv), K=1024. Grid 192 blocks x 512 thr
// (8 waves, 2M x 4N, per-wave 128x64 output). BK=64 per K-tile, staged as
// 4 half-tiles {A,B} x {K-half}; double-buffered 128 KB LDS; counted
// vmcnt(4) at phases 2/4 only (never drained in-loop); setprio around MFMA.
// LDS swizzle: chunk c of row r at slot r*4 + (c ^ ((r+(r>>2))&3)) ->
// 2-way (free) banks on ds_read_b128; implemented as pre-swizzled GLOBAL
// source + swizzled read (global_load_lds dest stays linear, rule #21).
// Epilogues: Q (x0.125*log2e) / K -> [B,H,N,64]; V -> V^T [B,H,64,N];
// LDS-staged, fully-coalesced uint4 stores.
// ---------------------------------------------------------------------------
__global__ __launch_bounds__(512, 2) void qkv_mfma(const unsigned short* __restrict__ A,
                                                   const unsigned short* __restrict__ Wt,
                                                   unsigned short* __restrict__ q,
                                                   unsigned short* __restrict__ k,
                                                   unsigned short* __restrict__ vt) {
    __shared__ unsigned short SM[65536];  // 128 KB: [dbuf][op][ks][1024 slots x 16B]
    const int tid = threadIdx.x;
    const int wave = tid >> 6, lane = tid & 63;
    const int quad = lane >> 4, l16 = lane & 15;
    const int wm = wave >> 2, wn = wave & 3;

    // XCD-chunked block swizzle (192 % 8 == 0 -> bijective simple form)
    const int bid = blockIdx.x;
    const int swz = (bid & 7) * 24 + (bid >> 3);
    const int by = swz / 12, bx = swz % 12;
    const int m0 = by * 256;
    const int z = bx >> 2, c0 = (bx & 3) * 256;  // weight id, col base within z
    const unsigned short* Bz = Wt + (size_t)z * D_MODEL * D_MODEL;

    // ---- staging descriptors: thread covers slots {tid, 512+tid} of each
    //      16KB half-tile region; source chunk pre-swizzled ----
    const unsigned short* aptr[2];
    const unsigned short* bptr[2];
    int ldsoff[2];  // ushort units
#pragma unroll
    for (int j = 0; j < 2; ++j) {
        const int s = j * 512 + tid;
        const int r = s >> 2;
        const int cg = (s & 3) ^ ((r + (r >> 2)) & 3);
        aptr[j] = A + (size_t)(m0 + r) * D_MODEL + cg * 8;
        bptr[j] = Bz + (size_t)(c0 + r) * D_MODEL + cg * 8;
        ldsoff[j] = (j * 512 + wave * 64) * 8;
    }

    // ---- fragment read offsets (swizzled; key matches staging) ----
    const int key = (l16 + (l16 >> 2)) & 3;
    const int chunk = quad ^ key;
    int aoff[8], boff[4];  // ushort units within [ks] region / [op] region
#pragma unroll
    for (int mt = 0; mt < 8; ++mt)
        aoff[mt] = ((wm * 128 + mt * 16 + l16) * 4 + chunk) * 8;
#pragma unroll
    for (int nt = 0; nt < 4; ++nt)
        boff[nt] = 16384 + ((wn * 64 + nt * 16 + l16) * 4 + chunk) * 8;

    f32x4 acc[8][4];
#pragma unroll
    for (int mt = 0; mt < 8; ++mt)
#pragma unroll
        for (int nt = 0; nt < 4; ++nt)
            acc[mt][nt] = (f32x4){0.f, 0.f, 0.f, 0.f};

    auto stage = [&](int d, int op, int ks, int T) {
        const int base = d * 32768 + op * 16384 + ks * 8192;
#pragma unroll
        for (int j = 0; j < 2; ++j)
            async16(SM + base + ldsoff[j],
                    (op ? bptr[j] : aptr[j]) + T * 64 + ks * 32);
    };
    auto dsA = [&](bf16x8* af, int mh, int d, int ks) {
        const int base = d * 32768 + ks * 8192;
#pragma unroll
        for (int i = 0; i < 4; ++i)
            af[i] = *(const bf16x8*)&SM[base + aoff[mh * 4 + i]];
    };
    auto dsB = [&](bf16x8* bf, int d, int ks) {
        const int base = d * 32768 + ks * 8192;
#pragma unroll
        for (int i = 0; i < 4; ++i)
            bf[i] = *(const bf16x8*)&SM[base + boff[i]];
    };
    auto mfma16 = [&](bf16x8* af, bf16x8* bf, int mh) {
        __builtin_amdgcn_s_setprio(1);
#pragma unroll
        for (int i = 0; i < 4; ++i)
#pragma unroll
            for (int nt = 0; nt < 4; ++nt)
                acc[mh * 4 + i][nt] = __builtin_amdgcn_mfma_f32_16x16x32_bf16(
                    af[i], bf[nt], acc[mh * 4 + i][nt], 0, 0, 0);
        __builtin_amdgcn_s_setprio(0);
    };

    // ---- prologue: stage tile 0 (A0,B0,A1,B1), retire A0+B0, sync ----
    stage(0, 0, 0, 0);
    stage(0, 1, 0, 0);
    stage(0, 0, 1, 0);
    stage(0, 1, 1, 0);
    asm volatile("s_waitcnt vmcnt(4)" ::: "memory");
    BAR();

    const int NT = D_MODEL / 64;  // 16
    for (int T = 0; T < NT; ++T) {
        const int d = T & 1, dn = d ^ 1;
        const bool nx = (T + 1 < NT);
        bf16x8 af[4], bf[4];
        // ph1: quadrant (mh=0, ks=0); issue A-half0(T+1)
        if (nx) stage(dn, 0, 0, T + 1);
        dsA(af, 0, d, 0);
        dsB(bf, d, 0);
        mfma16(af, bf, 0);
        BAR();
        // ph2: (mh=1, ks=0) reusing bf; issue B-half0(T+1); retire A1,B1(T)
        if (nx) stage(dn, 1, 0, T + 1);
        dsA(af, 1, d, 0);
        mfma16(af, bf, 1);
        if (nx) asm volatile("s_waitcnt vmcnt(4)" ::: "memory");
        else    asm volatile("s_waitcnt vmcnt(0)" ::: "memory");
        BAR();
        // ph3: (mh=0, ks=1); issue A-half1(T+1)
        if (nx) stage(dn, 0, 1, T + 1);
        dsA(af, 0, d, 1);
        dsB(bf, d, 1);
        mfma16(af, bf, 0);
        BAR();
        // ph4: (mh=1, ks=1); issue B-half1(T+1); retire A0,B0(T+1)
        if (nx) stage(dn, 1, 1, T + 1);
        dsA(af, 1, d, 1);
        mfma16(af, bf, 1);
        if (nx) asm volatile("s_waitcnt vmcnt(4)" ::: "memory");
        else    asm volatile("s_waitcnt vmcnt(0)" ::: "memory");
        BAR();
    }

    // ---- epilogues (LDS re-staged, coalesced 16B stores) ----
    __syncthreads();
    const int bb = m0 >> 11, tok0 = m0 & (SEQ - 1), h0 = c0 >> 6;  // 4 heads/block
    if (z < 2) {
        const float qsc = (z == 0) ? 0.18033688011112042f : 1.0f;  // 0.125*log2(e)
        unsigned short* dst = (z == 0) ? q : k;
#pragma unroll
        for (int pass = 0; pass < 2; ++pass) {
            if (pass) __syncthreads();
            if (wm == pass) {
#pragma unroll
                for (int mt = 0; mt < 8; ++mt)
#pragma unroll
                    for (int nt = 0; nt < 4; ++nt)
#pragma unroll
                        for (int reg = 0; reg < 4; ++reg) {
                            const int rr = mt * 16 + quad * 4 + reg;
                            const int cc = wn * 64 + nt * 16 + l16;
                            SM[rr * 264 + cc] = f2bf(acc[mt][nt][reg] * qsc);
                        }
            }
            __syncthreads();
#pragma unroll
            for (int it = 0; it < 8; ++it) {
                const int g = it * 512 + tid;
                const int r = g >> 5, gg = g & 31;
                uint4 val = *(const uint4*)&SM[r * 264 + gg * 8];
                *(uint4*)(dst + (((size_t)bb * NHEAD + h0 + (gg >> 3)) * SEQ +
                                 tok0 + pass * 128 + r) * HD + (gg & 7) * 8) = val;
            }
        }
    } else {
        // V^T: stage [d 0..255][tok 0..127] (pad 136), coalesced stores.
#pragma unroll
        for (int pass = 0; pass < 2; ++pass) {
            if (pass) __syncthreads();
            if (wm == pass) {
#pragma unroll
                for (int mt = 0; mt < 8; ++mt)
#pragma unroll
                    for (int nt = 0; nt < 4; ++nt) {
                        const int dd = wn * 64 + nt * 16 + l16;
                        const int m = mt * 16 + quad * 4;
                        uint2 w;
                        w.x = pk2bf(acc[mt][nt][0], acc[mt][nt][1]);
                        w.y = pk2bf(acc[mt][nt][2], acc[mt][nt][3]);
                        *(uint2*)&SM[dd * 136 + m] = w;
                    }
            }
            __syncthreads();
#pragma unroll
            for (int it = 0; it < 8; ++it) {
                const int g = it * 512 + tid;
                const int dd = g >> 4, tg = (g & 15) * 8;
                uint4 val = *(const uint4*)&SM[dd * 136 + tg];
                *(uint4*)(vt + (((size_t)bb * NHEAD + h0 + (dd >> 6)) * HD + (dd & 63)) * SEQ +
                          tok0 + pass * 128 + tg) = val;
            }
        }
    }
}

// ---------------------------------------------------------------------------
// bf16 MFMA GEMM (output projection only): 128x128 tile, BK=64, 4 waves,
// global_load_lds staging, fp32 row-major output.
// ---------------------------------------------------------------------------
__global__ __launch_bounds__(256) void gemm_out(const unsigned short* __restrict__ A,
                                                const unsigned short* __restrict__ Bw,
                                                float* __restrict__ outf) {
    __shared__ unsigned short SM[16384];  // As = SM[0:8192), Bs = SM[8192:16384)
    const int tid = threadIdx.x;
    const int m0 = blockIdx.y * 128, n0 = blockIdx.x * 128;
    const int wave = tid >> 6, lane = tid & 63;
    const int quad = lane >> 4, l16 = lane & 15;
    const int wm = wave & 1, wn = wave >> 1;

    f32x4 acc[4][4];
#pragma unroll
    for (int mt = 0; mt < 4; ++mt)
#pragma unroll
        for (int nt = 0; nt < 4; ++nt)
            acc[mt][nt] = (f32x4){0.f, 0.f, 0.f, 0.f};

    for (int k0 = 0; k0 < D_MODEL; k0 += 64) {
        __syncthreads();
#pragma unroll
        for (int i = 0; i < 4; ++i) {
            const int c = i * 256 + tid;
            const int r = c >> 3, cc = (c & 7) * 8;
            const int cbase = i * 256 + wave * 64;  // wave-uniform chunk base
            async16(SM + cbase * 8, A + (size_t)(m0 + r) * D_MODEL + k0 + cc);
            async16(SM + 8192 + cbase * 8, Bw + (size_t)(n0 + r) * D_MODEL + k0 + cc);
        }
        __syncthreads();
#pragma unroll
        for (int ks = 0; ks < 2; ++ks) {
            bf16x8 af[4], bfr[4];
#pragma unroll
            for (int mt = 0; mt < 4; ++mt)
                af[mt] = *(const bf16x8*)&SM[(wm * 64 + mt * 16 + l16) * 64 + ks * 32 + quad * 8];
#pragma unroll
            for (int nt = 0; nt < 4; ++nt)
                bfr[nt] = *(const bf16x8*)&SM[8192 + (wn * 64 + nt * 16 + l16) * 64 + ks * 32 + quad * 8];
#pragma unroll
            for (int mt = 0; mt < 4; ++mt)
#pragma unroll
                for (int nt = 0; nt < 4; ++nt)
                    acc[mt][nt] = __builtin_amdgcn_mfma_f32_16x16x32_bf16(
                        af[mt], bfr[nt], acc[mt][nt], 0, 0, 0);
        }
    }

#pragma unroll
    for (int mt = 0; mt < 4; ++mt)
#pragma unroll
        for (int nt = 0; nt < 4; ++nt)
#pragma unroll
            for (int reg = 0; reg < 4; ++reg) {
                const int m = m0 + wm * 64 + mt * 16 + quad * 4 + reg;
                const int n = n0 + wn * 64 + nt * 16 + l16;
                outf[(size_t)m * D_MODEL + n] = acc[mt][nt][reg];
            }
}

// ---------------------------------------------------------------------------
// MFMA flash attention (causal), PAIRED 64-row q-tiles + 4-way kt-SPLIT,
// K-PREFETCH pipelined (unroll-2, named Ka/Kb buffers: static indexing).
// Grid (NHEAD, 16, BATCH) = 512 blocks, 256 thr = 4 waves (round-1 proven
// structure; launch_bounds(256,2) -> 256 unified VGPR+AGPR budget, NO
// launch_bounds(...,4): on gfx950's unified RF that halves the budget to
// 128 and spills catastrophically — rounds 2/3 post-mortem).
// Pipeline per iteration: QK^T(cur) -> issue K(next) + V(cur) global loads
// -> softmax+pack+LDS round trip (hides both load latencies) -> PV(cur).
// This removes the top-of-iteration vmcnt stall that capped round 1.
// Fixed-shift additive softmax -> order-free; no barriers in the kt loop.
// Cross-wave combine: 2-round LDS tree. Ps XOR-swizzled unpadded [64][64].
// exp2 via __builtin_amdgcn_exp2f (guaranteed single v_exp_f32).
// ---------------------------------------------------------------------------
#define ATTN_ITER(CUR, NXT, KT, KTN)                                           \
  do {                                                                         \
    const int kt_ = (KT);                                                      \
    const int ktn_ = (KTN);                                                    \
    f32x4 sT[4][4];                                                            \
    __builtin_amdgcn_s_setprio(1);                                             \
    _Pragma("unroll") for (int mt = 0; mt < 4; ++mt)                           \
        _Pragma("unroll") for (int f = 0; f < 4; ++f) {                        \
      sT[mt][f] = __builtin_amdgcn_mfma_f32_16x16x32_bf16(                     \
          CUR[mt][0], bQ[f][0], (f32x4){0.f, 0.f, 0.f, 0.f}, 0, 0, 0);         \
      sT[mt][f] = __builtin_amdgcn_mfma_f32_16x16x32_bf16(                     \
          CUR[mt][1], bQ[f][1], sT[mt][f], 0, 0, 0);                           \
    }                                                                          \
    __builtin_amdgcn_s_setprio(0);                                             \
    if (ktn_ <= p) { /* prefetch next K tile (wave-uniform branch) */          \
      _Pragma("unroll") for (int mt = 0; mt < 4; ++mt)                         \
          _Pragma("unroll") for (int ks = 0; ks < 2; ++ks)                     \
        NXT[mt][ks] = *(const bf16x8*)(Kp +                                    \
            (size_t)(ktn_ * 64 + mt * 16 + l16) * HD + ks * 32 + quad * 8);    \
    }                                                                          \
    _Pragma("unroll") for (int nt = 0; nt < 4; ++nt) /* V(cur), hides under */ \
        _Pragma("unroll") for (int ks = 0; ks < 2; ++ks) /* softmax+LDS */     \
      aV[nt][ks] = *(const bf16x8*)(Vp +                                       \
          (size_t)(nt * 16 + l16) * SEQ + kt_ * 64 + ks * 32 + quad * 8);      \
    const bool diag = (kt_ == p);                                              \
    _Pragma("unroll") for (int mt = 0; mt < 4; ++mt)                           \
        _Pragma("unroll") for (int f = 0; f < 4; ++f) {                        \
      float pv[4];                                                             \
      _Pragma("unroll") for (int reg = 0; reg < 4; ++reg)                      \
          pv[reg] = __builtin_amdgcn_exp2f(sT[mt][f][reg]);                    \
      if (diag) {                                                              \
        const int kb = kt_ * 64 + mt * 16 + quad * 4;                          \
        const int qg = row0 + f * 16 + l16;                                    \
        _Pragma("unroll") for (int reg = 0; reg < 4; ++reg)                    \
            pv[reg] = (kb + reg > qg) ? 0.f : pv[reg];                         \
      }                                                                        \
      ps[f] += (pv[0] + pv[1]) + (pv[2] + pv[3]);                              \
      uint2 w;                                                                 \
      w.x = pk2bf(pv[0], pv[1]);                                               \
      w.y = pk2bf(pv[2], pv[3]);                                               \
      const int gph = ((mt * 2 + (quad >> 1)) ^ sw8);                          \
      *(uint2*)&Pw[(f * 16 + l16) * 64 + gph * 8 + (quad & 1) * 4] = w;        \
    }                                                                          \
    bf16x8 bP[4][2];                                                           \
    _Pragma("unroll") for (int f = 0; f < 4; ++f)                              \
        _Pragma("unroll") for (int ks = 0; ks < 2; ++ks)                       \
      bP[f][ks] = *(const bf16x8*)&Pw[(f * 16 + l16) * 64 +                    \
                                      ((ks * 4 + quad) ^ sw8) * 8];            \
    __builtin_amdgcn_s_setprio(1);                                             \
    _Pragma("unroll") for (int nt = 0; nt < 4; ++nt)                           \
        _Pragma("unroll") for (int f = 0; f < 4; ++f) {                        \
      o[nt][f] = __builtin_amdgcn_mfma_f32_16x16x32_bf16(                      \
          aV[nt][0], bP[f][0], o[nt][f], 0, 0, 0);                             \
      o[nt][f] = __builtin_amdgcn_mfma_f32_16x16x32_bf16(                      \
          aV[nt][1], bP[f][1], o[nt][f], 0, 0, 0);                             \
    }                                                                          \
    __builtin_amdgcn_s_setprio(0);                                             \
  } while (0)

__global__ __launch_bounds__(256, 2) void attn_mfma(const unsigned short* __restrict__ Q,
                                                    const unsigned short* __restrict__ K,
                                                    const unsigned short* __restrict__ VT,
                                                    unsigned short* __restrict__ ctx) {
    // Union LDS (35.3 KB):
    //   loop phase:    Ps = ushort[4][4096] (8 KB per wave), floats [0,8192)
    //   combine phase: R0 = floats [0,4352)  = 64x68 padded O partial
    //                  R1 = floats [4352,8704)
    //                  Ls = floats [8704,8832) = 2x64 row-sum partials
    __shared__ float CMB[8832];
    const int tid = threadIdx.x;
    const int wave = tid >> 6, lane = tid & 63;
    const int quad = lane >> 4, l16 = lane & 15;
    const int h = blockIdx.x, b = blockIdx.z;
    const int y = blockIdx.y;
    const unsigned short* Qp = Q + ((size_t)b * NHEAD + h) * SEQ * HD;
    const unsigned short* Kp = K + ((size_t)b * NHEAD + h) * SEQ * HD;
    const unsigned short* Vp = VT + ((size_t)b * NHEAD + h) * HD * SEQ;
    unsigned short* Pw = (unsigned short*)CMB + wave * 4096;
    const int sw8 = l16 & 7;  // swizzle key (row & 7)

#pragma unroll 1
    for (int half = 0; half < 2; ++half) {
        const int p = half ? y : (31 - y);  // heavy tile first
        const int row0 = p * 64;
        if (half) __syncthreads();  // previous combine's LDS reads done

        bf16x8 bQ[4][2];  // Q as B-operand: [q-frag][ks]
#pragma unroll
        for (int f = 0; f < 4; ++f)
#pragma unroll
            for (int ks = 0; ks < 2; ++ks)
                bQ[f][ks] = *(const bf16x8*)(Qp +
                    (size_t)(row0 + f * 16 + l16) * HD + ks * 32 + quad * 8);

        f32x4 o[4][4];    // O^T accumulators: [d-tile][q-frag]
        float ps[4] = {0.f, 0.f, 0.f, 0.f};
#pragma unroll
        for (int nt = 0; nt < 4; ++nt)
#pragma unroll
            for (int f = 0; f < 4; ++f)
                o[nt][f] = (f32x4){0.f, 0.f, 0.f, 0.f};

        bf16x8 Ka[4][2], Kb[4][2], aV[4][2];
        if (wave <= p) {  // prologue: first K tile
#pragma unroll
            for (int mt = 0; mt < 4; ++mt)
#pragma unroll
                for (int ks = 0; ks < 2; ++ks)
                    Ka[mt][ks] = *(const bf16x8*)(Kp +
                        (size_t)(wave * 64 + mt * 16 + l16) * HD + ks * 32 + quad * 8);
        }

#pragma unroll 1
        for (int kt = wave; kt <= p; kt += 8) {
            ATTN_ITER(Ka, Kb, kt, kt + 4);
            if (kt + 4 <= p) ATTN_ITER(Kb, Ka, kt + 4, kt + 8);
        }

        // ---- reduce ps across quads (q-row lives in l16; partials in quads) --
#pragma unroll
        for (int f = 0; f < 4; ++f) {
            ps[f] += __shfl_xor(ps[f], 16);
            ps[f] += __shfl_xor(ps[f], 32);
        }

        // ---- cross-wave tree combine: {2,3} -> {0,1} -> 0 ----
        __syncthreads();  // all waves done with Pw (regions overlay it)
        if (wave >= 2) {
            float* Rg = CMB + (wave - 2) * 4352;
#pragma unroll
            for (int nt = 0; nt < 4; ++nt)
#pragma unroll
                for (int f = 0; f < 4; ++f)
                    *(f32x4*)&Rg[(f * 16 + l16) * 68 + nt * 16 + quad * 4] = o[nt][f];
            if (quad == 0)
#pragma unroll
                for (int f = 0; f < 4; ++f)
                    CMB[8704 + (wave - 2) * 64 + f * 16 + l16] = ps[f];
        }
        __syncthreads();
        if (wave < 2) {
            float* Rg = CMB + wave * 4352;
#pragma unroll
            for (int nt = 0; nt < 4; ++nt)
#pragma unroll
                for (int f = 0; f < 4; ++f)
                    o[nt][f] += *(const f32x4*)&Rg[(f * 16 + l16) * 68 + nt * 16 + quad * 4];
#pragma unroll
            for (int f = 0; f < 4; ++f)
                ps[f] += CMB[8704 + wave * 64 + f * 16 + l16];
        }
        __syncthreads();
        if (wave == 1) {
#pragma unroll
            for (int nt = 0; nt < 4; ++nt)
#pragma unroll
                for (int f = 0; f < 4; ++f)
                    *(f32x4*)&CMB[(f * 16 + l16) * 68 + nt * 16 + quad * 4] = o[nt][f];
            if (quad == 0)
#pragma unroll
                for (int f = 0; f < 4; ++f)
                    CMB[8704 + f * 16 + l16] = ps[f];
        }
        __syncthreads();
        if (wave == 0) {
#pragma unroll
            for (int nt = 0; nt < 4; ++nt)
#pragma unroll
                for (int f = 0; f < 4; ++f)
                    o[nt][f] += *(const f32x4*)&CMB[(f * 16 + l16) * 68 + nt * 16 + quad * 4];
            float inv[4];
#pragma unroll
            for (int f = 0; f < 4; ++f)
                inv[f] = 1.f / (ps[f] + CMB[8704 + f * 16 + l16]);
#pragma unroll
            for (int nt = 0; nt < 4; ++nt)
#pragma unroll
                for (int f = 0; f < 4; ++f) {
                    const int tok = row0 + f * 16 + l16;
                    const int col = h * HD + nt * 16 + quad * 4;
                    uint2 w;
                    w.x = pk2bf(o[nt][f][0] * inv[f], o[nt][f][1] * inv[f]);
                    w.y = pk2bf(o[nt][f][2] * inv[f], o[nt][f][3] * inv[f]);
                    *(uint2*)(ctx + ((size_t)b * SEQ + tok) * D_MODEL + col) = w;
                }
        }
    }
}

extern "C" void kernel_launch(void* const* d_in, const int* in_sizes, int n_in,
                              void* d_out, int out_size, void* d_ws, size_t ws_size,
                              hipStream_t stream) {
    const float* x  = (const float*)d_in[0];
    const float* Wq = (const float*)d_in[1];
    const float* Wk = (const float*)d_in[2];
    const float* Wv = (const float*)d_in[3];
    const float* Wo = (const float*)d_in[4];
    float* out = (float*)d_out;

    unsigned short* ws = (unsigned short*)d_ws;
    const size_t T = (size_t)MTOT * D_MODEL;  // 4,194,304 elements
    unsigned short* xb  = ws;                 // [4096,1024] bf16
    unsigned short* Wt  = ws + T;             // 4 x [1024,1024] bf16 (W^T)
    unsigned short* q   = ws + 2 * T;         // [B,H,N,64]  (pre-scaled)
    unsigned short* k   = ws + 3 * T;         // [B,H,N,64]
    unsigned short* vt  = ws + 4 * T;         // [B,H,64,N]
    unsigned short* ctx = ws + 5 * T;         // [4096,1024]

    prep<<<dim3(8192), dim3(256), 0, stream>>>(x, xb, Wq, Wk, Wv, Wo, Wt);

    qkv_mfma<<<dim3(192), dim3(512), 0, stream>>>(xb, Wt, q, k, vt);

    attn_mfma<<<dim3(NHEAD, 16, BATCH), dim3(256), 0, stream>>>(q, k, vt, ctx);

    gemm_out<<<dim3(8, 32), dim3(256), 0, stream>>>(ctx, Wt + 3 * (size_t)D_MODEL * D_MODEL, out);
}

// Round 6
// 182.420 us; speedup vs baseline: 1.8489x; 1.1915x over previous
//
#include <hip/hip_runtime.h>
#include <math.h>

#define D_MODEL 1024
#define NHEAD 16
#define HD 64
#define SEQ 2048
#define BATCH 2
#define MTOT (BATCH * SEQ)  // 4096

typedef __attribute__((ext_vector_type(8))) short bf16x8;
typedef __attribute__((ext_vector_type(4))) float f32x4;

__device__ __forceinline__ unsigned short f2bf(float f) {
    unsigned int u = __float_as_uint(f);
    u += 0x7FFF + ((u >> 16) & 1);  // round-to-nearest-even
    return (unsigned short)(u >> 16);
}

// packed f32x2 -> bf16x2 via HW cvt (RNE, bit-identical to f2bf for normals)
__device__ __forceinline__ unsigned int pk2bf(float a, float b) {
    unsigned int r;
    asm("v_cvt_pk_bf16_f32 %0, %1, %2" : "=v"(r) : "v"(a), "v"(b));
    return r;
}

// async global->LDS, 16B per lane. lds must be the wave-uniform chunk base:
// HW writes lane's 16B to base + lane*16 (guide §5 caveat).
__device__ __forceinline__ void async16(unsigned short* lds, const unsigned short* g) {
    __builtin_amdgcn_global_load_lds(
        (const __attribute__((address_space(1))) unsigned int*)g,
        (__attribute__((address_space(3))) unsigned int*)lds, 16, 0, 0);
}

// raw barrier with compiler memory fence (no vmcnt drain, unlike __syncthreads)
__device__ __forceinline__ void BAR() {
    asm volatile("" ::: "memory");
    __builtin_amdgcn_s_barrier();
    asm volatile("" ::: "memory");
}

// ---------------------------------------------------------------------------
// Fused prep: blocks [0,4096) convert x fp32->bf16; blocks [4096,8192)
// transpose the 4 weights W[k][n] fp32 -> Wt[n][k] bf16.
// ---------------------------------------------------------------------------
__global__ __launch_bounds__(256) void prep(const float* __restrict__ x,
                                            unsigned short* __restrict__ xb,
                                            const float* __restrict__ W0,
                                            const float* __restrict__ W1,
                                            const float* __restrict__ W2,
                                            const float* __restrict__ W3,
                                            unsigned short* __restrict__ Wt) {
    const int bid = blockIdx.x;
    const int tid = threadIdx.x;
    if (bid < 4096) {
        const int i = (bid * 256 + tid) * 4;
        float4 v = *(const float4*)(x + i);
        uint2 pk;
        pk.x = pk2bf(v.x, v.y);
        pk.y = pk2bf(v.z, v.w);
        *(uint2*)(xb + i) = pk;
    } else {
        __shared__ float T[32][33];
        const int t = bid - 4096;
        const int z = t >> 10, rem = t & 1023;
        const int n0 = (rem & 31) * 32, k0 = (rem >> 5) * 32;
        const float* W = (z == 0) ? W0 : (z == 1) ? W1 : (z == 2) ? W2 : W3;
        unsigned short* out = Wt + (size_t)z * D_MODEL * D_MODEL;
        const int tx = tid & 31, ty = tid >> 5;
#pragma unroll
        for (int i = 0; i < 4; ++i)
            T[ty + 8 * i][tx] = W[(size_t)(k0 + ty + 8 * i) * D_MODEL + n0 + tx];
        __syncthreads();
#pragma unroll
        for (int i = 0; i < 4; ++i)
            out[(size_t)(n0 + ty + 8 * i) * D_MODEL + k0 + tx] = f2bf(T[tx][ty + 8 * i]);
    }
}

// ---------------------------------------------------------------------------
// Fused QKV GEMM: 256x256 tile, 8-phase schedule (T2+T3+T4+T5 per guide §5.5).
// M=4096 (tokens), N=3072 (Wq|Wk|Wv), K=1024. Grid 192 blocks x 512 thr
// (8 waves, 2M x 4N, per-wave 128x64 output). BK=64 per K-tile, staged as
// 4 half-tiles {A,B} x {K-half}; double-buffered 128 KB LDS; counted
// vmcnt(4) at phases 2/4 only (never drained in-loop); setprio around MFMA.
// LDS swizzle: chunk c of row r at slot r*4 + (c ^ ((r+(r>>2))&3)) ->
// 2-way (free) banks on ds_read_b128; implemented as pre-swizzled GLOBAL
// source + swizzled read (global_load_lds dest stays linear, rule #21).
// Epilogues: Q (x0.125*log2e) / K -> [B,H,N,64]; V -> V^T [B,H,64,N];
// LDS-staged, fully-coalesced uint4 stores.
// ---------------------------------------------------------------------------
__global__ __launch_bounds__(512, 2) void qkv_mfma(const unsigned short* __restrict__ A,
                                                   const unsigned short* __restrict__ Wt,
                                                   unsigned short* __restrict__ q,
                                                   unsigned short* __restrict__ k,
                                                   unsigned short* __restrict__ vt) {
    __shared__ unsigned short SM[65536];  // 128 KB: [dbuf][op][ks][1024 slots x 16B]
    const int tid = threadIdx.x;
    const int wave = tid >> 6, lane = tid & 63;
    const int quad = lane >> 4, l16 = lane & 15;
    const int wm = wave >> 2, wn = wave & 3;

    // XCD-chunked block swizzle (192 % 8 == 0 -> bijective simple form)
    const int bid = blockIdx.x;
    const int swz = (bid & 7) * 24 + (bid >> 3);
    const int by = swz / 12, bx = swz % 12;
    const int m0 = by * 256;
    const int z = bx >> 2, c0 = (bx & 3) * 256;  // weight id, col base within z
    const unsigned short* Bz = Wt + (size_t)z * D_MODEL * D_MODEL;

    // ---- staging descriptors: thread covers slots {tid, 512+tid} of each
    //      16KB half-tile region; source chunk pre-swizzled ----
    const unsigned short* aptr[2];
    const unsigned short* bptr[2];
    int ldsoff[2];  // ushort units
#pragma unroll
    for (int j = 0; j < 2; ++j) {
        const int s = j * 512 + tid;
        const int r = s >> 2;
        const int cg = (s & 3) ^ ((r + (r >> 2)) & 3);
        aptr[j] = A + (size_t)(m0 + r) * D_MODEL + cg * 8;
        bptr[j] = Bz + (size_t)(c0 + r) * D_MODEL + cg * 8;
        ldsoff[j] = (j * 512 + wave * 64) * 8;
    }

    // ---- fragment read offsets (swizzled; key matches staging) ----
    const int key = (l16 + (l16 >> 2)) & 3;
    const int chunk = quad ^ key;
    int aoff[8], boff[4];  // ushort units within [ks] region / [op] region
#pragma unroll
    for (int mt = 0; mt < 8; ++mt)
        aoff[mt] = ((wm * 128 + mt * 16 + l16) * 4 + chunk) * 8;
#pragma unroll
    for (int nt = 0; nt < 4; ++nt)
        boff[nt] = 16384 + ((wn * 64 + nt * 16 + l16) * 4 + chunk) * 8;

    f32x4 acc[8][4];
#pragma unroll
    for (int mt = 0; mt < 8; ++mt)
#pragma unroll
        for (int nt = 0; nt < 4; ++nt)
            acc[mt][nt] = (f32x4){0.f, 0.f, 0.f, 0.f};

    auto stage = [&](int d, int op, int ks, int T) {
        const int base = d * 32768 + op * 16384 + ks * 8192;
#pragma unroll
        for (int j = 0; j < 2; ++j)
            async16(SM + base + ldsoff[j],
                    (op ? bptr[j] : aptr[j]) + T * 64 + ks * 32);
    };
    auto dsA = [&](bf16x8* af, int mh, int d, int ks) {
        const int base = d * 32768 + ks * 8192;
#pragma unroll
        for (int i = 0; i < 4; ++i)
            af[i] = *(const bf16x8*)&SM[base + aoff[mh * 4 + i]];
    };
    auto dsB = [&](bf16x8* bf, int d, int ks) {
        const int base = d * 32768 + ks * 8192;
#pragma unroll
        for (int i = 0; i < 4; ++i)
            bf[i] = *(const bf16x8*)&SM[base + boff[i]];
    };
    auto mfma16 = [&](bf16x8* af, bf16x8* bf, int mh) {
        __builtin_amdgcn_s_setprio(1);
#pragma unroll
        for (int i = 0; i < 4; ++i)
#pragma unroll
            for (int nt = 0; nt < 4; ++nt)
                acc[mh * 4 + i][nt] = __builtin_amdgcn_mfma_f32_16x16x32_bf16(
                    af[i], bf[nt], acc[mh * 4 + i][nt], 0, 0, 0);
        __builtin_amdgcn_s_setprio(0);
    };

    // ---- prologue: stage tile 0 (A0,B0,A1,B1), retire A0+B0, sync ----
    stage(0, 0, 0, 0);
    stage(0, 1, 0, 0);
    stage(0, 0, 1, 0);
    stage(0, 1, 1, 0);
    asm volatile("s_waitcnt vmcnt(4)" ::: "memory");
    BAR();

    const int NT = D_MODEL / 64;  // 16
    for (int T = 0; T < NT; ++T) {
        const int d = T & 1, dn = d ^ 1;
        const bool nx = (T + 1 < NT);
        bf16x8 af[4], bf[4];
        // ph1: quadrant (mh=0, ks=0); issue A-half0(T+1)
        if (nx) stage(dn, 0, 0, T + 1);
        dsA(af, 0, d, 0);
        dsB(bf, d, 0);
        mfma16(af, bf, 0);
        BAR();
        // ph2: (mh=1, ks=0) reusing bf; issue B-half0(T+1); retire A1,B1(T)
        if (nx) stage(dn, 1, 0, T + 1);
        dsA(af, 1, d, 0);
        mfma16(af, bf, 1);
        if (nx) asm volatile("s_waitcnt vmcnt(4)" ::: "memory");
        else    asm volatile("s_waitcnt vmcnt(0)" ::: "memory");
        BAR();
        // ph3: (mh=0, ks=1); issue A-half1(T+1)
        if (nx) stage(dn, 0, 1, T + 1);
        dsA(af, 0, d, 1);
        dsB(bf, d, 1);
        mfma16(af, bf, 0);
        BAR();
        // ph4: (mh=1, ks=1); issue B-half1(T+1); retire A0,B0(T+1)
        if (nx) stage(dn, 1, 1, T + 1);
        dsA(af, 1, d, 1);
        mfma16(af, bf, 1);
        if (nx) asm volatile("s_waitcnt vmcnt(4)" ::: "memory");
        else    asm volatile("s_waitcnt vmcnt(0)" ::: "memory");
        BAR();
    }

    // ---- epilogues (LDS re-staged, coalesced 16B stores) ----
    __syncthreads();
    const int bb = m0 >> 11, tok0 = m0 & (SEQ - 1), h0 = c0 >> 6;  // 4 heads/block
    if (z < 2) {
        const float qsc = (z == 0) ? 0.18033688011112042f : 1.0f;  // 0.125*log2(e)
        unsigned short* dst = (z == 0) ? q : k;
#pragma unroll
        for (int pass = 0; pass < 2; ++pass) {
            if (pass) __syncthreads();
            if (wm == pass) {
#pragma unroll
                for (int mt = 0; mt < 8; ++mt)
#pragma unroll
                    for (int nt = 0; nt < 4; ++nt)
#pragma unroll
                        for (int reg = 0; reg < 4; ++reg) {
                            const int rr = mt * 16 + quad * 4 + reg;
                            const int cc = wn * 64 + nt * 16 + l16;
                            SM[rr * 264 + cc] = f2bf(acc[mt][nt][reg] * qsc);
                        }
            }
            __syncthreads();
#pragma unroll
            for (int it = 0; it < 8; ++it) {
                const int g = it * 512 + tid;
                const int r = g >> 5, gg = g & 31;
                uint4 val = *(const uint4*)&SM[r * 264 + gg * 8];
                *(uint4*)(dst + (((size_t)bb * NHEAD + h0 + (gg >> 3)) * SEQ +
                                 tok0 + pass * 128 + r) * HD + (gg & 7) * 8) = val;
            }
        }
    } else {
        // V^T: stage [d 0..255][tok 0..127] (pad 136), coalesced stores.
#pragma unroll
        for (int pass = 0; pass < 2; ++pass) {
            if (pass) __syncthreads();
            if (wm == pass) {
#pragma unroll
                for (int mt = 0; mt < 8; ++mt)
#pragma unroll
                    for (int nt = 0; nt < 4; ++nt) {
                        const int dd = wn * 64 + nt * 16 + l16;
                        const int m = mt * 16 + quad * 4;
                        uint2 w;
                        w.x = pk2bf(acc[mt][nt][0], acc[mt][nt][1]);
                        w.y = pk2bf(acc[mt][nt][2], acc[mt][nt][3]);
                        *(uint2*)&SM[dd * 136 + m] = w;
                    }
            }
            __syncthreads();
#pragma unroll
            for (int it = 0; it < 8; ++it) {
                const int g = it * 512 + tid;
                const int dd = g >> 4, tg = (g & 15) * 8;
                uint4 val = *(const uint4*)&SM[dd * 136 + tg];
                *(uint4*)(vt + (((size_t)bb * NHEAD + h0 + (dd >> 6)) * HD + (dd & 63)) * SEQ +
                          tok0 + pass * 128 + tg) = val;
            }
        }
    }
}

// ---------------------------------------------------------------------------
// bf16 MFMA GEMM (output projection only): 128x128 tile, BK=64, 4 waves,
// global_load_lds staging, fp32 row-major output.
// ---------------------------------------------------------------------------
__global__ __launch_bounds__(256) void gemm_out(const unsigned short* __restrict__ A,
                                                const unsigned short* __restrict__ Bw,
                                                float* __restrict__ outf) {
    __shared__ unsigned short SM[16384];  // As = SM[0:8192), Bs = SM[8192:16384)
    const int tid = threadIdx.x;
    const int m0 = blockIdx.y * 128, n0 = blockIdx.x * 128;
    const int wave = tid >> 6, lane = tid & 63;
    const int quad = lane >> 4, l16 = lane & 15;
    const int wm = wave & 1, wn = wave >> 1;

    f32x4 acc[4][4];
#pragma unroll
    for (int mt = 0; mt < 4; ++mt)
#pragma unroll
        for (int nt = 0; nt < 4; ++nt)
            acc[mt][nt] = (f32x4){0.f, 0.f, 0.f, 0.f};

    for (int k0 = 0; k0 < D_MODEL; k0 += 64) {
        __syncthreads();
#pragma unroll
        for (int i = 0; i < 4; ++i) {
            const int c = i * 256 + tid;
            const int r = c >> 3, cc = (c & 7) * 8;
            const int cbase = i * 256 + wave * 64;  // wave-uniform chunk base
            async16(SM + cbase * 8, A + (size_t)(m0 + r) * D_MODEL + k0 + cc);
            async16(SM + 8192 + cbase * 8, Bw + (size_t)(n0 + r) * D_MODEL + k0 + cc);
        }
        __syncthreads();
#pragma unroll
        for (int ks = 0; ks < 2; ++ks) {
            bf16x8 af[4], bfr[4];
#pragma unroll
            for (int mt = 0; mt < 4; ++mt)
                af[mt] = *(const bf16x8*)&SM[(wm * 64 + mt * 16 + l16) * 64 + ks * 32 + quad * 8];
#pragma unroll
            for (int nt = 0; nt < 4; ++nt)
                bfr[nt] = *(const bf16x8*)&SM[8192 + (wn * 64 + nt * 16 + l16) * 64 + ks * 32 + quad * 8];
#pragma unroll
            for (int mt = 0; mt < 4; ++mt)
#pragma unroll
                for (int nt = 0; nt < 4; ++nt)
                    acc[mt][nt] = __builtin_amdgcn_mfma_f32_16x16x32_bf16(
                        af[mt], bfr[nt], acc[mt][nt], 0, 0, 0);
        }
    }

#pragma unroll
    for (int mt = 0; mt < 4; ++mt)
#pragma unroll
        for (int nt = 0; nt < 4; ++nt)
#pragma unroll
            for (int reg = 0; reg < 4; ++reg) {
                const int m = m0 + wm * 64 + mt * 16 + quad * 4 + reg;
                const int n = n0 + wn * 64 + nt * 16 + l16;
                outf[(size_t)m * D_MODEL + n] = acc[mt][nt][reg];
            }
}

// ---------------------------------------------------------------------------
// MFMA flash attention (causal), PAIRED q-tiles + 4-way kt-SPLIT.
// Grid (NHEAD, 16, BATCH), block 256 = 4 waves. Each block handles q-tiles
// {31-y, y}: 33 kt-iterations always -> uniform work. No barriers in the
// kt loop; cross-wave combine is a 2-round LDS tree.
// ROUND-1 PROVEN STRUCTURE (52.2 µs). Only two pressure-reducing tweaks:
//   (1) exp2 via __builtin_amdgcn_exp2f (single v_exp_f32, no libcall);
//   (2) aV loaded AFTER QK^T (not live during the 64-reg sT window; V
//       latency hides under softmax + P LDS round-trip).
// NO prefetch double-buffer, NO launch_bounds min-wave bump: both spill
// (rounds 2-4 post-mortems — the body is at the unified-RF ceiling).
// ---------------------------------------------------------------------------
__global__ __launch_bounds__(256, 2) void attn_mfma(const unsigned short* __restrict__ Q,
                                                    const unsigned short* __restrict__ K,
                                                    const unsigned short* __restrict__ VT,
                                                    unsigned short* __restrict__ ctx) {
    // Union LDS (35.3 KB): loop: Ps = ushort[4][4096]; combine: R0/R1/Ls.
    __shared__ float CMB[8832];
    const int tid = threadIdx.x;
    const int wave = tid >> 6, lane = tid & 63;
    const int quad = lane >> 4, l16 = lane & 15;
    const int h = blockIdx.x, b = blockIdx.z;
    const int y = blockIdx.y;
    const unsigned short* Qp = Q + ((size_t)b * NHEAD + h) * SEQ * HD;
    const unsigned short* Kp = K + ((size_t)b * NHEAD + h) * SEQ * HD;
    const unsigned short* Vp = VT + ((size_t)b * NHEAD + h) * HD * SEQ;
    unsigned short* Pw = (unsigned short*)CMB + wave * 4096;
    const int sw8 = l16 & 7;  // swizzle key (row & 7)

#pragma unroll 1
    for (int half = 0; half < 2; ++half) {
        const int p = half ? y : (31 - y);  // heavy tile first
        const int row0 = p * 64;
        if (half) __syncthreads();  // previous combine's LDS reads done

        bf16x8 bQ[4][2];  // Q as B-operand: [q-frag][ks]
#pragma unroll
        for (int f = 0; f < 4; ++f)
#pragma unroll
            for (int ks = 0; ks < 2; ++ks)
                bQ[f][ks] = *(const bf16x8*)(Qp +
                    (size_t)(row0 + f * 16 + l16) * HD + ks * 32 + quad * 8);

        f32x4 o[4][4];    // O^T accumulators: [d-tile][q-frag]
        float ps[4] = {0.f, 0.f, 0.f, 0.f};
#pragma unroll
        for (int nt = 0; nt < 4; ++nt)
#pragma unroll
            for (int f = 0; f < 4; ++f)
                o[nt][f] = (f32x4){0.f, 0.f, 0.f, 0.f};

        for (int kt = wave; kt <= p; kt += 4) {
            // ---- K fragments (direct global; no loop barriers) ----
            bf16x8 aK[4][2];
#pragma unroll
            for (int mt = 0; mt < 4; ++mt)
#pragma unroll
                for (int ks = 0; ks < 2; ++ks)
                    aK[mt][ks] = *(const bf16x8*)(Kp +
                        (size_t)(kt * 64 + mt * 16 + l16) * HD + ks * 32 + quad * 8);

            // ---- S^T = K Q^T ----
            f32x4 sT[4][4];
            __builtin_amdgcn_s_setprio(1);
#pragma unroll
            for (int mt = 0; mt < 4; ++mt)
#pragma unroll
                for (int f = 0; f < 4; ++f) {
                    sT[mt][f] = __builtin_amdgcn_mfma_f32_16x16x32_bf16(
                        aK[mt][0], bQ[f][0], (f32x4){0.f, 0.f, 0.f, 0.f}, 0, 0, 0);
                    sT[mt][f] = __builtin_amdgcn_mfma_f32_16x16x32_bf16(
                        aK[mt][1], bQ[f][1], sT[mt][f], 0, 0, 0);
                }
            __builtin_amdgcn_s_setprio(0);

            // ---- V fragments (issued here: latency hides under softmax +
            //      P round-trip; not live during QK^T's sT window) ----
            bf16x8 aV[4][2];
#pragma unroll
            for (int nt = 0; nt < 4; ++nt)
#pragma unroll
                for (int ks = 0; ks < 2; ++ks)
                    aV[nt][ks] = *(const bf16x8*)(Vp +
                        (size_t)(nt * 16 + l16) * SEQ + kt * 64 + ks * 32 + quad * 8);

            // ---- exp2 + causal mask (diag tile only) + swizzled P write ----
            const bool diag = (kt == p);
#pragma unroll
            for (int mt = 0; mt < 4; ++mt)
#pragma unroll
                for (int f = 0; f < 4; ++f) {
                    float pv[4];
#pragma unroll
                    for (int reg = 0; reg < 4; ++reg)
                        pv[reg] = __builtin_amdgcn_exp2f(sT[mt][f][reg]);
                    if (diag) {
                        const int kb = kt * 64 + mt * 16 + quad * 4;
                        const int qg = row0 + f * 16 + l16;
#pragma unroll
                        for (int reg = 0; reg < 4; ++reg)
                            pv[reg] = (kb + reg > qg) ? 0.f : pv[reg];
                    }
                    ps[f] += (pv[0] + pv[1]) + (pv[2] + pv[3]);
                    uint2 w;
                    w.x = pk2bf(pv[0], pv[1]);
                    w.y = pk2bf(pv[2], pv[3]);
                    const int gph = ((mt * 2 + (quad >> 1)) ^ sw8);
                    *(uint2*)&Pw[(f * 16 + l16) * 64 + gph * 8 + (quad & 1) * 4] = w;
                }

            // ---- P back in B-layout (wave-private; same-wave DS order) ----
            bf16x8 bP[4][2];
#pragma unroll
            for (int f = 0; f < 4; ++f)
#pragma unroll
                for (int ks = 0; ks < 2; ++ks)
                    bP[f][ks] = *(const bf16x8*)&Pw[(f * 16 + l16) * 64 +
                                                    ((ks * 4 + quad) ^ sw8) * 8];

            // ---- O^T += V^T P^T ----
            __builtin_amdgcn_s_setprio(1);
#pragma unroll
            for (int nt = 0; nt < 4; ++nt)
#pragma unroll
                for (int f = 0; f < 4; ++f) {
                    o[nt][f] = __builtin_amdgcn_mfma_f32_16x16x32_bf16(
                        aV[nt][0], bP[f][0], o[nt][f], 0, 0, 0);
                    o[nt][f] = __builtin_amdgcn_mfma_f32_16x16x32_bf16(
                        aV[nt][1], bP[f][1], o[nt][f], 0, 0, 0);
                }
            __builtin_amdgcn_s_setprio(0);
        }

#pragma unroll
        for (int f = 0; f < 4; ++f) {
            ps[f] += __shfl_xor(ps[f], 16);
            ps[f] += __shfl_xor(ps[f], 32);
        }

        // ---- cross-wave tree combine: {2,3} -> {0,1} -> 0 ----
        __syncthreads();  // all waves done with Pw (regions overlay it)
        if (wave >= 2) {
            float* Rg = CMB + (wave - 2) * 4352;
#pragma unroll
            for (int nt = 0; nt < 4; ++nt)
#pragma unroll
                for (int f = 0; f < 4; ++f)
                    *(f32x4*)&Rg[(f * 16 + l16) * 68 + nt * 16 + quad * 4] = o[nt][f];
            if (quad == 0)
#pragma unroll
                for (int f = 0; f < 4; ++f)
                    CMB[8704 + (wave - 2) * 64 + f * 16 + l16] = ps[f];
        }
        __syncthreads();
        if (wave < 2) {
            float* Rg = CMB + wave * 4352;
#pragma unroll
            for (int nt = 0; nt < 4; ++nt)
#pragma unroll
                for (int f = 0; f < 4; ++f)
                    o[nt][f] += *(const f32x4*)&Rg[(f * 16 + l16) * 68 + nt * 16 + quad * 4];
#pragma unroll
            for (int f = 0; f < 4; ++f)
                ps[f] += CMB[8704 + wave * 64 + f * 16 + l16];
        }
        __syncthreads();
        if (wave == 1) {
#pragma unroll
            for (int nt = 0; nt < 4; ++nt)
#pragma unroll
                for (int f = 0; f < 4; ++f)
                    *(f32x4*)&CMB[(f * 16 + l16) * 68 + nt * 16 + quad * 4] = o[nt][f];
            if (quad == 0)
#pragma unroll
                for (int f = 0; f < 4; ++f)
                    CMB[8704 + f * 16 + l16] = ps[f];
        }
        __syncthreads();
        if (wave == 0) {
#pragma unroll
            for (int nt = 0; nt < 4; ++nt)
#pragma unroll
                for (int f = 0; f < 4; ++f)
                    o[nt][f] += *(const f32x4*)&CMB[(f * 16 + l16) * 68 + nt * 16 + quad * 4];
            float inv[4];
#pragma unroll
            for (int f = 0; f < 4; ++f)
                inv[f] = 1.f / (ps[f] + CMB[8704 + f * 16 + l16]);
#pragma unroll
            for (int nt = 0; nt < 4; ++nt)
#pragma unroll
                for (int f = 0; f < 4; ++f) {
                    const int tok = row0 + f * 16 + l16;
                    const int col = h * HD + nt * 16 + quad * 4;
                    uint2 w;
                    w.x = pk2bf(o[nt][f][0] * inv[f], o[nt][f][1] * inv[f]);
                    w.y = pk2bf(o[nt][f][2] * inv[f], o[nt][f][3] * inv[f]);
                    *(uint2*)(ctx + ((size_t)b * SEQ + tok) * D_MODEL + col) = w;
                }
        }
    }
}

extern "C" void kernel_launch(void* const* d_in, const int* in_sizes, int n_in,
                              void* d_out, int out_size, void* d_ws, size_t ws_size,
                              hipStream_t stream) {
    const float* x  = (const float*)d_in[0];
    const float* Wq = (const float*)d_in[1];
    const float* Wk = (const float*)d_in[2];
    const float* Wv = (const float*)d_in[3];
    const float* Wo = (const float*)d_in[4];
    float* out = (float*)d_out;

    unsigned short* ws = (unsigned short*)d_ws;
    const size_t T = (size_t)MTOT * D_MODEL;  // 4,194,304 elements
    unsigned short* xb  = ws;                 // [4096,1024] bf16
    unsigned short* Wt  = ws + T;             // 4 x [1024,1024] bf16 (W^T)
    unsigned short* q   = ws + 2 * T;         // [B,H,N,64]  (pre-scaled)
    unsigned short* k   = ws + 3 * T;         // [B,H,N,64]
    unsigned short* vt  = ws + 4 * T;         // [B,H,64,N]
    unsigned short* ctx = ws + 5 * T;         // [4096,1024]

    prep<<<dim3(8192), dim3(256), 0, stream>>>(x, xb, Wq, Wk, Wv, Wo, Wt);

    qkv_mfma<<<dim3(192), dim3(512), 0, stream>>>(xb, Wt, q, k, vt);

    attn_mfma<<<dim3(NHEAD, 16, BATCH), dim3(256), 0, stream>>>(q, k, vt, ctx);

    gemm_out<<<dim3(8, 32), dim3(256), 0, stream>>>(ctx, Wt + 3 * (size_t)D_MODEL * D_MODEL, out);
}

// Round 7
// 179.976 us; speedup vs baseline: 1.8740x; 1.0136x over previous
//
#include <hip/hip_runtime.h>
#include <math.h>

#define D_MODEL 1024
#define NHEAD 16
#define HD 64
#define SEQ 2048
#define BATCH 2
#define MTOT (BATCH * SEQ)  // 4096

typedef __attribute__((ext_vector_type(8))) short bf16x8;
typedef __attribute__((ext_vector_type(4))) float f32x4;

__device__ __forceinline__ unsigned short f2bf(float f) {
    unsigned int u = __float_as_uint(f);
    u += 0x7FFF + ((u >> 16) & 1);  // round-to-nearest-even
    return (unsigned short)(u >> 16);
}

// packed f32x2 -> bf16x2 via HW cvt (RNE, bit-identical to f2bf for normals)
__device__ __forceinline__ unsigned int pk2bf(float a, float b) {
    unsigned int r;
    asm("v_cvt_pk_bf16_f32 %0, %1, %2" : "=v"(r) : "v"(a), "v"(b));
    return r;
}

// async global->LDS, 16B per lane. lds must be the wave-uniform chunk base:
// HW writes lane's 16B to base + lane*16 (guide §5 caveat).
__device__ __forceinline__ void async16(unsigned short* lds, const unsigned short* g) {
    __builtin_amdgcn_global_load_lds(
        (const __attribute__((address_space(1))) unsigned int*)g,
        (__attribute__((address_space(3))) unsigned int*)lds, 16, 0, 0);
}

// raw barrier with compiler memory fence (no vmcnt drain, unlike __syncthreads)
__device__ __forceinline__ void BAR() {
    asm volatile("" ::: "memory");
    __builtin_amdgcn_s_barrier();
    asm volatile("" ::: "memory");
}

// ---------------------------------------------------------------------------
// Fused prep: blocks [0,4096) convert x fp32->bf16; blocks [4096,8192)
// transpose the 4 weights W[k][n] fp32 -> Wt[n][k] bf16.
// ---------------------------------------------------------------------------
__global__ __launch_bounds__(256) void prep(const float* __restrict__ x,
                                            unsigned short* __restrict__ xb,
                                            const float* __restrict__ W0,
                                            const float* __restrict__ W1,
                                            const float* __restrict__ W2,
                                            const float* __restrict__ W3,
                                            unsigned short* __restrict__ Wt) {
    const int bid = blockIdx.x;
    const int tid = threadIdx.x;
    if (bid < 4096) {
        const int i = (bid * 256 + tid) * 4;
        float4 v = *(const float4*)(x + i);
        uint2 pk;
        pk.x = pk2bf(v.x, v.y);
        pk.y = pk2bf(v.z, v.w);
        *(uint2*)(xb + i) = pk;
    } else {
        __shared__ float T[32][33];
        const int t = bid - 4096;
        const int z = t >> 10, rem = t & 1023;
        const int n0 = (rem & 31) * 32, k0 = (rem >> 5) * 32;
        const float* W = (z == 0) ? W0 : (z == 1) ? W1 : (z == 2) ? W2 : W3;
        unsigned short* out = Wt + (size_t)z * D_MODEL * D_MODEL;
        const int tx = tid & 31, ty = tid >> 5;
#pragma unroll
        for (int i = 0; i < 4; ++i)
            T[ty + 8 * i][tx] = W[(size_t)(k0 + ty + 8 * i) * D_MODEL + n0 + tx];
        __syncthreads();
#pragma unroll
        for (int i = 0; i < 4; ++i)
            out[(size_t)(n0 + ty + 8 * i) * D_MODEL + k0 + tx] = f2bf(T[tx][ty + 8 * i]);
    }
}

// ---------------------------------------------------------------------------
// Fused QKV GEMM: 256x192 tile, 8-phase schedule (T2+T3+T4+T5).
// M=4096, N=3072 (Wq|Wk|Wv as one [3072][1024] B), K=1024.
// Grid 16x16 = 256 blocks = EXACTLY 1 block/CU (the 256x256 version had 192
// blocks -> 25% of CUs idle; same total work, 0.75x per block => -25%).
// 512 thr = 8 waves (2M x 4N), per-wave 128x48 output (acc[8][3]).
// BK=64 staged as {A,B} x {K-half}; A half-tile 16KB (1024 slots), B
// half-tile 12KB (768 slots: waves 0-3 stage 2 chunks, waves 4-7 stage 1).
// Counted vmcnt is CLASS-DEPENDENT: allowed-outstanding = own next-tile
// issues = 2+2 (waves 0-3) / 2+1 (waves 4-7) -> vmcnt(4) / vmcnt(3).
// LDS 112KB double-buffered; swizzle identical to the proven 256x256 form
// (chunk keys invariant: row bases are 0 mod 4 after the (r+(r>>2))&3 map).
// Epilogue: per-64-col group (3 groups; may mix K and V columns in one
// block): zg<2 -> Q/K [B,H,N,64] path (Q x0.125*log2e); zg==2 -> V^T
// [B,H,64,N] transpose path. Groups never straddle 1024-boundaries.
// ---------------------------------------------------------------------------
__global__ __launch_bounds__(512, 2) void qkv_mfma(const unsigned short* __restrict__ A,
                                                   const unsigned short* __restrict__ Wt,
                                                   unsigned short* __restrict__ q,
                                                   unsigned short* __restrict__ k,
                                                   unsigned short* __restrict__ vt) {
    __shared__ unsigned short SM[57344];  // 112KB: [dbuf][A ks0|A ks1|B ks0|B ks1]
    const int tid = threadIdx.x;
    const int wave = tid >> 6, lane = tid & 63;
    const int quad = lane >> 4, l16 = lane & 15;
    const int wm = wave >> 2, wn = wave & 3;

    // XCD-chunked block swizzle (256 % 8 == 0 -> bijective)
    const int bid = blockIdx.x;
    const int swz = (bid & 7) * 32 + (bid >> 3);
    const int by = swz >> 4, bx = swz & 15;
    const int m0 = by * 256;
    const int c0 = bx * 192;  // column base within [3072]
    const unsigned short* Bz = Wt;  // Wt viewed as one [3072][1024]

    // ---- staging descriptors (source chunk pre-swizzled) ----
    const unsigned short* aptr[2];
    const unsigned short* bptr[2];
#pragma unroll
    for (int j = 0; j < 2; ++j) {
        const int s = j * 512 + tid;
        const int r = s >> 2;
        const int cg = (s & 3) ^ ((r + (r >> 2)) & 3);
        aptr[j] = A + (size_t)(m0 + r) * D_MODEL + cg * 8;
        // B rows only valid where used (j=1 used only by tid<256)
        const int rb = (r < 192) ? r : 191;
        bptr[j] = Bz + (size_t)(c0 + rb) * D_MODEL + cg * 8;
    }
    const int ldsA0 = (wave * 64) * 8, ldsA1 = (512 + wave * 64) * 8;
    const int ldsB0 = (wave * 64) * 8, ldsB1 = (512 + wave * 64) * 8;

    // ---- fragment read offsets (swizzled; key matches staging) ----
    const int key = (l16 + (l16 >> 2)) & 3;
    const int chunk = quad ^ key;
    int aoff[8], boff[3];
#pragma unroll
    for (int mt = 0; mt < 8; ++mt)
        aoff[mt] = ((wm * 128 + mt * 16 + l16) * 4 + chunk) * 8;
#pragma unroll
    for (int nt = 0; nt < 3; ++nt)
        boff[nt] = ((wn * 48 + nt * 16 + l16) * 4 + chunk) * 8;

    f32x4 acc[8][3];
#pragma unroll
    for (int mt = 0; mt < 8; ++mt)
#pragma unroll
        for (int nt = 0; nt < 3; ++nt)
            acc[mt][nt] = (f32x4){0.f, 0.f, 0.f, 0.f};

    // region bases (ushort units): per dbuf: A ks0 @0, A ks1 @8192,
    // B ks0 @16384, B ks1 @22528; dbuf stride 28672.
    auto stageA = [&](int d, int ks, int T) {
        const int base = d * 28672 + ks * 8192;
        async16(SM + base + ldsA0, aptr[0] + T * 64 + ks * 32);
        async16(SM + base + ldsA1, aptr[1] + T * 64 + ks * 32);
    };
    auto stageB = [&](int d, int ks, int T) {
        const int base = d * 28672 + 16384 + ks * 6144;
        async16(SM + base + ldsB0, bptr[0] + T * 64 + ks * 32);
        if (wave < 4)
            async16(SM + base + ldsB1, bptr[1] + T * 64 + ks * 32);
    };
    auto dsA = [&](bf16x8* af, int mh, int d, int ks) {
        const int base = d * 28672 + ks * 8192;
#pragma unroll
        for (int i = 0; i < 4; ++i)
            af[i] = *(const bf16x8*)&SM[base + aoff[mh * 4 + i]];
    };
    auto dsB = [&](bf16x8* bf, int d, int ks) {
        const int base = d * 28672 + 16384 + ks * 6144;
#pragma unroll
        for (int i = 0; i < 3; ++i)
            bf[i] = *(const bf16x8*)&SM[base + boff[i]];
    };
    auto mfma12 = [&](bf16x8* af, bf16x8* bf, int mh) {
        __builtin_amdgcn_s_setprio(1);
#pragma unroll
        for (int i = 0; i < 4; ++i)
#pragma unroll
            for (int nt = 0; nt < 3; ++nt)
                acc[mh * 4 + i][nt] = __builtin_amdgcn_mfma_f32_16x16x32_bf16(
                    af[i], bf[nt], acc[mh * 4 + i][nt], 0, 0, 0);
        __builtin_amdgcn_s_setprio(0);
    };
    auto waitc = [&](bool nx) {
        if (nx) {
            if (wave < 4) asm volatile("s_waitcnt vmcnt(4)" ::: "memory");
            else          asm volatile("s_waitcnt vmcnt(3)" ::: "memory");
        } else {
            asm volatile("s_waitcnt vmcnt(0)" ::: "memory");
        }
    };

    // ---- prologue: stage tile 0, retire A0+B0, sync ----
    stageA(0, 0, 0);
    stageB(0, 0, 0);
    stageA(0, 1, 0);
    stageB(0, 1, 0);
    waitc(true);
    BAR();

    const int NT = D_MODEL / 64;  // 16
    for (int T = 0; T < NT; ++T) {
        const int d = T & 1, dn = d ^ 1;
        const bool nx = (T + 1 < NT);
        bf16x8 af[4], bf[3];
        // ph1: (mh=0, ks=0); issue A-half0(T+1)
        if (nx) stageA(dn, 0, T + 1);
        dsA(af, 0, d, 0);
        dsB(bf, d, 0);
        mfma12(af, bf, 0);
        BAR();
        // ph2: (mh=1, ks=0) reuse bf; issue B-half0(T+1); retire A1,B1(T)
        if (nx) stageB(dn, 0, T + 1);
        dsA(af, 1, d, 0);
        mfma12(af, bf, 1);
        waitc(nx);
        BAR();
        // ph3: (mh=0, ks=1); issue A-half1(T+1)
        if (nx) stageA(dn, 1, T + 1);
        dsA(af, 0, d, 1);
        dsB(bf, d, 1);
        mfma12(af, bf, 0);
        BAR();
        // ph4: (mh=1, ks=1); issue B-half1(T+1); retire A0,B0(T+1)
        if (nx) stageB(dn, 1, T + 1);
        dsA(af, 1, d, 1);
        mfma12(af, bf, 1);
        waitc(nx);
        BAR();
    }

    // ---- epilogue: 3 x 64-col groups; QK path or V^T path per group ----
    __syncthreads();
    const int bb = m0 >> 11, tok0 = m0 & (SEQ - 1);
#pragma unroll 1
    for (int G = 0; G < 3; ++G) {
        if (G) __syncthreads();
        const int gcol = c0 + G * 64;
        const int zg = gcol >> 10;
        const int hg = (gcol >> 6) & 15;
        if (zg < 2) {
            const float sc = (zg == 0) ? 0.18033688011112042f : 1.0f;  // 0.125*log2(e)
            unsigned short* dst = (zg == 0) ? q : k;
            // stage [256 tok][64 d]
#pragma unroll
            for (int nt = 0; nt < 3; ++nt) {
                const int colb = wn * 48 + nt * 16;
                if ((colb >> 6) == G) {
                    const int cl = colb - G * 64 + l16;
#pragma unroll
                    for (int mt = 0; mt < 8; ++mt)
#pragma unroll
                        for (int reg = 0; reg < 4; ++reg) {
                            const int rr = wm * 128 + mt * 16 + quad * 4 + reg;
                            SM[rr * 64 + cl] = f2bf(acc[mt][nt][reg] * sc);
                        }
                }
            }
            __syncthreads();
#pragma unroll
            for (int it = 0; it < 4; ++it) {
                const int g = it * 512 + tid;
                const int r = g >> 3, c8 = g & 7;
                uint4 val = *(const uint4*)&SM[r * 64 + c8 * 8];
                *(uint4*)(dst + (((size_t)bb * NHEAD + hg) * SEQ + tok0 + r) * HD +
                          c8 * 8) = val;
            }
        } else {
            // V^T: stage [64 d][256 tok + pad 8]
#pragma unroll
            for (int nt = 0; nt < 3; ++nt) {
                const int colb = wn * 48 + nt * 16;
                if ((colb >> 6) == G) {
                    const int dl = colb - G * 64 + l16;
#pragma unroll
                    for (int mt = 0; mt < 8; ++mt) {
                        const int m = wm * 128 + mt * 16 + quad * 4;
                        uint2 w;
                        w.x = pk2bf(acc[mt][nt][0], acc[mt][nt][1]);
                        w.y = pk2bf(acc[mt][nt][2], acc[mt][nt][3]);
                        *(uint2*)&SM[dl * 264 + m] = w;
                    }
                }
            }
            __syncthreads();
#pragma unroll
            for (int it = 0; it < 4; ++it) {
                const int g = it * 512 + tid;
                const int dd = g >> 5, t8 = (g & 31) * 8;
                uint4 val = *(const uint4*)&SM[dd * 264 + t8];
                *(uint4*)(vt + (((size_t)bb * NHEAD + hg) * HD + dd) * SEQ + tok0 +
                          t8) = val;
            }
        }
    }
}

// ---------------------------------------------------------------------------
// bf16 MFMA GEMM (output projection only): 128x128 tile, BK=64, 4 waves,
// global_load_lds staging, fp32 row-major output.
// ---------------------------------------------------------------------------
__global__ __launch_bounds__(256) void gemm_out(const unsigned short* __restrict__ A,
                                                const unsigned short* __restrict__ Bw,
                                                float* __restrict__ outf) {
    __shared__ unsigned short SM[16384];  // As = SM[0:8192), Bs = SM[8192:16384)
    const int tid = threadIdx.x;
    const int m0 = blockIdx.y * 128, n0 = blockIdx.x * 128;
    const int wave = tid >> 6, lane = tid & 63;
    const int quad = lane >> 4, l16 = lane & 15;
    const int wm = wave & 1, wn = wave >> 1;

    f32x4 acc[4][4];
#pragma unroll
    for (int mt = 0; mt < 4; ++mt)
#pragma unroll
        for (int nt = 0; nt < 4; ++nt)
            acc[mt][nt] = (f32x4){0.f, 0.f, 0.f, 0.f};

    for (int k0 = 0; k0 < D_MODEL; k0 += 64) {
        __syncthreads();
#pragma unroll
        for (int i = 0; i < 4; ++i) {
            const int c = i * 256 + tid;
            const int r = c >> 3, cc = (c & 7) * 8;
            const int cbase = i * 256 + wave * 64;  // wave-uniform chunk base
            async16(SM + cbase * 8, A + (size_t)(m0 + r) * D_MODEL + k0 + cc);
            async16(SM + 8192 + cbase * 8, Bw + (size_t)(n0 + r) * D_MODEL + k0 + cc);
        }
        __syncthreads();
#pragma unroll
        for (int ks = 0; ks < 2; ++ks) {
            bf16x8 af[4], bfr[4];
#pragma unroll
            for (int mt = 0; mt < 4; ++mt)
                af[mt] = *(const bf16x8*)&SM[(wm * 64 + mt * 16 + l16) * 64 + ks * 32 + quad * 8];
#pragma unroll
            for (int nt = 0; nt < 4; ++nt)
                bfr[nt] = *(const bf16x8*)&SM[8192 + (wn * 64 + nt * 16 + l16) * 64 + ks * 32 + quad * 8];
#pragma unroll
            for (int mt = 0; mt < 4; ++mt)
#pragma unroll
                for (int nt = 0; nt < 4; ++nt)
                    acc[mt][nt] = __builtin_amdgcn_mfma_f32_16x16x32_bf16(
                        af[mt], bfr[nt], acc[mt][nt], 0, 0, 0);
        }
    }

#pragma unroll
    for (int mt = 0; mt < 4; ++mt)
#pragma unroll
        for (int nt = 0; nt < 4; ++nt)
#pragma unroll
            for (int reg = 0; reg < 4; ++reg) {
                const int m = m0 + wm * 64 + mt * 16 + quad * 4 + reg;
                const int n = n0 + wn * 64 + nt * 16 + l16;
                outf[(size_t)m * D_MODEL + n] = acc[mt][nt][reg];
            }
}

// ---------------------------------------------------------------------------
// MFMA flash attention (causal), PAIRED q-tiles + 4-way kt-SPLIT.
// ROUND-5 VERIFIED OPTIMUM (45.5 µs) — unchanged.
// ---------------------------------------------------------------------------
__global__ __launch_bounds__(256, 2) void attn_mfma(const unsigned short* __restrict__ Q,
                                                    const unsigned short* __restrict__ K,
                                                    const unsigned short* __restrict__ VT,
                                                    unsigned short* __restrict__ ctx) {
    // Union LDS (35.3 KB): loop: Ps = ushort[4][4096]; combine: R0/R1/Ls.
    __shared__ float CMB[8832];
    const int tid = threadIdx.x;
    const int wave = tid >> 6, lane = tid & 63;
    const int quad = lane >> 4, l16 = lane & 15;
    const int h = blockIdx.x, b = blockIdx.z;
    const int y = blockIdx.y;
    const unsigned short* Qp = Q + ((size_t)b * NHEAD + h) * SEQ * HD;
    const unsigned short* Kp = K + ((size_t)b * NHEAD + h) * SEQ * HD;
    const unsigned short* Vp = VT + ((size_t)b * NHEAD + h) * HD * SEQ;
    unsigned short* Pw = (unsigned short*)CMB + wave * 4096;
    const int sw8 = l16 & 7;  // swizzle key (row & 7)

#pragma unroll 1
    for (int half = 0; half < 2; ++half) {
        const int p = half ? y : (31 - y);  // heavy tile first
        const int row0 = p * 64;
        if (half) __syncthreads();  // previous combine's LDS reads done

        bf16x8 bQ[4][2];  // Q as B-operand: [q-frag][ks]
#pragma unroll
        for (int f = 0; f < 4; ++f)
#pragma unroll
            for (int ks = 0; ks < 2; ++ks)
                bQ[f][ks] = *(const bf16x8*)(Qp +
                    (size_t)(row0 + f * 16 + l16) * HD + ks * 32 + quad * 8);

        f32x4 o[4][4];    // O^T accumulators: [d-tile][q-frag]
        float ps[4] = {0.f, 0.f, 0.f, 0.f};
#pragma unroll
        for (int nt = 0; nt < 4; ++nt)
#pragma unroll
            for (int f = 0; f < 4; ++f)
                o[nt][f] = (f32x4){0.f, 0.f, 0.f, 0.f};

        for (int kt = wave; kt <= p; kt += 4) {
            // ---- K fragments (direct global; no loop barriers) ----
            bf16x8 aK[4][2];
#pragma unroll
            for (int mt = 0; mt < 4; ++mt)
#pragma unroll
                for (int ks = 0; ks < 2; ++ks)
                    aK[mt][ks] = *(const bf16x8*)(Kp +
                        (size_t)(kt * 64 + mt * 16 + l16) * HD + ks * 32 + quad * 8);

            // ---- S^T = K Q^T ----
            f32x4 sT[4][4];
            __builtin_amdgcn_s_setprio(1);
#pragma unroll
            for (int mt = 0; mt < 4; ++mt)
#pragma unroll
                for (int f = 0; f < 4; ++f) {
                    sT[mt][f] = __builtin_amdgcn_mfma_f32_16x16x32_bf16(
                        aK[mt][0], bQ[f][0], (f32x4){0.f, 0.f, 0.f, 0.f}, 0, 0, 0);
                    sT[mt][f] = __builtin_amdgcn_mfma_f32_16x16x32_bf16(
                        aK[mt][1], bQ[f][1], sT[mt][f], 0, 0, 0);
                }
            __builtin_amdgcn_s_setprio(0);

            // ---- V fragments (issued here: latency hides under softmax +
            //      P round-trip; not live during QK^T's sT window) ----
            bf16x8 aV[4][2];
#pragma unroll
            for (int nt = 0; nt < 4; ++nt)
#pragma unroll
                for (int ks = 0; ks < 2; ++ks)
                    aV[nt][ks] = *(const bf16x8*)(Vp +
                        (size_t)(nt * 16 + l16) * SEQ + kt * 64 + ks * 32 + quad * 8);

            // ---- exp2 + causal mask (diag tile only) + swizzled P write ----
            const bool diag = (kt == p);
#pragma unroll
            for (int mt = 0; mt < 4; ++mt)
#pragma unroll
                for (int f = 0; f < 4; ++f) {
                    float pv[4];
#pragma unroll
                    for (int reg = 0; reg < 4; ++reg)
                        pv[reg] = __builtin_amdgcn_exp2f(sT[mt][f][reg]);
                    if (diag) {
                        const int kb = kt * 64 + mt * 16 + quad * 4;
                        const int qg = row0 + f * 16 + l16;
#pragma unroll
                        for (int reg = 0; reg < 4; ++reg)
                            pv[reg] = (kb + reg > qg) ? 0.f : pv[reg];
                    }
                    ps[f] += (pv[0] + pv[1]) + (pv[2] + pv[3]);
                    uint2 w;
                    w.x = pk2bf(pv[0], pv[1]);
                    w.y = pk2bf(pv[2], pv[3]);
                    const int gph = ((mt * 2 + (quad >> 1)) ^ sw8);
                    *(uint2*)&Pw[(f * 16 + l16) * 64 + gph * 8 + (quad & 1) * 4] = w;
                }

            // ---- P back in B-layout (wave-private; same-wave DS order) ----
            bf16x8 bP[4][2];
#pragma unroll
            for (int f = 0; f < 4; ++f)
#pragma unroll
                for (int ks = 0; ks < 2; ++ks)
                    bP[f][ks] = *(const bf16x8*)&Pw[(f * 16 + l16) * 64 +
                                                    ((ks * 4 + quad) ^ sw8) * 8];

            // ---- O^T += V^T P^T ----
            __builtin_amdgcn_s_setprio(1);
#pragma unroll
            for (int nt = 0; nt < 4; ++nt)
#pragma unroll
                for (int f = 0; f < 4; ++f) {
                    o[nt][f] = __builtin_amdgcn_mfma_f32_16x16x32_bf16(
                        aV[nt][0], bP[f][0], o[nt][f], 0, 0, 0);
                    o[nt][f] = __builtin_amdgcn_mfma_f32_16x16x32_bf16(
                        aV[nt][1], bP[f][1], o[nt][f], 0, 0, 0);
                }
            __builtin_amdgcn_s_setprio(0);
        }

#pragma unroll
        for (int f = 0; f < 4; ++f) {
            ps[f] += __shfl_xor(ps[f], 16);
            ps[f] += __shfl_xor(ps[f], 32);
        }

        // ---- cross-wave tree combine: {2,3} -> {0,1} -> 0 ----
        __syncthreads();  // all waves done with Pw (regions overlay it)
        if (wave >= 2) {
            float* Rg = CMB + (wave - 2) * 4352;
#pragma unroll
            for (int nt = 0; nt < 4; ++nt)
#pragma unroll
                for (int f = 0; f < 4; ++f)
                    *(f32x4*)&Rg[(f * 16 + l16) * 68 + nt * 16 + quad * 4] = o[nt][f];
            if (quad == 0)
#pragma unroll
                for (int f = 0; f < 4; ++f)
                    CMB[8704 + (wave - 2) * 64 + f * 16 + l16] = ps[f];
        }
        __syncthreads();
        if (wave < 2) {
            float* Rg = CMB + wave * 4352;
#pragma unroll
            for (int nt = 0; nt < 4; ++nt)
#pragma unroll
                for (int f = 0; f < 4; ++f)
                    o[nt][f] += *(const f32x4*)&Rg[(f * 16 + l16) * 68 + nt * 16 + quad * 4];
#pragma unroll
            for (int f = 0; f < 4; ++f)
                ps[f] += CMB[8704 + wave * 64 + f * 16 + l16];
        }
        __syncthreads();
        if (wave == 1) {
#pragma unroll
            for (int nt = 0; nt < 4; ++nt)
#pragma unroll
                for (int f = 0; f < 4; ++f)
                    *(f32x4*)&CMB[(f * 16 + l16) * 68 + nt * 16 + quad * 4] = o[nt][f];
            if (quad == 0)
#pragma unroll
                for (int f = 0; f < 4; ++f)
                    CMB[8704 + f * 16 + l16] = ps[f];
        }
        __syncthreads();
        if (wave == 0) {
#pragma unroll
            for (int nt = 0; nt < 4; ++nt)
#pragma unroll
                for (int f = 0; f < 4; ++f)
                    o[nt][f] += *(const f32x4*)&CMB[(f * 16 + l16) * 68 + nt * 16 + quad * 4];
            float inv[4];
#pragma unroll
            for (int f = 0; f < 4; ++f)
                inv[f] = 1.f / (ps[f] + CMB[8704 + f * 16 + l16]);
#pragma unroll
            for (int nt = 0; nt < 4; ++nt)
#pragma unroll
                for (int f = 0; f < 4; ++f) {
                    const int tok = row0 + f * 16 + l16;
                    const int col = h * HD + nt * 16 + quad * 4;
                    uint2 w;
                    w.x = pk2bf(o[nt][f][0] * inv[f], o[nt][f][1] * inv[f]);
                    w.y = pk2bf(o[nt][f][2] * inv[f], o[nt][f][3] * inv[f]);
                    *(uint2*)(ctx + ((size_t)b * SEQ + tok) * D_MODEL + col) = w;
                }
        }
    }
}

extern "C" void kernel_launch(void* const* d_in, const int* in_sizes, int n_in,
                              void* d_out, int out_size, void* d_ws, size_t ws_size,
                              hipStream_t stream) {
    const float* x  = (const float*)d_in[0];
    const float* Wq = (const float*)d_in[1];
    const float* Wk = (const float*)d_in[2];
    const float* Wv = (const float*)d_in[3];
    const float* Wo = (const float*)d_in[4];
    float* out = (float*)d_out;

    unsigned short* ws = (unsigned short*)d_ws;
    const size_t T = (size_t)MTOT * D_MODEL;  // 4,194,304 elements
    unsigned short* xb  = ws;                 // [4096,1024] bf16
    unsigned short* Wt  = ws + T;             // 4 x [1024,1024] bf16 (W^T)
    unsigned short* q   = ws + 2 * T;         // [B,H,N,64]  (pre-scaled)
    unsigned short* k   = ws + 3 * T;         // [B,H,N,64]
    unsigned short* vt  = ws + 4 * T;         // [B,H,64,N]
    unsigned short* ctx = ws + 5 * T;         // [4096,1024]

    prep<<<dim3(8192), dim3(256), 0, stream>>>(x, xb, Wq, Wk, Wv, Wo, Wt);

    qkv_mfma<<<dim3(256), dim3(512), 0, stream>>>(xb, Wt, q, k, vt);

    attn_mfma<<<dim3(NHEAD, 16, BATCH), dim3(256), 0, stream>>>(q, k, vt, ctx);

    gemm_out<<<dim3(8, 32), dim3(256), 0, stream>>>(ctx, Wt + 3 * (size_t)D_MODEL * D_MODEL, out);
}

// Round 8
// 179.093 us; speedup vs baseline: 1.8833x; 1.0049x over previous
//
#include <hip/hip_runtime.h>
#include <math.h>

#define D_MODEL 1024
#define NHEAD 16
#define HD 64
#define SEQ 2048
#define BATCH 2
#define MTOT (BATCH * SEQ)  // 4096

typedef __attribute__((ext_vector_type(8))) short bf16x8;
typedef __attribute__((ext_vector_type(4))) float f32x4;

__device__ __forceinline__ unsigned short f2bf(float f) {
    unsigned int u = __float_as_uint(f);
    u += 0x7FFF + ((u >> 16) & 1);  // round-to-nearest-even
    return (unsigned short)(u >> 16);
}

// packed f32x2 -> bf16x2 via HW cvt (RNE, bit-identical to f2bf for normals)
__device__ __forceinline__ unsigned int pk2bf(float a, float b) {
    unsigned int r;
    asm("v_cvt_pk_bf16_f32 %0, %1, %2" : "=v"(r) : "v"(a), "v"(b));
    return r;
}

// async global->LDS, 16B per lane. lds must be the wave-uniform chunk base:
// HW writes lane's 16B to base + lane*16 (guide §5 caveat).
__device__ __forceinline__ void async16(unsigned short* lds, const unsigned short* g) {
    __builtin_amdgcn_global_load_lds(
        (const __attribute__((address_space(1))) unsigned int*)g,
        (__attribute__((address_space(3))) unsigned int*)lds, 16, 0, 0);
}

// raw barrier with compiler memory fence (no vmcnt drain, unlike __syncthreads)
__device__ __forceinline__ void BAR() {
    asm volatile("" ::: "memory");
    __builtin_amdgcn_s_barrier();
    asm volatile("" ::: "memory");
}

// ---------------------------------------------------------------------------
// Fused prep: blocks [0,4096) convert x fp32->bf16; blocks [4096,8192)
// transpose the 4 weights W[k][n] fp32 -> Wt[n][k] bf16.
// ---------------------------------------------------------------------------
__global__ __launch_bounds__(256) void prep(const float* __restrict__ x,
                                            unsigned short* __restrict__ xb,
                                            const float* __restrict__ W0,
                                            const float* __restrict__ W1,
                                            const float* __restrict__ W2,
                                            const float* __restrict__ W3,
                                            unsigned short* __restrict__ Wt) {
    const int bid = blockIdx.x;
    const int tid = threadIdx.x;
    if (bid < 4096) {
        const int i = (bid * 256 + tid) * 4;
        float4 v = *(const float4*)(x + i);
        uint2 pk;
        pk.x = pk2bf(v.x, v.y);
        pk.y = pk2bf(v.z, v.w);
        *(uint2*)(xb + i) = pk;
    } else {
        __shared__ float T[32][33];
        const int t = bid - 4096;
        const int z = t >> 10, rem = t & 1023;
        const int n0 = (rem & 31) * 32, k0 = (rem >> 5) * 32;
        const float* W = (z == 0) ? W0 : (z == 1) ? W1 : (z == 2) ? W2 : W3;
        unsigned short* out = Wt + (size_t)z * D_MODEL * D_MODEL;
        const int tx = tid & 31, ty = tid >> 5;
#pragma unroll
        for (int i = 0; i < 4; ++i)
            T[ty + 8 * i][tx] = W[(size_t)(k0 + ty + 8 * i) * D_MODEL + n0 + tx];
        __syncthreads();
#pragma unroll
        for (int i = 0; i < 4; ++i)
            out[(size_t)(n0 + ty + 8 * i) * D_MODEL + k0 + tx] = f2bf(T[tx][ty + 8 * i]);
    }
}

// ---------------------------------------------------------------------------
// Fused QKV GEMM: 256x192 tile, TRUE 8-barrier-per-tile phase rhythm (m201
// template: ds_reads BEFORE the barrier so LDS latency hides under the
// rendezvous; two barriers per phase; counted vmcnt between stage and BAR).
// M=4096, N=3072, K=1024. Grid 16x16 = 256 blocks = 1 block/CU, 512 thr =
// 8 waves (2M x 4N), per-wave 128x48 (acc[8][3]).
// Per phase: {ds_read cluster; stage next half-tile; [gate ph2/ph4];
//             sched_barrier; BAR; MFMA (compiler lgkmcnt); BAR}.
// Gates (class-dependent: waves 0-3 stage B with 2 issues, 4-7 with 1):
//   ph2 gates A1,B1(T)   leaving A0,B0(T+1) -> vmcnt(4)/vmcnt(3)
//   ph4 gates A0,B0(T+1) leaving A1,B1(T+1) -> vmcnt(4)/vmcnt(3)
// Read-safety: ph1 reads ks0(T) gated at T-1 ph4 (+2 BARs); ph3 reads
// ks1(T) gated at T ph2 (+1 BAR). Swizzle/staging/epilogue unchanged.
// ---------------------------------------------------------------------------
__global__ __launch_bounds__(512, 2) void qkv_mfma(const unsigned short* __restrict__ A,
                                                   const unsigned short* __restrict__ Wt,
                                                   unsigned short* __restrict__ q,
                                                   unsigned short* __restrict__ k,
                                                   unsigned short* __restrict__ vt) {
    __shared__ unsigned short SM[57344];  // 112KB: [dbuf][A ks0|A ks1|B ks0|B ks1]
    const int tid = threadIdx.x;
    const int wave = tid >> 6, lane = tid & 63;
    const int quad = lane >> 4, l16 = lane & 15;
    const int wm = wave >> 2, wn = wave & 3;

    // XCD-chunked block swizzle (256 % 8 == 0 -> bijective)
    const int bid = blockIdx.x;
    const int swz = (bid & 7) * 32 + (bid >> 3);
    const int by = swz >> 4, bx = swz & 15;
    const int m0 = by * 256;
    const int c0 = bx * 192;  // column base within [3072]
    const unsigned short* Bz = Wt;  // Wt viewed as one [3072][1024]

    // ---- staging descriptors (source chunk pre-swizzled) ----
    const unsigned short* aptr[2];
    const unsigned short* bptr[2];
#pragma unroll
    for (int j = 0; j < 2; ++j) {
        const int s = j * 512 + tid;
        const int r = s >> 2;
        const int cg = (s & 3) ^ ((r + (r >> 2)) & 3);
        aptr[j] = A + (size_t)(m0 + r) * D_MODEL + cg * 8;
        // B rows only valid where used (j=1 used only by tid<256)
        const int rb = (r < 192) ? r : 191;
        bptr[j] = Bz + (size_t)(c0 + rb) * D_MODEL + cg * 8;
    }
    const int ldsA0 = (wave * 64) * 8, ldsA1 = (512 + wave * 64) * 8;
    const int ldsB0 = (wave * 64) * 8, ldsB1 = (512 + wave * 64) * 8;

    // ---- fragment read offsets (swizzled; key matches staging) ----
    const int key = (l16 + (l16 >> 2)) & 3;
    const int chunk = quad ^ key;
    int aoff[8], boff[3];
#pragma unroll
    for (int mt = 0; mt < 8; ++mt)
        aoff[mt] = ((wm * 128 + mt * 16 + l16) * 4 + chunk) * 8;
#pragma unroll
    for (int nt = 0; nt < 3; ++nt)
        boff[nt] = ((wn * 48 + nt * 16 + l16) * 4 + chunk) * 8;

    f32x4 acc[8][3];
#pragma unroll
    for (int mt = 0; mt < 8; ++mt)
#pragma unroll
        for (int nt = 0; nt < 3; ++nt)
            acc[mt][nt] = (f32x4){0.f, 0.f, 0.f, 0.f};

    // region bases (ushort units): per dbuf: A ks0 @0, A ks1 @8192,
    // B ks0 @16384, B ks1 @22528; dbuf stride 28672.
    auto stageA = [&](int d, int ks, int T) {
        const int base = d * 28672 + ks * 8192;
        async16(SM + base + ldsA0, aptr[0] + T * 64 + ks * 32);
        async16(SM + base + ldsA1, aptr[1] + T * 64 + ks * 32);
    };
    auto stageB = [&](int d, int ks, int T) {
        const int base = d * 28672 + 16384 + ks * 6144;
        async16(SM + base + ldsB0, bptr[0] + T * 64 + ks * 32);
        if (wave < 4)
            async16(SM + base + ldsB1, bptr[1] + T * 64 + ks * 32);
    };
    auto dsA = [&](bf16x8* af, int mh, int d, int ks) {
        const int base = d * 28672 + ks * 8192;
#pragma unroll
        for (int i = 0; i < 4; ++i)
            af[i] = *(const bf16x8*)&SM[base + aoff[mh * 4 + i]];
    };
    auto dsB = [&](bf16x8* bf, int d, int ks) {
        const int base = d * 28672 + 16384 + ks * 6144;
#pragma unroll
        for (int i = 0; i < 3; ++i)
            bf[i] = *(const bf16x8*)&SM[base + boff[i]];
    };
    auto mfma12 = [&](bf16x8* af, bf16x8* bf, int mh) {
        __builtin_amdgcn_s_setprio(1);
#pragma unroll
        for (int i = 0; i < 4; ++i)
#pragma unroll
            for (int nt = 0; nt < 3; ++nt)
                acc[mh * 4 + i][nt] = __builtin_amdgcn_mfma_f32_16x16x32_bf16(
                    af[i], bf[nt], acc[mh * 4 + i][nt], 0, 0, 0);
        __builtin_amdgcn_s_setprio(0);
    };
    auto waitc = [&](bool nx) {
        if (nx) {
            if (wave < 4) asm volatile("s_waitcnt vmcnt(4)" ::: "memory");
            else          asm volatile("s_waitcnt vmcnt(3)" ::: "memory");
        } else {
            asm volatile("s_waitcnt vmcnt(0)" ::: "memory");
        }
    };

    // ---- prologue: stage tile 0, retire A0+B0, sync ----
    stageA(0, 0, 0);
    stageB(0, 0, 0);
    stageA(0, 1, 0);
    stageB(0, 1, 0);
    waitc(true);
    BAR();

    const int NT = D_MODEL / 64;  // 16
    for (int T = 0; T < NT; ++T) {
        const int d = T & 1, dn = d ^ 1;
        const bool nx = (T + 1 < NT);
        bf16x8 af[4], bf[3];
        // ph1: reads (mh0,ks0); stage A-half0(T+1); BAR; MFMA; BAR
        dsA(af, 0, d, 0);
        dsB(bf, d, 0);
        if (nx) stageA(dn, 0, T + 1);
        __builtin_amdgcn_sched_barrier(0);
        BAR();
        mfma12(af, bf, 0);
        BAR();
        // ph2: reads (mh1,ks0) reuse bf; stage B-half0(T+1); gate A1,B1(T)
        dsA(af, 1, d, 0);
        if (nx) stageB(dn, 0, T + 1);
        waitc(nx);
        __builtin_amdgcn_sched_barrier(0);
        BAR();
        mfma12(af, bf, 1);
        BAR();
        // ph3: reads (mh0,ks1); stage A-half1(T+1); BAR; MFMA; BAR
        dsA(af, 0, d, 1);
        dsB(bf, d, 1);
        if (nx) stageA(dn, 1, T + 1);
        __builtin_amdgcn_sched_barrier(0);
        BAR();
        mfma12(af, bf, 0);
        BAR();
        // ph4: reads (mh1,ks1); stage B-half1(T+1); gate A0,B0(T+1)
        dsA(af, 1, d, 1);
        if (nx) stageB(dn, 1, T + 1);
        waitc(nx);
        __builtin_amdgcn_sched_barrier(0);
        BAR();
        mfma12(af, bf, 1);
        BAR();
    }

    // ---- epilogue: 3 x 64-col groups; QK path or V^T path per group ----
    __syncthreads();
    const int bb = m0 >> 11, tok0 = m0 & (SEQ - 1);
#pragma unroll 1
    for (int G = 0; G < 3; ++G) {
        if (G) __syncthreads();
        const int gcol = c0 + G * 64;
        const int zg = gcol >> 10;
        const int hg = (gcol >> 6) & 15;
        if (zg < 2) {
            const float sc = (zg == 0) ? 0.18033688011112042f : 1.0f;  // 0.125*log2(e)
            unsigned short* dst = (zg == 0) ? q : k;
            // stage [256 tok][64 d]
#pragma unroll
            for (int nt = 0; nt < 3; ++nt) {
                const int colb = wn * 48 + nt * 16;
                if ((colb >> 6) == G) {
                    const int cl = colb - G * 64 + l16;
#pragma unroll
                    for (int mt = 0; mt < 8; ++mt)
#pragma unroll
                        for (int reg = 0; reg < 4; ++reg) {
                            const int rr = wm * 128 + mt * 16 + quad * 4 + reg;
                            SM[rr * 64 + cl] = f2bf(acc[mt][nt][reg] * sc);
                        }
                }
            }
            __syncthreads();
#pragma unroll
            for (int it = 0; it < 4; ++it) {
                const int g = it * 512 + tid;
                const int r = g >> 3, c8 = g & 7;
                uint4 val = *(const uint4*)&SM[r * 64 + c8 * 8];
                *(uint4*)(dst + (((size_t)bb * NHEAD + hg) * SEQ + tok0 + r) * HD +
                          c8 * 8) = val;
            }
        } else {
            // V^T: stage [64 d][256 tok + pad 8]
#pragma unroll
            for (int nt = 0; nt < 3; ++nt) {
                const int colb = wn * 48 + nt * 16;
                if ((colb >> 6) == G) {
                    const int dl = colb - G * 64 + l16;
#pragma unroll
                    for (int mt = 0; mt < 8; ++mt) {
                        const int m = wm * 128 + mt * 16 + quad * 4;
                        uint2 w;
                        w.x = pk2bf(acc[mt][nt][0], acc[mt][nt][1]);
                        w.y = pk2bf(acc[mt][nt][2], acc[mt][nt][3]);
                        *(uint2*)&SM[dl * 264 + m] = w;
                    }
                }
            }
            __syncthreads();
#pragma unroll
            for (int it = 0; it < 4; ++it) {
                const int g = it * 512 + tid;
                const int dd = g >> 5, t8 = (g & 31) * 8;
                uint4 val = *(const uint4*)&SM[dd * 264 + t8];
                *(uint4*)(vt + (((size_t)bb * NHEAD + hg) * HD + dd) * SEQ + tok0 +
                          t8) = val;
            }
        }
    }
}

// ---------------------------------------------------------------------------
// bf16 MFMA GEMM (output projection only): 128x128 tile, BK=64, 4 waves,
// global_load_lds staging, fp32 row-major output.
// ---------------------------------------------------------------------------
__global__ __launch_bounds__(256) void gemm_out(const unsigned short* __restrict__ A,
                                                const unsigned short* __restrict__ Bw,
                                                float* __restrict__ outf) {
    __shared__ unsigned short SM[16384];  // As = SM[0:8192), Bs = SM[8192:16384)
    const int tid = threadIdx.x;
    const int m0 = blockIdx.y * 128, n0 = blockIdx.x * 128;
    const int wave = tid >> 6, lane = tid & 63;
    const int quad = lane >> 4, l16 = lane & 15;
    const int wm = wave & 1, wn = wave >> 1;

    f32x4 acc[4][4];
#pragma unroll
    for (int mt = 0; mt < 4; ++mt)
#pragma unroll
        for (int nt = 0; nt < 4; ++nt)
            acc[mt][nt] = (f32x4){0.f, 0.f, 0.f, 0.f};

    for (int k0 = 0; k0 < D_MODEL; k0 += 64) {
        __syncthreads();
#pragma unroll
        for (int i = 0; i < 4; ++i) {
            const int c = i * 256 + tid;
            const int r = c >> 3, cc = (c & 7) * 8;
            const int cbase = i * 256 + wave * 64;  // wave-uniform chunk base
            async16(SM + cbase * 8, A + (size_t)(m0 + r) * D_MODEL + k0 + cc);
            async16(SM + 8192 + cbase * 8, Bw + (size_t)(n0 + r) * D_MODEL + k0 + cc);
        }
        __syncthreads();
#pragma unroll
        for (int ks = 0; ks < 2; ++ks) {
            bf16x8 af[4], bfr[4];
#pragma unroll
            for (int mt = 0; mt < 4; ++mt)
                af[mt] = *(const bf16x8*)&SM[(wm * 64 + mt * 16 + l16) * 64 + ks * 32 + quad * 8];
#pragma unroll
            for (int nt = 0; nt < 4; ++nt)
                bfr[nt] = *(const bf16x8*)&SM[8192 + (wn * 64 + nt * 16 + l16) * 64 + ks * 32 + quad * 8];
#pragma unroll
            for (int mt = 0; mt < 4; ++mt)
#pragma unroll
                for (int nt = 0; nt < 4; ++nt)
                    acc[mt][nt] = __builtin_amdgcn_mfma_f32_16x16x32_bf16(
                        af[mt], bfr[nt], acc[mt][nt], 0, 0, 0);
        }
    }

#pragma unroll
    for (int mt = 0; mt < 4; ++mt)
#pragma unroll
        for (int nt = 0; nt < 4; ++nt)
#pragma unroll
            for (int reg = 0; reg < 4; ++reg) {
                const int m = m0 + wm * 64 + mt * 16 + quad * 4 + reg;
                const int n = n0 + wn * 64 + nt * 16 + l16;
                outf[(size_t)m * D_MODEL + n] = acc[mt][nt][reg];
            }
}

// ---------------------------------------------------------------------------
// MFMA flash attention (causal), PAIRED q-tiles + 4-way kt-SPLIT.
// ROUND-5 VERIFIED OPTIMUM (45.5 µs) — unchanged.
// ---------------------------------------------------------------------------
__global__ __launch_bounds__(256, 2) void attn_mfma(const unsigned short* __restrict__ Q,
                                                    const unsigned short* __restrict__ K,
                                                    const unsigned short* __restrict__ VT,
                                                    unsigned short* __restrict__ ctx) {
    // Union LDS (35.3 KB): loop: Ps = ushort[4][4096]; combine: R0/R1/Ls.
    __shared__ float CMB[8832];
    const int tid = threadIdx.x;
    const int wave = tid >> 6, lane = tid & 63;
    const int quad = lane >> 4, l16 = lane & 15;
    const int h = blockIdx.x, b = blockIdx.z;
    const int y = blockIdx.y;
    const unsigned short* Qp = Q + ((size_t)b * NHEAD + h) * SEQ * HD;
    const unsigned short* Kp = K + ((size_t)b * NHEAD + h) * SEQ * HD;
    const unsigned short* Vp = VT + ((size_t)b * NHEAD + h) * HD * SEQ;
    unsigned short* Pw = (unsigned short*)CMB + wave * 4096;
    const int sw8 = l16 & 7;  // swizzle key (row & 7)

#pragma unroll 1
    for (int half = 0; half < 2; ++half) {
        const int p = half ? y : (31 - y);  // heavy tile first
        const int row0 = p * 64;
        if (half) __syncthreads();  // previous combine's LDS reads done

        bf16x8 bQ[4][2];  // Q as B-operand: [q-frag][ks]
#pragma unroll
        for (int f = 0; f < 4; ++f)
#pragma unroll
            for (int ks = 0; ks < 2; ++ks)
                bQ[f][ks] = *(const bf16x8*)(Qp +
                    (size_t)(row0 + f * 16 + l16) * HD + ks * 32 + quad * 8);

        f32x4 o[4][4];    // O^T accumulators: [d-tile][q-frag]
        float ps[4] = {0.f, 0.f, 0.f, 0.f};
#pragma unroll
        for (int nt = 0; nt < 4; ++nt)
#pragma unroll
            for (int f = 0; f < 4; ++f)
                o[nt][f] = (f32x4){0.f, 0.f, 0.f, 0.f};

        for (int kt = wave; kt <= p; kt += 4) {
            // ---- K fragments (direct global; no loop barriers) ----
            bf16x8 aK[4][2];
#pragma unroll
            for (int mt = 0; mt < 4; ++mt)
#pragma unroll
                for (int ks = 0; ks < 2; ++ks)
                    aK[mt][ks] = *(const bf16x8*)(Kp +
                        (size_t)(kt * 64 + mt * 16 + l16) * HD + ks * 32 + quad * 8);

            // ---- S^T = K Q^T ----
            f32x4 sT[4][4];
            __builtin_amdgcn_s_setprio(1);
#pragma unroll
            for (int mt = 0; mt < 4; ++mt)
#pragma unroll
                for (int f = 0; f < 4; ++f) {
                    sT[mt][f] = __builtin_amdgcn_mfma_f32_16x16x32_bf16(
                        aK[mt][0], bQ[f][0], (f32x4){0.f, 0.f, 0.f, 0.f}, 0, 0, 0);
                    sT[mt][f] = __builtin_amdgcn_mfma_f32_16x16x32_bf16(
                        aK[mt][1], bQ[f][1], sT[mt][f], 0, 0, 0);
                }
            __builtin_amdgcn_s_setprio(0);

            // ---- V fragments (issued here: latency hides under softmax +
            //      P round-trip; not live during QK^T's sT window) ----
            bf16x8 aV[4][2];
#pragma unroll
            for (int nt = 0; nt < 4; ++nt)
#pragma unroll
                for (int ks = 0; ks < 2; ++ks)
                    aV[nt][ks] = *(const bf16x8*)(Vp +
                        (size_t)(nt * 16 + l16) * SEQ + kt * 64 + ks * 32 + quad * 8);

            // ---- exp2 + causal mask (diag tile only) + swizzled P write ----
            const bool diag = (kt == p);
#pragma unroll
            for (int mt = 0; mt < 4; ++mt)
#pragma unroll
                for (int f = 0; f < 4; ++f) {
                    float pv[4];
#pragma unroll
                    for (int reg = 0; reg < 4; ++reg)
                        pv[reg] = __builtin_amdgcn_exp2f(sT[mt][f][reg]);
                    if (diag) {
                        const int kb = kt * 64 + mt * 16 + quad * 4;
                        const int qg = row0 + f * 16 + l16;
#pragma unroll
                        for (int reg = 0; reg < 4; ++reg)
                            pv[reg] = (kb + reg > qg) ? 0.f : pv[reg];
                    }
                    ps[f] += (pv[0] + pv[1]) + (pv[2] + pv[3]);
                    uint2 w;
                    w.x = pk2bf(pv[0], pv[1]);
                    w.y = pk2bf(pv[2], pv[3]);
                    const int gph = ((mt * 2 + (quad >> 1)) ^ sw8);
                    *(uint2*)&Pw[(f * 16 + l16) * 64 + gph * 8 + (quad & 1) * 4] = w;
                }

            // ---- P back in B-layout (wave-private; same-wave DS order) ----
            bf16x8 bP[4][2];
#pragma unroll
            for (int f = 0; f < 4; ++f)
#pragma unroll
                for (int ks = 0; ks < 2; ++ks)
                    bP[f][ks] = *(const bf16x8*)&Pw[(f * 16 + l16) * 64 +
                                                    ((ks * 4 + quad) ^ sw8) * 8];

            // ---- O^T += V^T P^T ----
            __builtin_amdgcn_s_setprio(1);
#pragma unroll
            for (int nt = 0; nt < 4; ++nt)
#pragma unroll
                for (int f = 0; f < 4; ++f) {
                    o[nt][f] = __builtin_amdgcn_mfma_f32_16x16x32_bf16(
                        aV[nt][0], bP[f][0], o[nt][f], 0, 0, 0);
                    o[nt][f] = __builtin_amdgcn_mfma_f32_16x16x32_bf16(
                        aV[nt][1], bP[f][1], o[nt][f], 0, 0, 0);
                }
            __builtin_amdgcn_s_setprio(0);
        }

#pragma unroll
        for (int f = 0; f < 4; ++f) {
            ps[f] += __shfl_xor(ps[f], 16);
            ps[f] += __shfl_xor(ps[f], 32);
        }

        // ---- cross-wave tree combine: {2,3} -> {0,1} -> 0 ----
        __syncthreads();  // all waves done with Pw (regions overlay it)
        if (wave >= 2) {
            float* Rg = CMB + (wave - 2) * 4352;
#pragma unroll
            for (int nt = 0; nt < 4; ++nt)
#pragma unroll
                for (int f = 0; f < 4; ++f)
                    *(f32x4*)&Rg[(f * 16 + l16) * 68 + nt * 16 + quad * 4] = o[nt][f];
            if (quad == 0)
#pragma unroll
                for (int f = 0; f < 4; ++f)
                    CMB[8704 + (wave - 2) * 64 + f * 16 + l16] = ps[f];
        }
        __syncthreads();
        if (wave < 2) {
            float* Rg = CMB + wave * 4352;
#pragma unroll
            for (int nt = 0; nt < 4; ++nt)
#pragma unroll
                for (int f = 0; f < 4; ++f)
                    o[nt][f] += *(const f32x4*)&Rg[(f * 16 + l16) * 68 + nt * 16 + quad * 4];
#pragma unroll
            for (int f = 0; f < 4; ++f)
                ps[f] += CMB[8704 + wave * 64 + f * 16 + l16];
        }
        __syncthreads();
        if (wave == 1) {
#pragma unroll
            for (int nt = 0; nt < 4; ++nt)
#pragma unroll
                for (int f = 0; f < 4; ++f)
                    *(f32x4*)&CMB[(f * 16 + l16) * 68 + nt * 16 + quad * 4] = o[nt][f];
            if (quad == 0)
#pragma unroll
                for (int f = 0; f < 4; ++f)
                    CMB[8704 + f * 16 + l16] = ps[f];
        }
        __syncthreads();
        if (wave == 0) {
#pragma unroll
            for (int nt = 0; nt < 4; ++nt)
#pragma unroll
                for (int f = 0; f < 4; ++f)
                    o[nt][f] += *(const f32x4*)&CMB[(f * 16 + l16) * 68 + nt * 16 + quad * 4];
            float inv[4];
#pragma unroll
            for (int f = 0; f < 4; ++f)
                inv[f] = 1.f / (ps[f] + CMB[8704 + f * 16 + l16]);
#pragma unroll
            for (int nt = 0; nt < 4; ++nt)
#pragma unroll
                for (int f = 0; f < 4; ++f) {
                    const int tok = row0 + f * 16 + l16;
                    const int col = h * HD + nt * 16 + quad * 4;
                    uint2 w;
                    w.x = pk2bf(o[nt][f][0] * inv[f], o[nt][f][1] * inv[f]);
                    w.y = pk2bf(o[nt][f][2] * inv[f], o[nt][f][3] * inv[f]);
                    *(uint2*)(ctx + ((size_t)b * SEQ + tok) * D_MODEL + col) = w;
                }
        }
    }
}

extern "C" void kernel_launch(void* const* d_in, const int* in_sizes, int n_in,
                              void* d_out, int out_size, void* d_ws, size_t ws_size,
                              hipStream_t stream) {
    const float* x  = (const float*)d_in[0];
    const float* Wq = (const float*)d_in[1];
    const float* Wk = (const float*)d_in[2];
    const float* Wv = (const float*)d_in[3];
    const float* Wo = (const float*)d_in[4];
    float* out = (float*)d_out;

    unsigned short* ws = (unsigned short*)d_ws;
    const size_t T = (size_t)MTOT * D_MODEL;  // 4,194,304 elements
    unsigned short* xb  = ws;                 // [4096,1024] bf16
    unsigned short* Wt  = ws + T;             // 4 x [1024,1024] bf16 (W^T)
    unsigned short* q   = ws + 2 * T;         // [B,H,N,64]  (pre-scaled)
    unsigned short* k   = ws + 3 * T;         // [B,H,N,64]
    unsigned short* vt  = ws + 4 * T;         // [B,H,64,N]
    unsigned short* ctx = ws + 5 * T;         // [4096,1024]

    prep<<<dim3(8192), dim3(256), 0, stream>>>(x, xb, Wq, Wk, Wv, Wo, Wt);

    qkv_mfma<<<dim3(256), dim3(512), 0, stream>>>(xb, Wt, q, k, vt);

    attn_mfma<<<dim3(NHEAD, 16, BATCH), dim3(256), 0, stream>>>(q, k, vt, ctx);

    gemm_out<<<dim3(8, 32), dim3(256), 0, stream>>>(ctx, Wt + 3 * (size_t)D_MODEL * D_MODEL, out);
}

// Round 9
// 176.625 us; speedup vs baseline: 1.9096x; 1.0140x over previous
//
#include <hip/hip_runtime.h>
#include <math.h>

#define D_MODEL 1024
#define NHEAD 16
#define HD 64
#define SEQ 2048
#define BATCH 2
#define MTOT (BATCH * SEQ)  // 4096

typedef __attribute__((ext_vector_type(8))) short bf16x8;
typedef __attribute__((ext_vector_type(4))) float f32x4;

__device__ __forceinline__ unsigned short f2bf(float f) {
    unsigned int u = __float_as_uint(f);
    u += 0x7FFF + ((u >> 16) & 1);  // round-to-nearest-even
    return (unsigned short)(u >> 16);
}

// packed f32x2 -> bf16x2 via HW cvt (RNE, bit-identical to f2bf for normals)
__device__ __forceinline__ unsigned int pk2bf(float a, float b) {
    unsigned int r;
    asm("v_cvt_pk_bf16_f32 %0, %1, %2" : "=v"(r) : "v"(a), "v"(b));
    return r;
}

// async global->LDS, 16B per lane. lds must be the wave-uniform chunk base:
// HW writes lane's 16B to base + lane*16 (guide §5 caveat).
__device__ __forceinline__ void async16(unsigned short* lds, const unsigned short* g) {
    __builtin_amdgcn_global_load_lds(
        (const __attribute__((address_space(1))) unsigned int*)g,
        (__attribute__((address_space(3))) unsigned int*)lds, 16, 0, 0);
}

// raw barrier with compiler memory fence (no vmcnt drain, unlike __syncthreads)
__device__ __forceinline__ void BAR() {
    asm volatile("" ::: "memory");
    __builtin_amdgcn_s_barrier();
    asm volatile("" ::: "memory");
}

// ---------------------------------------------------------------------------
// Fused prep: blocks [0,4096) convert x fp32->bf16; blocks [4096,8192)
// transpose the 4 weights W[k][n] fp32 -> Wt[n][k] bf16.
// ---------------------------------------------------------------------------
__global__ __launch_bounds__(256) void prep(const float* __restrict__ x,
                                            unsigned short* __restrict__ xb,
                                            const float* __restrict__ W0,
                                            const float* __restrict__ W1,
                                            const float* __restrict__ W2,
                                            const float* __restrict__ W3,
                                            unsigned short* __restrict__ Wt) {
    const int bid = blockIdx.x;
    const int tid = threadIdx.x;
    if (bid < 4096) {
        const int i = (bid * 256 + tid) * 4;
        float4 v = *(const float4*)(x + i);
        uint2 pk;
        pk.x = pk2bf(v.x, v.y);
        pk.y = pk2bf(v.z, v.w);
        *(uint2*)(xb + i) = pk;
    } else {
        __shared__ float T[32][33];
        const int t = bid - 4096;
        const int z = t >> 10, rem = t & 1023;
        const int n0 = (rem & 31) * 32, k0 = (rem >> 5) * 32;
        const float* W = (z == 0) ? W0 : (z == 1) ? W1 : (z == 2) ? W2 : W3;
        unsigned short* out = Wt + (size_t)z * D_MODEL * D_MODEL;
        const int tx = tid & 31, ty = tid >> 5;
#pragma unroll
        for (int i = 0; i < 4; ++i)
            T[ty + 8 * i][tx] = W[(size_t)(k0 + ty + 8 * i) * D_MODEL + n0 + tx];
        __syncthreads();
#pragma unroll
        for (int i = 0; i < 4; ++i)
            out[(size_t)(n0 + ty + 8 * i) * D_MODEL + k0 + tx] = f2bf(T[tx][ty + 8 * i]);
    }
}

// ---------------------------------------------------------------------------
// Fused QKV GEMM: 256x192 tile, 8-barrier-per-tile phase rhythm.
// (Round-7 verified; see comments there.) Grid 256 blocks x 512 thr.
// ---------------------------------------------------------------------------
__global__ __launch_bounds__(512, 2) void qkv_mfma(const unsigned short* __restrict__ A,
                                                   const unsigned short* __restrict__ Wt,
                                                   unsigned short* __restrict__ q,
                                                   unsigned short* __restrict__ k,
                                                   unsigned short* __restrict__ vt) {
    __shared__ unsigned short SM[57344];  // 112KB: [dbuf][A ks0|A ks1|B ks0|B ks1]
    const int tid = threadIdx.x;
    const int wave = tid >> 6, lane = tid & 63;
    const int quad = lane >> 4, l16 = lane & 15;
    const int wm = wave >> 2, wn = wave & 3;

    // XCD-chunked block swizzle (256 % 8 == 0 -> bijective)
    const int bid = blockIdx.x;
    const int swz = (bid & 7) * 32 + (bid >> 3);
    const int by = swz >> 4, bx = swz & 15;
    const int m0 = by * 256;
    const int c0 = bx * 192;  // column base within [3072]
    const unsigned short* Bz = Wt;  // Wt viewed as one [3072][1024]

    // ---- staging descriptors (source chunk pre-swizzled) ----
    const unsigned short* aptr[2];
    const unsigned short* bptr[2];
#pragma unroll
    for (int j = 0; j < 2; ++j) {
        const int s = j * 512 + tid;
        const int r = s >> 2;
        const int cg = (s & 3) ^ ((r + (r >> 2)) & 3);
        aptr[j] = A + (size_t)(m0 + r) * D_MODEL + cg * 8;
        // B rows only valid where used (j=1 used only by tid<256)
        const int rb = (r < 192) ? r : 191;
        bptr[j] = Bz + (size_t)(c0 + rb) * D_MODEL + cg * 8;
    }
    const int ldsA0 = (wave * 64) * 8, ldsA1 = (512 + wave * 64) * 8;
    const int ldsB0 = (wave * 64) * 8, ldsB1 = (512 + wave * 64) * 8;

    // ---- fragment read offsets (swizzled; key matches staging) ----
    const int key = (l16 + (l16 >> 2)) & 3;
    const int chunk = quad ^ key;
    int aoff[8], boff[3];
#pragma unroll
    for (int mt = 0; mt < 8; ++mt)
        aoff[mt] = ((wm * 128 + mt * 16 + l16) * 4 + chunk) * 8;
#pragma unroll
    for (int nt = 0; nt < 3; ++nt)
        boff[nt] = ((wn * 48 + nt * 16 + l16) * 4 + chunk) * 8;

    f32x4 acc[8][3];
#pragma unroll
    for (int mt = 0; mt < 8; ++mt)
#pragma unroll
        for (int nt = 0; nt < 3; ++nt)
            acc[mt][nt] = (f32x4){0.f, 0.f, 0.f, 0.f};

    // region bases (ushort units): per dbuf: A ks0 @0, A ks1 @8192,
    // B ks0 @16384, B ks1 @22528; dbuf stride 28672.
    auto stageA = [&](int d, int ks, int T) {
        const int base = d * 28672 + ks * 8192;
        async16(SM + base + ldsA0, aptr[0] + T * 64 + ks * 32);
        async16(SM + base + ldsA1, aptr[1] + T * 64 + ks * 32);
    };
    auto stageB = [&](int d, int ks, int T) {
        const int base = d * 28672 + 16384 + ks * 6144;
        async16(SM + base + ldsB0, bptr[0] + T * 64 + ks * 32);
        if (wave < 4)
            async16(SM + base + ldsB1, bptr[1] + T * 64 + ks * 32);
    };
    auto dsA = [&](bf16x8* af, int mh, int d, int ks) {
        const int base = d * 28672 + ks * 8192;
#pragma unroll
        for (int i = 0; i < 4; ++i)
            af[i] = *(const bf16x8*)&SM[base + aoff[mh * 4 + i]];
    };
    auto dsB = [&](bf16x8* bf, int d, int ks) {
        const int base = d * 28672 + 16384 + ks * 6144;
#pragma unroll
        for (int i = 0; i < 3; ++i)
            bf[i] = *(const bf16x8*)&SM[base + boff[i]];
    };
    auto mfma12 = [&](bf16x8* af, bf16x8* bf, int mh) {
        __builtin_amdgcn_s_setprio(1);
#pragma unroll
        for (int i = 0; i < 4; ++i)
#pragma unroll
            for (int nt = 0; nt < 3; ++nt)
                acc[mh * 4 + i][nt] = __builtin_amdgcn_mfma_f32_16x16x32_bf16(
                    af[i], bf[nt], acc[mh * 4 + i][nt], 0, 0, 0);
        __builtin_amdgcn_s_setprio(0);
    };
    auto waitc = [&](bool nx) {
        if (nx) {
            if (wave < 4) asm volatile("s_waitcnt vmcnt(4)" ::: "memory");
            else          asm volatile("s_waitcnt vmcnt(3)" ::: "memory");
        } else {
            asm volatile("s_waitcnt vmcnt(0)" ::: "memory");
        }
    };

    // ---- prologue: stage tile 0, retire A0+B0, sync ----
    stageA(0, 0, 0);
    stageB(0, 0, 0);
    stageA(0, 1, 0);
    stageB(0, 1, 0);
    waitc(true);
    BAR();

    const int NT = D_MODEL / 64;  // 16
    for (int T = 0; T < NT; ++T) {
        const int d = T & 1, dn = d ^ 1;
        const bool nx = (T + 1 < NT);
        bf16x8 af[4], bf[3];
        // ph1: reads (mh0,ks0); stage A-half0(T+1); BAR; MFMA; BAR
        dsA(af, 0, d, 0);
        dsB(bf, d, 0);
        if (nx) stageA(dn, 0, T + 1);
        __builtin_amdgcn_sched_barrier(0);
        BAR();
        mfma12(af, bf, 0);
        BAR();
        // ph2: reads (mh1,ks0) reuse bf; stage B-half0(T+1); gate A1,B1(T)
        dsA(af, 1, d, 0);
        if (nx) stageB(dn, 0, T + 1);
        waitc(nx);
        __builtin_amdgcn_sched_barrier(0);
        BAR();
        mfma12(af, bf, 1);
        BAR();
        // ph3: reads (mh0,ks1); stage A-half1(T+1); BAR; MFMA; BAR
        dsA(af, 0, d, 1);
        dsB(bf, d, 1);
        if (nx) stageA(dn, 1, T + 1);
        __builtin_amdgcn_sched_barrier(0);
        BAR();
        mfma12(af, bf, 0);
        BAR();
        // ph4: reads (mh1,ks1); stage B-half1(T+1); gate A0,B0(T+1)
        dsA(af, 1, d, 1);
        if (nx) stageB(dn, 1, T + 1);
        waitc(nx);
        __builtin_amdgcn_sched_barrier(0);
        BAR();
        mfma12(af, bf, 1);
        BAR();
    }

    // ---- epilogue: 3 x 64-col groups; QK path or V^T path per group ----
    __syncthreads();
    const int bb = m0 >> 11, tok0 = m0 & (SEQ - 1);
#pragma unroll 1
    for (int G = 0; G < 3; ++G) {
        if (G) __syncthreads();
        const int gcol = c0 + G * 64;
        const int zg = gcol >> 10;
        const int hg = (gcol >> 6) & 15;
        if (zg < 2) {
            const float sc = (zg == 0) ? 0.18033688011112042f : 1.0f;  // 0.125*log2(e)
            unsigned short* dst = (zg == 0) ? q : k;
            // stage [256 tok][64 d]
#pragma unroll
            for (int nt = 0; nt < 3; ++nt) {
                const int colb = wn * 48 + nt * 16;
                if ((colb >> 6) == G) {
                    const int cl = colb - G * 64 + l16;
#pragma unroll
                    for (int mt = 0; mt < 8; ++mt)
#pragma unroll
                        for (int reg = 0; reg < 4; ++reg) {
                            const int rr = wm * 128 + mt * 16 + quad * 4 + reg;
                            SM[rr * 64 + cl] = f2bf(acc[mt][nt][reg] * sc);
                        }
                }
            }
            __syncthreads();
#pragma unroll
            for (int it = 0; it < 4; ++it) {
                const int g = it * 512 + tid;
                const int r = g >> 3, c8 = g & 7;
                uint4 val = *(const uint4*)&SM[r * 64 + c8 * 8];
                *(uint4*)(dst + (((size_t)bb * NHEAD + hg) * SEQ + tok0 + r) * HD +
                          c8 * 8) = val;
            }
        } else {
            // V^T: stage [64 d][256 tok + pad 8]
#pragma unroll
            for (int nt = 0; nt < 3; ++nt) {
                const int colb = wn * 48 + nt * 16;
                if ((colb >> 6) == G) {
                    const int dl = colb - G * 64 + l16;
#pragma unroll
                    for (int mt = 0; mt < 8; ++mt) {
                        const int m = wm * 128 + mt * 16 + quad * 4;
                        uint2 w;
                        w.x = pk2bf(acc[mt][nt][0], acc[mt][nt][1]);
                        w.y = pk2bf(acc[mt][nt][2], acc[mt][nt][3]);
                        *(uint2*)&SM[dl * 264 + m] = w;
                    }
                }
            }
            __syncthreads();
#pragma unroll
            for (int it = 0; it < 4; ++it) {
                const int g = it * 512 + tid;
                const int dd = g >> 5, t8 = (g & 31) * 8;
                uint4 val = *(const uint4*)&SM[dd * 264 + t8];
                *(uint4*)(vt + (((size_t)bb * NHEAD + hg) * HD + dd) * SEQ + tok0 +
                          t8) = val;
            }
        }
    }
}

// ---------------------------------------------------------------------------
// bf16 MFMA GEMM (output projection only): 64x128 tile, BK=64, 4 waves.
// Grid (8,64) = 512 blocks = 2 blocks/CU (the 128x128/grid-256 version was
// 1 block/CU: the 2-phase drain structure needs cross-block overlap (m114);
// at 1 block/CU the drain is fully exposed). LDS 24 KB, VGPR light.
// ---------------------------------------------------------------------------
__global__ __launch_bounds__(256) void gemm_out(const unsigned short* __restrict__ A,
                                                const unsigned short* __restrict__ Bw,
                                                float* __restrict__ outf) {
    __shared__ unsigned short SM[12288];  // As = [0,4096), Bs = [4096,12288)
    const int tid = threadIdx.x;
    const int m0 = blockIdx.y * 64, n0 = blockIdx.x * 128;
    const int wave = tid >> 6, lane = tid & 63;
    const int quad = lane >> 4, l16 = lane & 15;
    const int wm = wave & 1, wn = wave >> 1;  // wave tile: 32 rows x 64 cols

    f32x4 acc[2][4];
#pragma unroll
    for (int mt = 0; mt < 2; ++mt)
#pragma unroll
        for (int nt = 0; nt < 4; ++nt)
            acc[mt][nt] = (f32x4){0.f, 0.f, 0.f, 0.f};

    for (int k0 = 0; k0 < D_MODEL; k0 += 64) {
        __syncthreads();
        // A: 64 rows -> 512 chunks (2/thread); B: 128 rows -> 1024 (4/thread)
#pragma unroll
        for (int i = 0; i < 2; ++i) {
            const int c = i * 256 + tid;
            const int r = c >> 3, cc = (c & 7) * 8;
            const int cbase = i * 256 + wave * 64;  // wave-uniform chunk base
            async16(SM + cbase * 8, A + (size_t)(m0 + r) * D_MODEL + k0 + cc);
        }
#pragma unroll
        for (int i = 0; i < 4; ++i) {
            const int c = i * 256 + tid;
            const int r = c >> 3, cc = (c & 7) * 8;
            const int cbase = i * 256 + wave * 64;
            async16(SM + 4096 + cbase * 8, Bw + (size_t)(n0 + r) * D_MODEL + k0 + cc);
        }
        __syncthreads();
#pragma unroll
        for (int ks = 0; ks < 2; ++ks) {
            bf16x8 af[2], bfr[4];
#pragma unroll
            for (int mt = 0; mt < 2; ++mt)
                af[mt] = *(const bf16x8*)&SM[(wm * 32 + mt * 16 + l16) * 64 + ks * 32 + quad * 8];
#pragma unroll
            for (int nt = 0; nt < 4; ++nt)
                bfr[nt] = *(const bf16x8*)&SM[4096 + (wn * 64 + nt * 16 + l16) * 64 + ks * 32 + quad * 8];
#pragma unroll
            for (int mt = 0; mt < 2; ++mt)
#pragma unroll
                for (int nt = 0; nt < 4; ++nt)
                    acc[mt][nt] = __builtin_amdgcn_mfma_f32_16x16x32_bf16(
                        af[mt], bfr[nt], acc[mt][nt], 0, 0, 0);
        }
    }

#pragma unroll
    for (int mt = 0; mt < 2; ++mt)
#pragma unroll
        for (int nt = 0; nt < 4; ++nt)
#pragma unroll
            for (int reg = 0; reg < 4; ++reg) {
                const int m = m0 + wm * 32 + mt * 16 + quad * 4 + reg;
                const int n = n0 + wn * 64 + nt * 16 + l16;
                outf[(size_t)m * D_MODEL + n] = acc[mt][nt][reg];
            }
}

// ---------------------------------------------------------------------------
// MFMA flash attention (causal), SINGLE 64-row q-tile per block + 4-way
// kt-SPLIT. Grid (NHEAD, 32, BATCH) = 1024 blocks, 256 thr = 4 waves,
// heavy-first (p = 31 - y). Body is byte-identical to the round-5 verified
// optimum (VGPR=128, no spill); un-pairing doubles grid -> 4 blocks/CU
// (LDS 4x35.3=141<=160 KB; VGPR 4 waves/SIMD x 128 = 512 = pool) = 2x the
// latency-hiding depth. Trade: causal imbalance returns (~+20% slot count,
// mitigated by heavy-first over 4 rounds/CU) for 2x occupancy on a ~60%-
// stalled chain. Rounds 2-4 failed by FORCING occupancy (launch-bounds reg
// cap -> spill) or shrinking tiles (halved intensity); this keeps both.
// ---------------------------------------------------------------------------
__global__ __launch_bounds__(256, 2) void attn_mfma(const unsigned short* __restrict__ Q,
                                                    const unsigned short* __restrict__ K,
                                                    const unsigned short* __restrict__ VT,
                                                    unsigned short* __restrict__ ctx) {
    // Union LDS (35.3 KB): loop: Ps = ushort[4][4096]; combine: R0/R1/Ls.
    __shared__ float CMB[8832];
    const int tid = threadIdx.x;
    const int wave = tid >> 6, lane = tid & 63;
    const int quad = lane >> 4, l16 = lane & 15;
    const int h = blockIdx.x, b = blockIdx.z;
    const int p = 31 - (int)blockIdx.y;  // heavy-first dispatch order
    const int row0 = p * 64;
    const unsigned short* Qp = Q + ((size_t)b * NHEAD + h) * SEQ * HD;
    const unsigned short* Kp = K + ((size_t)b * NHEAD + h) * SEQ * HD;
    const unsigned short* Vp = VT + ((size_t)b * NHEAD + h) * HD * SEQ;
    unsigned short* Pw = (unsigned short*)CMB + wave * 4096;
    const int sw8 = l16 & 7;  // swizzle key (row & 7)

    bf16x8 bQ[4][2];  // Q as B-operand: [q-frag][ks]
#pragma unroll
    for (int f = 0; f < 4; ++f)
#pragma unroll
        for (int ks = 0; ks < 2; ++ks)
            bQ[f][ks] = *(const bf16x8*)(Qp +
                (size_t)(row0 + f * 16 + l16) * HD + ks * 32 + quad * 8);

    f32x4 o[4][4];    // O^T accumulators: [d-tile][q-frag]
    float ps[4] = {0.f, 0.f, 0.f, 0.f};
#pragma unroll
    for (int nt = 0; nt < 4; ++nt)
#pragma unroll
        for (int f = 0; f < 4; ++f)
            o[nt][f] = (f32x4){0.f, 0.f, 0.f, 0.f};

    for (int kt = wave; kt <= p; kt += 4) {
        // ---- K fragments (direct global; no loop barriers) ----
        bf16x8 aK[4][2];
#pragma unroll
        for (int mt = 0; mt < 4; ++mt)
#pragma unroll
            for (int ks = 0; ks < 2; ++ks)
                aK[mt][ks] = *(const bf16x8*)(Kp +
                    (size_t)(kt * 64 + mt * 16 + l16) * HD + ks * 32 + quad * 8);

        // ---- S^T = K Q^T ----
        f32x4 sT[4][4];
        __builtin_amdgcn_s_setprio(1);
#pragma unroll
        for (int mt = 0; mt < 4; ++mt)
#pragma unroll
            for (int f = 0; f < 4; ++f) {
                sT[mt][f] = __builtin_amdgcn_mfma_f32_16x16x32_bf16(
                    aK[mt][0], bQ[f][0], (f32x4){0.f, 0.f, 0.f, 0.f}, 0, 0, 0);
                sT[mt][f] = __builtin_amdgcn_mfma_f32_16x16x32_bf16(
                    aK[mt][1], bQ[f][1], sT[mt][f], 0, 0, 0);
            }
        __builtin_amdgcn_s_setprio(0);

        // ---- V fragments (issued here: latency hides under softmax +
        //      P round-trip; not live during QK^T's sT window) ----
        bf16x8 aV[4][2];
#pragma unroll
        for (int nt = 0; nt < 4; ++nt)
#pragma unroll
            for (int ks = 0; ks < 2; ++ks)
                aV[nt][ks] = *(const bf16x8*)(Vp +
                    (size_t)(nt * 16 + l16) * SEQ + kt * 64 + ks * 32 + quad * 8);

        // ---- exp2 + causal mask (diag tile only) + swizzled P write ----
        const bool diag = (kt == p);
#pragma unroll
        for (int mt = 0; mt < 4; ++mt)
#pragma unroll
            for (int f = 0; f < 4; ++f) {
                float pv[4];
#pragma unroll
                for (int reg = 0; reg < 4; ++reg)
                    pv[reg] = __builtin_amdgcn_exp2f(sT[mt][f][reg]);
                if (diag) {
                    const int kb = kt * 64 + mt * 16 + quad * 4;
                    const int qg = row0 + f * 16 + l16;
#pragma unroll
                    for (int reg = 0; reg < 4; ++reg)
                        pv[reg] = (kb + reg > qg) ? 0.f : pv[reg];
                }
                ps[f] += (pv[0] + pv[1]) + (pv[2] + pv[3]);
                uint2 w;
                w.x = pk2bf(pv[0], pv[1]);
                w.y = pk2bf(pv[2], pv[3]);
                const int gph = ((mt * 2 + (quad >> 1)) ^ sw8);
                *(uint2*)&Pw[(f * 16 + l16) * 64 + gph * 8 + (quad & 1) * 4] = w;
            }

        // ---- P back in B-layout (wave-private; same-wave DS order) ----
        bf16x8 bP[4][2];
#pragma unroll
        for (int f = 0; f < 4; ++f)
#pragma unroll
            for (int ks = 0; ks < 2; ++ks)
                bP[f][ks] = *(const bf16x8*)&Pw[(f * 16 + l16) * 64 +
                                                ((ks * 4 + quad) ^ sw8) * 8];

        // ---- O^T += V^T P^T ----
        __builtin_amdgcn_s_setprio(1);
#pragma unroll
        for (int nt = 0; nt < 4; ++nt)
#pragma unroll
            for (int f = 0; f < 4; ++f) {
                o[nt][f] = __builtin_amdgcn_mfma_f32_16x16x32_bf16(
                    aV[nt][0], bP[f][0], o[nt][f], 0, 0, 0);
                o[nt][f] = __builtin_amdgcn_mfma_f32_16x16x32_bf16(
                    aV[nt][1], bP[f][1], o[nt][f], 0, 0, 0);
            }
        __builtin_amdgcn_s_setprio(0);
    }

#pragma unroll
    for (int f = 0; f < 4; ++f) {
        ps[f] += __shfl_xor(ps[f], 16);
        ps[f] += __shfl_xor(ps[f], 32);
    }

    // ---- cross-wave tree combine: {2,3} -> {0,1} -> 0 ----
    __syncthreads();  // all waves done with Pw (regions overlay it)
    if (wave >= 2) {
        float* Rg = CMB + (wave - 2) * 4352;
#pragma unroll
        for (int nt = 0; nt < 4; ++nt)
#pragma unroll
            for (int f = 0; f < 4; ++f)
                *(f32x4*)&Rg[(f * 16 + l16) * 68 + nt * 16 + quad * 4] = o[nt][f];
        if (quad == 0)
#pragma unroll
            for (int f = 0; f < 4; ++f)
                CMB[8704 + (wave - 2) * 64 + f * 16 + l16] = ps[f];
    }
    __syncthreads();
    if (wave < 2) {
        float* Rg = CMB + wave * 4352;
#pragma unroll
        for (int nt = 0; nt < 4; ++nt)
#pragma unroll
            for (int f = 0; f < 4; ++f)
                o[nt][f] += *(const f32x4*)&Rg[(f * 16 + l16) * 68 + nt * 16 + quad * 4];
#pragma unroll
        for (int f = 0; f < 4; ++f)
            ps[f] += CMB[8704 + wave * 64 + f * 16 + l16];
    }
    __syncthreads();
    if (wave == 1) {
#pragma unroll
        for (int nt = 0; nt < 4; ++nt)
#pragma unroll
            for (int f = 0; f < 4; ++f)
                *(f32x4*)&CMB[(f * 16 + l16) * 68 + nt * 16 + quad * 4] = o[nt][f];
        if (quad == 0)
#pragma unroll
            for (int f = 0; f < 4; ++f)
                CMB[8704 + f * 16 + l16] = ps[f];
    }
    __syncthreads();
    if (wave == 0) {
#pragma unroll
        for (int nt = 0; nt < 4; ++nt)
#pragma unroll
            for (int f = 0; f < 4; ++f)
                o[nt][f] += *(const f32x4*)&CMB[(f * 16 + l16) * 68 + nt * 16 + quad * 4];
        float inv[4];
#pragma unroll
        for (int f = 0; f < 4; ++f)
            inv[f] = 1.f / (ps[f] + CMB[8704 + f * 16 + l16]);
#pragma unroll
        for (int nt = 0; nt < 4; ++nt)
#pragma unroll
            for (int f = 0; f < 4; ++f) {
                const int tok = row0 + f * 16 + l16;
                const int col = h * HD + nt * 16 + quad * 4;
                uint2 w;
                w.x = pk2bf(o[nt][f][0] * inv[f], o[nt][f][1] * inv[f]);
                w.y = pk2bf(o[nt][f][2] * inv[f], o[nt][f][3] * inv[f]);
                *(uint2*)(ctx + ((size_t)b * SEQ + tok) * D_MODEL + col) = w;
            }
    }
}

extern "C" void kernel_launch(void* const* d_in, const int* in_sizes, int n_in,
                              void* d_out, int out_size, void* d_ws, size_t ws_size,
                              hipStream_t stream) {
    const float* x  = (const float*)d_in[0];
    const float* Wq = (const float*)d_in[1];
    const float* Wk = (const float*)d_in[2];
    const float* Wv = (const float*)d_in[3];
    const float* Wo = (const float*)d_in[4];
    float* out = (float*)d_out;

    unsigned short* ws = (unsigned short*)d_ws;
    const size_t T = (size_t)MTOT * D_MODEL;  // 4,194,304 elements
    unsigned short* xb  = ws;                 // [4096,1024] bf16
    unsigned short* Wt  = ws + T;             // 4 x [1024,1024] bf16 (W^T)
    unsigned short* q   = ws + 2 * T;         // [B,H,N,64]  (pre-scaled)
    unsigned short* k   = ws + 3 * T;         // [B,H,N,64]
    unsigned short* vt  = ws + 4 * T;         // [B,H,64,N]
    unsigned short* ctx = ws + 5 * T;         // [4096,1024]

    prep<<<dim3(8192), dim3(256), 0, stream>>>(x, xb, Wq, Wk, Wv, Wo, Wt);

    qkv_mfma<<<dim3(256), dim3(512), 0, stream>>>(xb, Wt, q, k, vt);

    attn_mfma<<<dim3(NHEAD, 32, BATCH), dim3(256), 0, stream>>>(q, k, vt, ctx);

    gemm_out<<<dim3(8, 64), dim3(256), 0, stream>>>(ctx, Wt + 3 * (size_t)D_MODEL * D_MODEL, out);
}

// Round 10
// 174.250 us; speedup vs baseline: 1.9356x; 1.0136x over previous
//
#include <hip/hip_runtime.h>
#include <math.h>

#define D_MODEL 1024
#define NHEAD 16
#define HD 64
#define SEQ 2048
#define BATCH 2
#define MTOT (BATCH * SEQ)  // 4096

typedef __attribute__((ext_vector_type(8))) short bf16x8;
typedef __attribute__((ext_vector_type(4))) float f32x4;

__device__ __forceinline__ unsigned short f2bf(float f) {
    unsigned int u = __float_as_uint(f);
    u += 0x7FFF + ((u >> 16) & 1);  // round-to-nearest-even
    return (unsigned short)(u >> 16);
}

// packed f32x2 -> bf16x2 via HW cvt (RNE, bit-identical to f2bf for normals)
__device__ __forceinline__ unsigned int pk2bf(float a, float b) {
    unsigned int r;
    asm("v_cvt_pk_bf16_f32 %0, %1, %2" : "=v"(r) : "v"(a), "v"(b));
    return r;
}

// async global->LDS, 16B per lane. lds must be the wave-uniform chunk base:
// HW writes lane's 16B to base + lane*16 (guide §5 caveat).
__device__ __forceinline__ void async16(unsigned short* lds, const unsigned short* g) {
    __builtin_amdgcn_global_load_lds(
        (const __attribute__((address_space(1))) unsigned int*)g,
        (__attribute__((address_space(3))) unsigned int*)lds, 16, 0, 0);
}

// raw barrier with compiler memory fence (no vmcnt drain, unlike __syncthreads)
__device__ __forceinline__ void BAR() {
    asm volatile("" ::: "memory");
    __builtin_amdgcn_s_barrier();
    asm volatile("" ::: "memory");
}

// ---------------------------------------------------------------------------
// Fused prep: blocks [0,4096) convert x fp32->bf16; blocks [4096,8192)
// transpose the 4 weights W[k][n] fp32 -> Wt[n][k] bf16.
// ---------------------------------------------------------------------------
__global__ __launch_bounds__(256) void prep(const float* __restrict__ x,
                                            unsigned short* __restrict__ xb,
                                            const float* __restrict__ W0,
                                            const float* __restrict__ W1,
                                            const float* __restrict__ W2,
                                            const float* __restrict__ W3,
                                            unsigned short* __restrict__ Wt) {
    const int bid = blockIdx.x;
    const int tid = threadIdx.x;
    if (bid < 4096) {
        const int i = (bid * 256 + tid) * 4;
        float4 v = *(const float4*)(x + i);
        uint2 pk;
        pk.x = pk2bf(v.x, v.y);
        pk.y = pk2bf(v.z, v.w);
        *(uint2*)(xb + i) = pk;
    } else {
        __shared__ float T[32][33];
        const int t = bid - 4096;
        const int z = t >> 10, rem = t & 1023;
        const int n0 = (rem & 31) * 32, k0 = (rem >> 5) * 32;
        const float* W = (z == 0) ? W0 : (z == 1) ? W1 : (z == 2) ? W2 : W3;
        unsigned short* out = Wt + (size_t)z * D_MODEL * D_MODEL;
        const int tx = tid & 31, ty = tid >> 5;
#pragma unroll
        for (int i = 0; i < 4; ++i)
            T[ty + 8 * i][tx] = W[(size_t)(k0 + ty + 8 * i) * D_MODEL + n0 + tx];
        __syncthreads();
#pragma unroll
        for (int i = 0; i < 4; ++i)
            out[(size_t)(n0 + ty + 8 * i) * D_MODEL + k0 + tx] = f2bf(T[tx][ty + 8 * i]);
    }
}

// ---------------------------------------------------------------------------
// Fused QKV GEMM: 128x192 tile, 8-barrier-per-tile phase rhythm.
// M=4096, N=3072, K=1024. Grid 32x16 = 512 blocks = 2 blocks/CU (the
// 256x192 version was 1 block/CU with zero cross-block overlap — the
// drain was fully exposed; m114 mechanism, same as gemm_out's round-8
// win). 512 thr = 8 waves (2M x 4N), per-wave 64x48 (acc[4][3] = 48 regs,
// half the old pressure). LDS 80 KB double-buffered:
//   per dbuf (ushorts): A ks0 @0, A ks1 @4096, B ks0 @8192, B ks1 @14336;
//   dbuf stride 20480.
// A half-tile = 512 chunks (1/thread); B = 768 (waves 0-3: 2, waves 4-7: 1).
// Counted gates: leave own next-half {A,B} outstanding -> waves 0-3
// vmcnt(3), waves 4-7 vmcnt(2); drain 0 only at the last tile.
// Swizzle: identical algebra (chunk c of row r at slot c ^ ((r+(r>>2))&3)),
// pre-swizzled global source + swizzled read (rule #21).
// Epilogue: 3 x 64-col groups routed per zg (Q/K path or V^T path).
// ---------------------------------------------------------------------------
__global__ __launch_bounds__(512, 2) void qkv_mfma(const unsigned short* __restrict__ A,
                                                   const unsigned short* __restrict__ Wt,
                                                   unsigned short* __restrict__ q,
                                                   unsigned short* __restrict__ k,
                                                   unsigned short* __restrict__ vt) {
    __shared__ unsigned short SM[40960];  // 80 KB
    const int tid = threadIdx.x;
    const int wave = tid >> 6, lane = tid & 63;
    const int quad = lane >> 4, l16 = lane & 15;
    const int wm = wave >> 2, wn = wave & 3;

    // XCD-chunked block swizzle (512 % 8 == 0 -> bijective)
    const int bid = blockIdx.x;
    const int swz = (bid & 7) * 64 + (bid >> 3);
    const int by = swz >> 4, bx = swz & 15;
    const int m0 = by * 128;
    const int c0 = bx * 192;  // column base within [3072]
    const unsigned short* Bz = Wt;  // Wt viewed as one [3072][1024]

    // ---- staging descriptors (source chunk pre-swizzled) ----
    const unsigned short* aptr;
    {
        const int s = tid, r = s >> 2;
        const int cg = (s & 3) ^ ((r + (r >> 2)) & 3);
        aptr = A + (size_t)(m0 + r) * D_MODEL + cg * 8;
    }
    const unsigned short* bptr[2];
#pragma unroll
    for (int j = 0; j < 2; ++j) {
        const int s = j * 512 + tid;
        const int r = s >> 2;
        const int cg = (s & 3) ^ ((r + (r >> 2)) & 3);
        const int rb = (r < 192) ? r : 191;  // j=1 used only by tid<256
        bptr[j] = Bz + (size_t)(c0 + rb) * D_MODEL + cg * 8;
    }
    const int ldsA0 = wave * 512;                 // ushort units
    const int ldsB0 = wave * 512, ldsB1 = 4096 + wave * 512;

    // ---- fragment read offsets (swizzled; key matches staging) ----
    const int key = (l16 + (l16 >> 2)) & 3;
    const int chunk = quad ^ key;
    int aoff[4], boff[3];
#pragma unroll
    for (int mt = 0; mt < 4; ++mt)
        aoff[mt] = ((wm * 64 + mt * 16 + l16) * 4 + chunk) * 8;
#pragma unroll
    for (int nt = 0; nt < 3; ++nt)
        boff[nt] = ((wn * 48 + nt * 16 + l16) * 4 + chunk) * 8;

    f32x4 acc[4][3];
#pragma unroll
    for (int mt = 0; mt < 4; ++mt)
#pragma unroll
        for (int nt = 0; nt < 3; ++nt)
            acc[mt][nt] = (f32x4){0.f, 0.f, 0.f, 0.f};

    auto stageA = [&](int d, int ks, int T) {
        const int base = d * 20480 + ks * 4096;
        async16(SM + base + ldsA0, aptr + T * 64 + ks * 32);
    };
    auto stageB = [&](int d, int ks, int T) {
        const int base = d * 20480 + 8192 + ks * 6144;
        async16(SM + base + ldsB0, bptr[0] + T * 64 + ks * 32);
        if (wave < 4)
            async16(SM + base + ldsB1, bptr[1] + T * 64 + ks * 32);
    };
    auto dsA = [&](bf16x8* af, int mh, int d, int ks) {
        const int base = d * 20480 + ks * 4096;
#pragma unroll
        for (int i = 0; i < 2; ++i)
            af[i] = *(const bf16x8*)&SM[base + aoff[mh * 2 + i]];
    };
    auto dsB = [&](bf16x8* bf, int d, int ks) {
        const int base = d * 20480 + 8192 + ks * 6144;
#pragma unroll
        for (int i = 0; i < 3; ++i)
            bf[i] = *(const bf16x8*)&SM[base + boff[i]];
    };
    auto mfma6 = [&](bf16x8* af, bf16x8* bf, int mh) {
        __builtin_amdgcn_s_setprio(1);
#pragma unroll
        for (int i = 0; i < 2; ++i)
#pragma unroll
            for (int nt = 0; nt < 3; ++nt)
                acc[mh * 2 + i][nt] = __builtin_amdgcn_mfma_f32_16x16x32_bf16(
                    af[i], bf[nt], acc[mh * 2 + i][nt], 0, 0, 0);
        __builtin_amdgcn_s_setprio(0);
    };
    auto waitc = [&](bool nx) {
        if (nx) {
            if (wave < 4) asm volatile("s_waitcnt vmcnt(3)" ::: "memory");
            else          asm volatile("s_waitcnt vmcnt(2)" ::: "memory");
        } else {
            asm volatile("s_waitcnt vmcnt(0)" ::: "memory");
        }
    };

    // ---- prologue: stage tile 0 (A0,B0,A1,B1), retire A0+B0, sync ----
    stageA(0, 0, 0);
    stageB(0, 0, 0);
    stageA(0, 1, 0);
    stageB(0, 1, 0);
    waitc(true);
    BAR();

    const int NT = D_MODEL / 64;  // 16
    for (int T = 0; T < NT; ++T) {
        const int d = T & 1, dn = d ^ 1;
        const bool nx = (T + 1 < NT);
        bf16x8 af[2], bf[3];
        // ph1: reads (mh0,ks0); stage A-half0(T+1); BAR; MFMA; BAR
        dsA(af, 0, d, 0);
        dsB(bf, d, 0);
        if (nx) stageA(dn, 0, T + 1);
        __builtin_amdgcn_sched_barrier(0);
        BAR();
        mfma6(af, bf, 0);
        BAR();
        // ph2: reads (mh1,ks0) reuse bf; stage B-half0(T+1); gate A1,B1(T)
        dsA(af, 1, d, 0);
        if (nx) stageB(dn, 0, T + 1);
        waitc(nx);
        __builtin_amdgcn_sched_barrier(0);
        BAR();
        mfma6(af, bf, 1);
        BAR();
        // ph3: reads (mh0,ks1); stage A-half1(T+1); BAR; MFMA; BAR
        dsA(af, 0, d, 1);
        dsB(bf, d, 1);
        if (nx) stageA(dn, 1, T + 1);
        __builtin_amdgcn_sched_barrier(0);
        BAR();
        mfma6(af, bf, 0);
        BAR();
        // ph4: reads (mh1,ks1); stage B-half1(T+1); gate A0,B0(T+1)
        dsA(af, 1, d, 1);
        if (nx) stageB(dn, 1, T + 1);
        waitc(nx);
        __builtin_amdgcn_sched_barrier(0);
        BAR();
        mfma6(af, bf, 1);
        BAR();
    }

    // ---- epilogue: 3 x 64-col groups; QK path or V^T path per group ----
    __syncthreads();
    const int bb = m0 >> 11, tok0 = m0 & (SEQ - 1);
#pragma unroll 1
    for (int G = 0; G < 3; ++G) {
        if (G) __syncthreads();
        const int gcol = c0 + G * 64;
        const int zg = gcol >> 10;
        const int hg = (gcol >> 6) & 15;
        if (zg < 2) {
            const float sc = (zg == 0) ? 0.18033688011112042f : 1.0f;  // 0.125*log2(e)
            unsigned short* dst = (zg == 0) ? q : k;
            // stage [128 tok][64 d]
#pragma unroll
            for (int nt = 0; nt < 3; ++nt) {
                const int colb = wn * 48 + nt * 16;
                if ((colb >> 6) == G) {
                    const int cl = colb - G * 64 + l16;
#pragma unroll
                    for (int mt = 0; mt < 4; ++mt)
#pragma unroll
                        for (int reg = 0; reg < 4; ++reg) {
                            const int rr = wm * 64 + mt * 16 + quad * 4 + reg;
                            SM[rr * 64 + cl] = f2bf(acc[mt][nt][reg] * sc);
                        }
                }
            }
            __syncthreads();
#pragma unroll
            for (int it = 0; it < 2; ++it) {
                const int g = it * 512 + tid;
                const int r = g >> 3, c8 = g & 7;
                uint4 val = *(const uint4*)&SM[r * 64 + c8 * 8];
                *(uint4*)(dst + (((size_t)bb * NHEAD + hg) * SEQ + tok0 + r) * HD +
                          c8 * 8) = val;
            }
        } else {
            // V^T: stage [64 d][128 tok + pad 8]
#pragma unroll
            for (int nt = 0; nt < 3; ++nt) {
                const int colb = wn * 48 + nt * 16;
                if ((colb >> 6) == G) {
                    const int dl = colb - G * 64 + l16;
#pragma unroll
                    for (int mt = 0; mt < 4; ++mt) {
                        const int m = wm * 64 + mt * 16 + quad * 4;
                        uint2 w;
                        w.x = pk2bf(acc[mt][nt][0], acc[mt][nt][1]);
                        w.y = pk2bf(acc[mt][nt][2], acc[mt][nt][3]);
                        *(uint2*)&SM[dl * 136 + m] = w;
                    }
                }
            }
            __syncthreads();
#pragma unroll
            for (int it = 0; it < 2; ++it) {
                const int g = it * 512 + tid;
                const int dd = g >> 4, t8 = (g & 15) * 8;
                uint4 val = *(const uint4*)&SM[dd * 136 + t8];
                *(uint4*)(vt + (((size_t)bb * NHEAD + hg) * HD + dd) * SEQ + tok0 +
                          t8) = val;
            }
        }
    }
}

// ---------------------------------------------------------------------------
// bf16 MFMA GEMM (output projection only): 64x128 tile, BK=64, 4 waves.
// Grid (8,64) = 512 blocks = 2 blocks/CU (round-8 verified win).
// ---------------------------------------------------------------------------
__global__ __launch_bounds__(256) void gemm_out(const unsigned short* __restrict__ A,
                                                const unsigned short* __restrict__ Bw,
                                                float* __restrict__ outf) {
    __shared__ unsigned short SM[12288];  // As = [0,4096), Bs = [4096,12288)
    const int tid = threadIdx.x;
    const int m0 = blockIdx.y * 64, n0 = blockIdx.x * 128;
    const int wave = tid >> 6, lane = tid & 63;
    const int quad = lane >> 4, l16 = lane & 15;
    const int wm = wave & 1, wn = wave >> 1;  // wave tile: 32 rows x 64 cols

    f32x4 acc[2][4];
#pragma unroll
    for (int mt = 0; mt < 2; ++mt)
#pragma unroll
        for (int nt = 0; nt < 4; ++nt)
            acc[mt][nt] = (f32x4){0.f, 0.f, 0.f, 0.f};

    for (int k0 = 0; k0 < D_MODEL; k0 += 64) {
        __syncthreads();
        // A: 64 rows -> 512 chunks (2/thread); B: 128 rows -> 1024 (4/thread)
#pragma unroll
        for (int i = 0; i < 2; ++i) {
            const int c = i * 256 + tid;
            const int r = c >> 3, cc = (c & 7) * 8;
            const int cbase = i * 256 + wave * 64;  // wave-uniform chunk base
            async16(SM + cbase * 8, A + (size_t)(m0 + r) * D_MODEL + k0 + cc);
        }
#pragma unroll
        for (int i = 0; i < 4; ++i) {
            const int c = i * 256 + tid;
            const int r = c >> 3, cc = (c & 7) * 8;
            const int cbase = i * 256 + wave * 64;
            async16(SM + 4096 + cbase * 8, Bw + (size_t)(n0 + r) * D_MODEL + k0 + cc);
        }
        __syncthreads();
#pragma unroll
        for (int ks = 0; ks < 2; ++ks) {
            bf16x8 af[2], bfr[4];
#pragma unroll
            for (int mt = 0; mt < 2; ++mt)
                af[mt] = *(const bf16x8*)&SM[(wm * 32 + mt * 16 + l16) * 64 + ks * 32 + quad * 8];
#pragma unroll
            for (int nt = 0; nt < 4; ++nt)
                bfr[nt] = *(const bf16x8*)&SM[4096 + (wn * 64 + nt * 16 + l16) * 64 + ks * 32 + quad * 8];
#pragma unroll
            for (int mt = 0; mt < 2; ++mt)
#pragma unroll
                for (int nt = 0; nt < 4; ++nt)
                    acc[mt][nt] = __builtin_amdgcn_mfma_f32_16x16x32_bf16(
                        af[mt], bfr[nt], acc[mt][nt], 0, 0, 0);
        }
    }

#pragma unroll
    for (int mt = 0; mt < 2; ++mt)
#pragma unroll
        for (int nt = 0; nt < 4; ++nt)
#pragma unroll
            for (int reg = 0; reg < 4; ++reg) {
                const int m = m0 + wm * 32 + mt * 16 + quad * 4 + reg;
                const int n = n0 + wn * 64 + nt * 16 + l16;
                outf[(size_t)m * D_MODEL + n] = acc[mt][nt][reg];
            }
}

// ---------------------------------------------------------------------------
// MFMA flash attention (causal), PAIRED q-tiles + 4-way kt-SPLIT.
// ROUND-5 VERIFIED OPTIMUM (45.5 µs) — restored exactly. The un-paired
// 4-blocks/CU variant (round 8) was null: true unified reg usage ~250/wave
// caps residency at 2 waves/SIMD regardless of grid, and un-pairing
// re-introduced causal imbalance. Paired = balanced at the register wall.
// ---------------------------------------------------------------------------
__global__ __launch_bounds__(256, 2) void attn_mfma(const unsigned short* __restrict__ Q,
                                                    const unsigned short* __restrict__ K,
                                                    const unsigned short* __restrict__ VT,
                                                    unsigned short* __restrict__ ctx) {
    // Union LDS (35.3 KB): loop: Ps = ushort[4][4096]; combine: R0/R1/Ls.
    __shared__ float CMB[8832];
    const int tid = threadIdx.x;
    const int wave = tid >> 6, lane = tid & 63;
    const int quad = lane >> 4, l16 = lane & 15;
    const int h = blockIdx.x, b = blockIdx.z;
    const int y = blockIdx.y;
    const unsigned short* Qp = Q + ((size_t)b * NHEAD + h) * SEQ * HD;
    const unsigned short* Kp = K + ((size_t)b * NHEAD + h) * SEQ * HD;
    const unsigned short* Vp = VT + ((size_t)b * NHEAD + h) * HD * SEQ;
    unsigned short* Pw = (unsigned short*)CMB + wave * 4096;
    const int sw8 = l16 & 7;  // swizzle key (row & 7)

#pragma unroll 1
    for (int half = 0; half < 2; ++half) {
        const int p = half ? y : (31 - y);  // heavy tile first
        const int row0 = p * 64;
        if (half) __syncthreads();  // previous combine's LDS reads done

        bf16x8 bQ[4][2];  // Q as B-operand: [q-frag][ks]
#pragma unroll
        for (int f = 0; f < 4; ++f)
#pragma unroll
            for (int ks = 0; ks < 2; ++ks)
                bQ[f][ks] = *(const bf16x8*)(Qp +
                    (size_t)(row0 + f * 16 + l16) * HD + ks * 32 + quad * 8);

        f32x4 o[4][4];    // O^T accumulators: [d-tile][q-frag]
        float ps[4] = {0.f, 0.f, 0.f, 0.f};
#pragma unroll
        for (int nt = 0; nt < 4; ++nt)
#pragma unroll
            for (int f = 0; f < 4; ++f)
                o[nt][f] = (f32x4){0.f, 0.f, 0.f, 0.f};

        for (int kt = wave; kt <= p; kt += 4) {
            // ---- K fragments (direct global; no loop barriers) ----
            bf16x8 aK[4][2];
#pragma unroll
            for (int mt = 0; mt < 4; ++mt)
#pragma unroll
                for (int ks = 0; ks < 2; ++ks)
                    aK[mt][ks] = *(const bf16x8*)(Kp +
                        (size_t)(kt * 64 + mt * 16 + l16) * HD + ks * 32 + quad * 8);

            // ---- S^T = K Q^T ----
            f32x4 sT[4][4];
            __builtin_amdgcn_s_setprio(1);
#pragma unroll
            for (int mt = 0; mt < 4; ++mt)
#pragma unroll
                for (int f = 0; f < 4; ++f) {
                    sT[mt][f] = __builtin_amdgcn_mfma_f32_16x16x32_bf16(
                        aK[mt][0], bQ[f][0], (f32x4){0.f, 0.f, 0.f, 0.f}, 0, 0, 0);
                    sT[mt][f] = __builtin_amdgcn_mfma_f32_16x16x32_bf16(
                        aK[mt][1], bQ[f][1], sT[mt][f], 0, 0, 0);
                }
            __builtin_amdgcn_s_setprio(0);

            // ---- V fragments (issued here: latency hides under softmax +
            //      P round-trip; not live during QK^T's sT window) ----
            bf16x8 aV[4][2];
#pragma unroll
            for (int nt = 0; nt < 4; ++nt)
#pragma unroll
                for (int ks = 0; ks < 2; ++ks)
                    aV[nt][ks] = *(const bf16x8*)(Vp +
                        (size_t)(nt * 16 + l16) * SEQ + kt * 64 + ks * 32 + quad * 8);

            // ---- exp2 + causal mask (diag tile only) + swizzled P write ----
            const bool diag = (kt == p);
#pragma unroll
            for (int mt = 0; mt < 4; ++mt)
#pragma unroll
                for (int f = 0; f < 4; ++f) {
                    float pv[4];
#pragma unroll
                    for (int reg = 0; reg < 4; ++reg)
                        pv[reg] = __builtin_amdgcn_exp2f(sT[mt][f][reg]);
                    if (diag) {
                        const int kb = kt * 64 + mt * 16 + quad * 4;
                        const int qg = row0 + f * 16 + l16;
#pragma unroll
                        for (int reg = 0; reg < 4; ++reg)
                            pv[reg] = (kb + reg > qg) ? 0.f : pv[reg];
                    }
                    ps[f] += (pv[0] + pv[1]) + (pv[2] + pv[3]);
                    uint2 w;
                    w.x = pk2bf(pv[0], pv[1]);
                    w.y = pk2bf(pv[2], pv[3]);
                    const int gph = ((mt * 2 + (quad >> 1)) ^ sw8);
                    *(uint2*)&Pw[(f * 16 + l16) * 64 + gph * 8 + (quad & 1) * 4] = w;
                }

            // ---- P back in B-layout (wave-private; same-wave DS order) ----
            bf16x8 bP[4][2];
#pragma unroll
            for (int f = 0; f < 4; ++f)
#pragma unroll
                for (int ks = 0; ks < 2; ++ks)
                    bP[f][ks] = *(const bf16x8*)&Pw[(f * 16 + l16) * 64 +
                                                    ((ks * 4 + quad) ^ sw8) * 8];

            // ---- O^T += V^T P^T ----
            __builtin_amdgcn_s_setprio(1);
#pragma unroll
            for (int nt = 0; nt < 4; ++nt)
#pragma unroll
                for (int f = 0; f < 4; ++f) {
                    o[nt][f] = __builtin_amdgcn_mfma_f32_16x16x32_bf16(
                        aV[nt][0], bP[f][0], o[nt][f], 0, 0, 0);
                    o[nt][f] = __builtin_amdgcn_mfma_f32_16x16x32_bf16(
                        aV[nt][1], bP[f][1], o[nt][f], 0, 0, 0);
                }
            __builtin_amdgcn_s_setprio(0);
        }

#pragma unroll
        for (int f = 0; f < 4; ++f) {
            ps[f] += __shfl_xor(ps[f], 16);
            ps[f] += __shfl_xor(ps[f], 32);
        }

        // ---- cross-wave tree combine: {2,3} -> {0,1} -> 0 ----
        __syncthreads();  // all waves done with Pw (regions overlay it)
        if (wave >= 2) {
            float* Rg = CMB + (wave - 2) * 4352;
#pragma unroll
            for (int nt = 0; nt < 4; ++nt)
#pragma unroll
                for (int f = 0; f < 4; ++f)
                    *(f32x4*)&Rg[(f * 16 + l16) * 68 + nt * 16 + quad * 4] = o[nt][f];
            if (quad == 0)
#pragma unroll
                for (int f = 0; f < 4; ++f)
                    CMB[8704 + (wave - 2) * 64 + f * 16 + l16] = ps[f];
        }
        __syncthreads();
        if (wave < 2) {
            float* Rg = CMB + wave * 4352;
#pragma unroll
            for (int nt = 0; nt < 4; ++nt)
#pragma unroll
                for (int f = 0; f < 4; ++f)
                    o[nt][f] += *(const f32x4*)&Rg[(f * 16 + l16) * 68 + nt * 16 + quad * 4];
#pragma unroll
            for (int f = 0; f < 4; ++f)
                ps[f] += CMB[8704 + wave * 64 + f * 16 + l16];
        }
        __syncthreads();
        if (wave == 1) {
#pragma unroll
            for (int nt = 0; nt < 4; ++nt)
#pragma unroll
                for (int f = 0; f < 4; ++f)
                    *(f32x4*)&CMB[(f * 16 + l16) * 68 + nt * 16 + quad * 4] = o[nt][f];
            if (quad == 0)
#pragma unroll
                for (int f = 0; f < 4; ++f)
                    CMB[8704 + f * 16 + l16] = ps[f];
        }
        __syncthreads();
        if (wave == 0) {
#pragma unroll
            for (int nt = 0; nt < 4; ++nt)
#pragma unroll
                for (int f = 0; f < 4; ++f)
                    o[nt][f] += *(const f32x4*)&CMB[(f * 16 + l16) * 68 + nt * 16 + quad * 4];
            float inv[4];
#pragma unroll
            for (int f = 0; f < 4; ++f)
                inv[f] = 1.f / (ps[f] + CMB[8704 + f * 16 + l16]);
#pragma unroll
            for (int nt = 0; nt < 4; ++nt)
#pragma unroll
                for (int f = 0; f < 4; ++f) {
                    const int tok = row0 + f * 16 + l16;
                    const int col = h * HD + nt * 16 + quad * 4;
                    uint2 w;
                    w.x = pk2bf(o[nt][f][0] * inv[f], o[nt][f][1] * inv[f]);
                    w.y = pk2bf(o[nt][f][2] * inv[f], o[nt][f][3] * inv[f]);
                    *(uint2*)(ctx + ((size_t)b * SEQ + tok) * D_MODEL + col) = w;
                }
        }
    }
}

extern "C" void kernel_launch(void* const* d_in, const int* in_sizes, int n_in,
                              void* d_out, int out_size, void* d_ws, size_t ws_size,
                              hipStream_t stream) {
    const float* x  = (const float*)d_in[0];
    const float* Wq = (const float*)d_in[1];
    const float* Wk = (const float*)d_in[2];
    const float* Wv = (const float*)d_in[3];
    const float* Wo = (const float*)d_in[4];
    float* out = (float*)d_out;

    unsigned short* ws = (unsigned short*)d_ws;
    const size_t T = (size_t)MTOT * D_MODEL;  // 4,194,304 elements
    unsigned short* xb  = ws;                 // [4096,1024] bf16
    unsigned short* Wt  = ws + T;             // 4 x [1024,1024] bf16 (W^T)
    unsigned short* q   = ws + 2 * T;         // [B,H,N,64]  (pre-scaled)
    unsigned short* k   = ws + 3 * T;         // [B,H,N,64]
    unsigned short* vt  = ws + 4 * T;         // [B,H,64,N]
    unsigned short* ctx = ws + 5 * T;         // [4096,1024]

    prep<<<dim3(8192), dim3(256), 0, stream>>>(x, xb, Wq, Wk, Wv, Wo, Wt);

    qkv_mfma<<<dim3(512), dim3(512), 0, stream>>>(xb, Wt, q, k, vt);

    attn_mfma<<<dim3(NHEAD, 16, BATCH), dim3(256), 0, stream>>>(q, k, vt, ctx);

    gemm_out<<<dim3(8, 64), dim3(256), 0, stream>>>(ctx, Wt + 3 * (size_t)D_MODEL * D_MODEL, out);
}

// Round 11
// 169.951 us; speedup vs baseline: 1.9846x; 1.0253x over previous
//
#include <hip/hip_runtime.h>
#include <math.h>

#define D_MODEL 1024
#define NHEAD 16
#define HD 64
#define SEQ 2048
#define BATCH 2
#define MTOT (BATCH * SEQ)  // 4096

typedef __attribute__((ext_vector_type(8))) short bf16x8;
typedef __attribute__((ext_vector_type(4))) float f32x4;

__device__ __forceinline__ unsigned short f2bf(float f) {
    unsigned int u = __float_as_uint(f);
    u += 0x7FFF + ((u >> 16) & 1);  // round-to-nearest-even
    return (unsigned short)(u >> 16);
}

// packed f32x2 -> bf16x2 via HW cvt (RNE, bit-identical to f2bf for normals)
__device__ __forceinline__ unsigned int pk2bf(float a, float b) {
    unsigned int r;
    asm("v_cvt_pk_bf16_f32 %0, %1, %2" : "=v"(r) : "v"(a), "v"(b));
    return r;
}

// async global->LDS, 16B per lane. lds must be the wave-uniform chunk base:
// HW writes lane's 16B to base + lane*16 (guide §5 caveat).
__device__ __forceinline__ void async16(unsigned short* lds, const unsigned short* g) {
    __builtin_amdgcn_global_load_lds(
        (const __attribute__((address_space(1))) unsigned int*)g,
        (__attribute__((address_space(3))) unsigned int*)lds, 16, 0, 0);
}

// raw barrier with compiler memory fence (no vmcnt drain, unlike __syncthreads)
__device__ __forceinline__ void BAR() {
    asm volatile("" ::: "memory");
    __builtin_amdgcn_s_barrier();
    asm volatile("" ::: "memory");
}

// ---------------------------------------------------------------------------
// Fused prep: blocks [0,4096) convert x fp32->bf16; blocks [4096,8192)
// transpose the 4 weights W[k][n] fp32 -> Wt[n][k] bf16.
// ---------------------------------------------------------------------------
__global__ __launch_bounds__(256) void prep(const float* __restrict__ x,
                                            unsigned short* __restrict__ xb,
                                            const float* __restrict__ W0,
                                            const float* __restrict__ W1,
                                            const float* __restrict__ W2,
                                            const float* __restrict__ W3,
                                            unsigned short* __restrict__ Wt) {
    const int bid = blockIdx.x;
    const int tid = threadIdx.x;
    if (bid < 4096) {
        const int i = (bid * 256 + tid) * 4;
        float4 v = *(const float4*)(x + i);
        uint2 pk;
        pk.x = pk2bf(v.x, v.y);
        pk.y = pk2bf(v.z, v.w);
        *(uint2*)(xb + i) = pk;
    } else {
        __shared__ float T[32][33];
        const int t = bid - 4096;
        const int z = t >> 10, rem = t & 1023;
        const int n0 = (rem & 31) * 32, k0 = (rem >> 5) * 32;
        const float* W = (z == 0) ? W0 : (z == 1) ? W1 : (z == 2) ? W2 : W3;
        unsigned short* out = Wt + (size_t)z * D_MODEL * D_MODEL;
        const int tx = tid & 31, ty = tid >> 5;
#pragma unroll
        for (int i = 0; i < 4; ++i)
            T[ty + 8 * i][tx] = W[(size_t)(k0 + ty + 8 * i) * D_MODEL + n0 + tx];
        __syncthreads();
#pragma unroll
        for (int i = 0; i < 4; ++i)
            out[(size_t)(n0 + ty + 8 * i) * D_MODEL + k0 + tx] = f2bf(T[tx][ty + 8 * i]);
    }
}

// ---------------------------------------------------------------------------
// Fused QKV GEMM: 128x192 tile, 8-barrier-per-tile phase rhythm.
// (Round-9 verified.) Grid 32x16 = 512 blocks = 2 blocks/CU, 512 thr.
// ---------------------------------------------------------------------------
__global__ __launch_bounds__(512, 2) void qkv_mfma(const unsigned short* __restrict__ A,
                                                   const unsigned short* __restrict__ Wt,
                                                   unsigned short* __restrict__ q,
                                                   unsigned short* __restrict__ k,
                                                   unsigned short* __restrict__ vt) {
    __shared__ unsigned short SM[40960];  // 80 KB
    const int tid = threadIdx.x;
    const int wave = tid >> 6, lane = tid & 63;
    const int quad = lane >> 4, l16 = lane & 15;
    const int wm = wave >> 2, wn = wave & 3;

    // XCD-chunked block swizzle (512 % 8 == 0 -> bijective)
    const int bid = blockIdx.x;
    const int swz = (bid & 7) * 64 + (bid >> 3);
    const int by = swz >> 4, bx = swz & 15;
    const int m0 = by * 128;
    const int c0 = bx * 192;  // column base within [3072]
    const unsigned short* Bz = Wt;  // Wt viewed as one [3072][1024]

    // ---- staging descriptors (source chunk pre-swizzled) ----
    const unsigned short* aptr;
    {
        const int s = tid, r = s >> 2;
        const int cg = (s & 3) ^ ((r + (r >> 2)) & 3);
        aptr = A + (size_t)(m0 + r) * D_MODEL + cg * 8;
    }
    const unsigned short* bptr[2];
#pragma unroll
    for (int j = 0; j < 2; ++j) {
        const int s = j * 512 + tid;
        const int r = s >> 2;
        const int cg = (s & 3) ^ ((r + (r >> 2)) & 3);
        const int rb = (r < 192) ? r : 191;  // j=1 used only by tid<256
        bptr[j] = Bz + (size_t)(c0 + rb) * D_MODEL + cg * 8;
    }
    const int ldsA0 = wave * 512;                 // ushort units
    const int ldsB0 = wave * 512, ldsB1 = 4096 + wave * 512;

    // ---- fragment read offsets (swizzled; key matches staging) ----
    const int key = (l16 + (l16 >> 2)) & 3;
    const int chunk = quad ^ key;
    int aoff[4], boff[3];
#pragma unroll
    for (int mt = 0; mt < 4; ++mt)
        aoff[mt] = ((wm * 64 + mt * 16 + l16) * 4 + chunk) * 8;
#pragma unroll
    for (int nt = 0; nt < 3; ++nt)
        boff[nt] = ((wn * 48 + nt * 16 + l16) * 4 + chunk) * 8;

    f32x4 acc[4][3];
#pragma unroll
    for (int mt = 0; mt < 4; ++mt)
#pragma unroll
        for (int nt = 0; nt < 3; ++nt)
            acc[mt][nt] = (f32x4){0.f, 0.f, 0.f, 0.f};

    auto stageA = [&](int d, int ks, int T) {
        const int base = d * 20480 + ks * 4096;
        async16(SM + base + ldsA0, aptr + T * 64 + ks * 32);
    };
    auto stageB = [&](int d, int ks, int T) {
        const int base = d * 20480 + 8192 + ks * 6144;
        async16(SM + base + ldsB0, bptr[0] + T * 64 + ks * 32);
        if (wave < 4)
            async16(SM + base + ldsB1, bptr[1] + T * 64 + ks * 32);
    };
    auto dsA = [&](bf16x8* af, int mh, int d, int ks) {
        const int base = d * 20480 + ks * 4096;
#pragma unroll
        for (int i = 0; i < 2; ++i)
            af[i] = *(const bf16x8*)&SM[base + aoff[mh * 2 + i]];
    };
    auto dsB = [&](bf16x8* bf, int d, int ks) {
        const int base = d * 20480 + 8192 + ks * 6144;
#pragma unroll
        for (int i = 0; i < 3; ++i)
            bf[i] = *(const bf16x8*)&SM[base + boff[i]];
    };
    auto mfma6 = [&](bf16x8* af, bf16x8* bf, int mh) {
        __builtin_amdgcn_s_setprio(1);
#pragma unroll
        for (int i = 0; i < 2; ++i)
#pragma unroll
            for (int nt = 0; nt < 3; ++nt)
                acc[mh * 2 + i][nt] = __builtin_amdgcn_mfma_f32_16x16x32_bf16(
                    af[i], bf[nt], acc[mh * 2 + i][nt], 0, 0, 0);
        __builtin_amdgcn_s_setprio(0);
    };
    auto waitc = [&](bool nx) {
        if (nx) {
            if (wave < 4) asm volatile("s_waitcnt vmcnt(3)" ::: "memory");
            else          asm volatile("s_waitcnt vmcnt(2)" ::: "memory");
        } else {
            asm volatile("s_waitcnt vmcnt(0)" ::: "memory");
        }
    };

    // ---- prologue: stage tile 0 (A0,B0,A1,B1), retire A0+B0, sync ----
    stageA(0, 0, 0);
    stageB(0, 0, 0);
    stageA(0, 1, 0);
    stageB(0, 1, 0);
    waitc(true);
    BAR();

    const int NT = D_MODEL / 64;  // 16
    for (int T = 0; T < NT; ++T) {
        const int d = T & 1, dn = d ^ 1;
        const bool nx = (T + 1 < NT);
        bf16x8 af[2], bf[3];
        // ph1: reads (mh0,ks0); stage A-half0(T+1); BAR; MFMA; BAR
        dsA(af, 0, d, 0);
        dsB(bf, d, 0);
        if (nx) stageA(dn, 0, T + 1);
        __builtin_amdgcn_sched_barrier(0);
        BAR();
        mfma6(af, bf, 0);
        BAR();
        // ph2: reads (mh1,ks0) reuse bf; stage B-half0(T+1); gate A1,B1(T)
        dsA(af, 1, d, 0);
        if (nx) stageB(dn, 0, T + 1);
        waitc(nx);
        __builtin_amdgcn_sched_barrier(0);
        BAR();
        mfma6(af, bf, 1);
        BAR();
        // ph3: reads (mh0,ks1); stage A-half1(T+1); BAR; MFMA; BAR
        dsA(af, 0, d, 1);
        dsB(bf, d, 1);
        if (nx) stageA(dn, 1, T + 1);
        __builtin_amdgcn_sched_barrier(0);
        BAR();
        mfma6(af, bf, 0);
        BAR();
        // ph4: reads (mh1,ks1); stage B-half1(T+1); gate A0,B0(T+1)
        dsA(af, 1, d, 1);
        if (nx) stageB(dn, 1, T + 1);
        waitc(nx);
        __builtin_amdgcn_sched_barrier(0);
        BAR();
        mfma6(af, bf, 1);
        BAR();
    }

    // ---- epilogue: 3 x 64-col groups; QK path or V^T path per group ----
    __syncthreads();
    const int bb = m0 >> 11, tok0 = m0 & (SEQ - 1);
#pragma unroll 1
    for (int G = 0; G < 3; ++G) {
        if (G) __syncthreads();
        const int gcol = c0 + G * 64;
        const int zg = gcol >> 10;
        const int hg = (gcol >> 6) & 15;
        if (zg < 2) {
            const float sc = (zg == 0) ? 0.18033688011112042f : 1.0f;  // 0.125*log2(e)
            unsigned short* dst = (zg == 0) ? q : k;
            // stage [128 tok][64 d]
#pragma unroll
            for (int nt = 0; nt < 3; ++nt) {
                const int colb = wn * 48 + nt * 16;
                if ((colb >> 6) == G) {
                    const int cl = colb - G * 64 + l16;
#pragma unroll
                    for (int mt = 0; mt < 4; ++mt)
#pragma unroll
                        for (int reg = 0; reg < 4; ++reg) {
                            const int rr = wm * 64 + mt * 16 + quad * 4 + reg;
                            SM[rr * 64 + cl] = f2bf(acc[mt][nt][reg] * sc);
                        }
                }
            }
            __syncthreads();
#pragma unroll
            for (int it = 0; it < 2; ++it) {
                const int g = it * 512 + tid;
                const int r = g >> 3, c8 = g & 7;
                uint4 val = *(const uint4*)&SM[r * 64 + c8 * 8];
                *(uint4*)(dst + (((size_t)bb * NHEAD + hg) * SEQ + tok0 + r) * HD +
                          c8 * 8) = val;
            }
        } else {
            // V^T: stage [64 d][128 tok + pad 8]
#pragma unroll
            for (int nt = 0; nt < 3; ++nt) {
                const int colb = wn * 48 + nt * 16;
                if ((colb >> 6) == G) {
                    const int dl = colb - G * 64 + l16;
#pragma unroll
                    for (int mt = 0; mt < 4; ++mt) {
                        const int m = wm * 64 + mt * 16 + quad * 4;
                        uint2 w;
                        w.x = pk2bf(acc[mt][nt][0], acc[mt][nt][1]);
                        w.y = pk2bf(acc[mt][nt][2], acc[mt][nt][3]);
                        *(uint2*)&SM[dl * 136 + m] = w;
                    }
                }
            }
            __syncthreads();
#pragma unroll
            for (int it = 0; it < 2; ++it) {
                const int g = it * 512 + tid;
                const int dd = g >> 4, t8 = (g & 15) * 8;
                uint4 val = *(const uint4*)&SM[dd * 136 + t8];
                *(uint4*)(vt + (((size_t)bb * NHEAD + hg) * HD + dd) * SEQ + tok0 +
                          t8) = val;
            }
        }
    }
}

// ---------------------------------------------------------------------------
// bf16 MFMA GEMM (output projection only): 64x128 tile, BK=64, 4 waves.
// Grid (8,64) = 512 blocks = 2 blocks/CU (round-8 verified win).
// ---------------------------------------------------------------------------
__global__ __launch_bounds__(256) void gemm_out(const unsigned short* __restrict__ A,
                                                const unsigned short* __restrict__ Bw,
                                                float* __restrict__ outf) {
    __shared__ unsigned short SM[12288];  // As = [0,4096), Bs = [4096,12288)
    const int tid = threadIdx.x;
    const int m0 = blockIdx.y * 64, n0 = blockIdx.x * 128;
    const int wave = tid >> 6, lane = tid & 63;
    const int quad = lane >> 4, l16 = lane & 15;
    const int wm = wave & 1, wn = wave >> 1;  // wave tile: 32 rows x 64 cols

    f32x4 acc[2][4];
#pragma unroll
    for (int mt = 0; mt < 2; ++mt)
#pragma unroll
        for (int nt = 0; nt < 4; ++nt)
            acc[mt][nt] = (f32x4){0.f, 0.f, 0.f, 0.f};

    for (int k0 = 0; k0 < D_MODEL; k0 += 64) {
        __syncthreads();
        // A: 64 rows -> 512 chunks (2/thread); B: 128 rows -> 1024 (4/thread)
#pragma unroll
        for (int i = 0; i < 2; ++i) {
            const int c = i * 256 + tid;
            const int r = c >> 3, cc = (c & 7) * 8;
            const int cbase = i * 256 + wave * 64;  // wave-uniform chunk base
            async16(SM + cbase * 8, A + (size_t)(m0 + r) * D_MODEL + k0 + cc);
        }
#pragma unroll
        for (int i = 0; i < 4; ++i) {
            const int c = i * 256 + tid;
            const int r = c >> 3, cc = (c & 7) * 8;
            const int cbase = i * 256 + wave * 64;
            async16(SM + 4096 + cbase * 8, Bw + (size_t)(n0 + r) * D_MODEL + k0 + cc);
        }
        __syncthreads();
#pragma unroll
        for (int ks = 0; ks < 2; ++ks) {
            bf16x8 af[2], bfr[4];
#pragma unroll
            for (int mt = 0; mt < 2; ++mt)
                af[mt] = *(const bf16x8*)&SM[(wm * 32 + mt * 16 + l16) * 64 + ks * 32 + quad * 8];
#pragma unroll
            for (int nt = 0; nt < 4; ++nt)
                bfr[nt] = *(const bf16x8*)&SM[4096 + (wn * 64 + nt * 16 + l16) * 64 + ks * 32 + quad * 8];
#pragma unroll
            for (int mt = 0; mt < 2; ++mt)
#pragma unroll
                for (int nt = 0; nt < 4; ++nt)
                    acc[mt][nt] = __builtin_amdgcn_mfma_f32_16x16x32_bf16(
                        af[mt], bfr[nt], acc[mt][nt], 0, 0, 0);
        }
    }

#pragma unroll
    for (int mt = 0; mt < 2; ++mt)
#pragma unroll
        for (int nt = 0; nt < 4; ++nt)
#pragma unroll
            for (int reg = 0; reg < 4; ++reg) {
                const int m = m0 + wm * 32 + mt * 16 + quad * 4 + reg;
                const int n = n0 + wn * 64 + nt * 16 + l16;
                outf[(size_t)m * D_MODEL + n] = acc[mt][nt][reg];
            }
}

// ---------------------------------------------------------------------------
// MFMA flash attention (causal), Q-SPLIT restructure: each of 4 waves owns
// 16 q-rows; all waves march over the SAME kt tiles. K/V tiles are
// block-shared, staged via global_load_lds into 2x8KB double buffers with
// XOR swizzle (pre-swizzled source + swizzled ds_read, rule #21; 2-way
// banks = free). One barrier + vmcnt(0) per kt (stage targets the other
// buffer; issue right after aK reads so loads land under softmax+PV).
// Per-wave state collapses (o[4]=16, sT[4]=16, bQ=8, ~100 regs) ->
// launch_bounds(256,4) caps at 128 WITHOUT spill (unlike the 64-row body,
// rounds 2-4). No cross-wave combine (each wave owns its rows end-to-end).
// LDS 40KB -> 4 blocks/CU; grid (16,32,2)=1024 heavy-first -> 4 waves/SIMD.
// ---------------------------------------------------------------------------
__global__ __launch_bounds__(256, 4) void attn_mfma(const unsigned short* __restrict__ Q,
                                                    const unsigned short* __restrict__ K,
                                                    const unsigned short* __restrict__ VT,
                                                    unsigned short* __restrict__ ctx) {
    // LDS (ushorts): K dbuf [0,4096)+[4096,8192); V dbuf [8192,12288)+
    // [12288,16384); P [16384,20480) = 4 waves x 1024 (16 q x 64 k).
    __shared__ unsigned short SM[20480];  // 40 KB
    const int tid = threadIdx.x;
    const int wave = tid >> 6, lane = tid & 63;
    const int quad = lane >> 4, l16 = lane & 15;
    const int h = blockIdx.x, b = blockIdx.z;
    const int p = 31 - (int)blockIdx.y;  // heavy-first
    const int row0 = p * 64;
    const int qrow = row0 + wave * 16 + l16;  // this lane's q-row
    const unsigned short* Qp = Q + ((size_t)b * NHEAD + h) * SEQ * HD;
    const unsigned short* Kp = K + ((size_t)b * NHEAD + h) * SEQ * HD;
    const unsigned short* Vp = VT + ((size_t)b * NHEAD + h) * HD * SEQ;
    unsigned short* Pw = SM + 16384 + wave * 1024;
    const int sw8 = l16 & 7;  // swizzle key (row & 7)

    // ---- staging descriptors: chunk c = j*256+tid covers LDS row r=c>>3,
    //      slot s=c&7; source holds global slot s^(r&7) (pre-swizzle) ----
    const unsigned short* kptr[2];
    const unsigned short* vptr[2];
    int ldsoff[2];
#pragma unroll
    for (int j = 0; j < 2; ++j) {
        const int c = j * 256 + tid;
        const int r = c >> 3, s = c & 7;
        const int sg = (s ^ (r & 7)) * 8;
        kptr[j] = Kp + (size_t)r * HD + sg;   // + kt*64*HD per tile
        vptr[j] = Vp + (size_t)r * SEQ + sg;  // + kt*64 per tile
        ldsoff[j] = (j * 256 + wave * 64) * 8;  // wave-uniform chunk base
    }
    auto stageKV = [&](int d, int kt) {
        const int kb = d * 4096, vb = 8192 + d * 4096;
#pragma unroll
        for (int j = 0; j < 2; ++j) {
            async16(SM + kb + ldsoff[j], kptr[j] + (size_t)kt * 64 * HD);
            async16(SM + vb + ldsoff[j], vptr[j] + kt * 64);
        }
    };

    // ---- Q fragment (one 16-row block per wave) ----
    bf16x8 bQ[2];
#pragma unroll
    for (int ks = 0; ks < 2; ++ks)
        bQ[ks] = *(const bf16x8*)(Qp + (size_t)qrow * HD + ks * 32 + quad * 8);

    f32x4 o[4];  // O^T accumulators: [d-tile]; lane value (d=nt*16+quad*4+reg, q=l16)
    float ps = 0.f;
#pragma unroll
    for (int nt = 0; nt < 4; ++nt)
        o[nt] = (f32x4){0.f, 0.f, 0.f, 0.f};

    // ---- prologue: stage tile 0 (vmcnt also covers the bQ loads) ----
    stageKV(0, 0);
    asm volatile("s_waitcnt vmcnt(0)" ::: "memory");
    BAR();

    for (int kt = 0; kt <= p; ++kt) {
        const int cur = kt & 1;
        const int kbase = cur * 4096, vbase = 8192 + cur * 4096;

        // ---- aK from shared K tile (swizzled ds_read_b128, 2-way free) ----
        bf16x8 aK[4][2];
#pragma unroll
        for (int mt = 0; mt < 4; ++mt)
#pragma unroll
            for (int ks = 0; ks < 2; ++ks)
                aK[mt][ks] = *(const bf16x8*)&SM[kbase + (mt * 16 + l16) * 64 +
                                                 (((ks * 4 + quad)) ^ sw8) * 8];

        // ---- issue next tile's staging early (lands under softmax+PV) ----
        if (kt < p) stageKV(cur ^ 1, kt + 1);

        // ---- S^T = K Q^T (m = k-row, n = q-row) ----
        f32x4 sT[4];
        __builtin_amdgcn_s_setprio(1);
#pragma unroll
        for (int mt = 0; mt < 4; ++mt) {
            sT[mt] = __builtin_amdgcn_mfma_f32_16x16x32_bf16(
                aK[mt][0], bQ[0], (f32x4){0.f, 0.f, 0.f, 0.f}, 0, 0, 0);
            sT[mt] = __builtin_amdgcn_mfma_f32_16x16x32_bf16(
                aK[mt][1], bQ[1], sT[mt], 0, 0, 0);
        }
        __builtin_amdgcn_s_setprio(0);

        // ---- exp2 + causal mask (diag tile only) + swizzled P write ----
        const bool diag = (kt == p);
#pragma unroll
        for (int mt = 0; mt < 4; ++mt) {
            float pv[4];
#pragma unroll
            for (int reg = 0; reg < 4; ++reg)
                pv[reg] = __builtin_amdgcn_exp2f(sT[mt][reg]);
            if (diag) {
                const int kb = kt * 64 + mt * 16 + quad * 4;
#pragma unroll
                for (int reg = 0; reg < 4; ++reg)
                    pv[reg] = (kb + reg > qrow) ? 0.f : pv[reg];
            }
            ps += (pv[0] + pv[1]) + (pv[2] + pv[3]);
            uint2 w;
            w.x = pk2bf(pv[0], pv[1]);
            w.y = pk2bf(pv[2], pv[3]);
            const int gph = ((mt * 2 + (quad >> 1)) ^ sw8);
            *(uint2*)&Pw[l16 * 64 + gph * 8 + (quad & 1) * 4] = w;
        }

        // ---- P back in B-layout (wave-private; same-wave DS order) ----
        bf16x8 bP[2];
#pragma unroll
        for (int ks = 0; ks < 2; ++ks)
            bP[ks] = *(const bf16x8*)&Pw[l16 * 64 + ((ks * 4 + quad) ^ sw8) * 8];

        // ---- aV from shared V tile + O^T += V^T P^T ----
        bf16x8 aV[4][2];
#pragma unroll
        for (int nt = 0; nt < 4; ++nt)
#pragma unroll
            for (int ks = 0; ks < 2; ++ks)
                aV[nt][ks] = *(const bf16x8*)&SM[vbase + (nt * 16 + l16) * 64 +
                                                 (((ks * 4 + quad)) ^ sw8) * 8];
        __builtin_amdgcn_s_setprio(1);
#pragma unroll
        for (int nt = 0; nt < 4; ++nt) {
            o[nt] = __builtin_amdgcn_mfma_f32_16x16x32_bf16(
                aV[nt][0], bP[0], o[nt], 0, 0, 0);
            o[nt] = __builtin_amdgcn_mfma_f32_16x16x32_bf16(
                aV[nt][1], bP[1], o[nt], 0, 0, 0);
        }
        __builtin_amdgcn_s_setprio(0);

        // ---- next tile staged + all waves done with cur ----
        asm volatile("s_waitcnt vmcnt(0)" ::: "memory");
        BAR();
    }

    // ---- row-sum reduce across quads (q lives in l16; partials in quads) --
    ps += __shfl_xor(ps, 16);
    ps += __shfl_xor(ps, 32);
    const float inv = 1.f / ps;

    // ---- direct store (no cross-wave combine: each wave owns its rows) ----
#pragma unroll
    for (int nt = 0; nt < 4; ++nt) {
        const int col = h * HD + nt * 16 + quad * 4;
        uint2 w;
        w.x = pk2bf(o[nt][0] * inv, o[nt][1] * inv);
        w.y = pk2bf(o[nt][2] * inv, o[nt][3] * inv);
        *(uint2*)(ctx + ((size_t)b * SEQ + qrow) * D_MODEL + col) = w;
    }
}

extern "C" void kernel_launch(void* const* d_in, const int* in_sizes, int n_in,
                              void* d_out, int out_size, void* d_ws, size_t ws_size,
                              hipStream_t stream) {
    const float* x  = (const float*)d_in[0];
    const float* Wq = (const float*)d_in[1];
    const float* Wk = (const float*)d_in[2];
    const float* Wv = (const float*)d_in[3];
    const float* Wo = (const float*)d_in[4];
    float* out = (float*)d_out;

    unsigned short* ws = (unsigned short*)d_ws;
    const size_t T = (size_t)MTOT * D_MODEL;  // 4,194,304 elements
    unsigned short* xb  = ws;                 // [4096,1024] bf16
    unsigned short* Wt  = ws + T;             // 4 x [1024,1024] bf16 (W^T)
    unsigned short* q   = ws + 2 * T;         // [B,H,N,64]  (pre-scaled)
    unsigned short* k   = ws + 3 * T;         // [B,H,N,64]
    unsigned short* vt  = ws + 4 * T;         // [B,H,64,N]
    unsigned short* ctx = ws + 5 * T;         // [4096,1024]

    prep<<<dim3(8192), dim3(256), 0, stream>>>(x, xb, Wq, Wk, Wv, Wo, Wt);

    qkv_mfma<<<dim3(512), dim3(512), 0, stream>>>(xb, Wt, q, k, vt);

    attn_mfma<<<dim3(NHEAD, 32, BATCH), dim3(256), 0, stream>>>(q, k, vt, ctx);

    gemm_out<<<dim3(8, 64), dim3(256), 0, stream>>>(ctx, Wt + 3 * (size_t)D_MODEL * D_MODEL, out);
}

// Round 12
// 165.697 us; speedup vs baseline: 2.0355x; 1.0257x over previous
//
#include <hip/hip_runtime.h>
#include <math.h>

#define D_MODEL 1024
#define NHEAD 16
#define HD 64
#define SEQ 2048
#define BATCH 2
#define MTOT (BATCH * SEQ)  // 4096

typedef __attribute__((ext_vector_type(8))) short bf16x8;
typedef __attribute__((ext_vector_type(4))) float f32x4;

__device__ __forceinline__ unsigned short f2bf(float f) {
    unsigned int u = __float_as_uint(f);
    u += 0x7FFF + ((u >> 16) & 1);  // round-to-nearest-even
    return (unsigned short)(u >> 16);
}

// packed f32x2 -> bf16x2 via HW cvt (RNE, bit-identical to f2bf for normals)
__device__ __forceinline__ unsigned int pk2bf(float a, float b) {
    unsigned int r;
    asm("v_cvt_pk_bf16_f32 %0, %1, %2" : "=v"(r) : "v"(a), "v"(b));
    return r;
}

// async global->LDS, 16B per lane. lds must be the wave-uniform chunk base:
// HW writes lane's 16B to base + lane*16 (guide §5 caveat).
__device__ __forceinline__ void async16(unsigned short* lds, const unsigned short* g) {
    __builtin_amdgcn_global_load_lds(
        (const __attribute__((address_space(1))) unsigned int*)g,
        (__attribute__((address_space(3))) unsigned int*)lds, 16, 0, 0);
}

// raw barrier with compiler memory fence (no vmcnt drain, unlike __syncthreads)
__device__ __forceinline__ void BAR() {
    asm volatile("" ::: "memory");
    __builtin_amdgcn_s_barrier();
    asm volatile("" ::: "memory");
}

// ---------------------------------------------------------------------------
// Fused prep: blocks [0,4096) convert x fp32->bf16; blocks [4096,8192)
// transpose the 4 weights W[k][n] fp32 -> Wt[n][k] bf16.
// ---------------------------------------------------------------------------
__global__ __launch_bounds__(256) void prep(const float* __restrict__ x,
                                            unsigned short* __restrict__ xb,
                                            const float* __restrict__ W0,
                                            const float* __restrict__ W1,
                                            const float* __restrict__ W2,
                                            const float* __restrict__ W3,
                                            unsigned short* __restrict__ Wt) {
    const int bid = blockIdx.x;
    const int tid = threadIdx.x;
    if (bid < 4096) {
        const int i = (bid * 256 + tid) * 4;
        float4 v = *(const float4*)(x + i);
        uint2 pk;
        pk.x = pk2bf(v.x, v.y);
        pk.y = pk2bf(v.z, v.w);
        *(uint2*)(xb + i) = pk;
    } else {
        __shared__ float T[32][33];
        const int t = bid - 4096;
        const int z = t >> 10, rem = t & 1023;
        const int n0 = (rem & 31) * 32, k0 = (rem >> 5) * 32;
        const float* W = (z == 0) ? W0 : (z == 1) ? W1 : (z == 2) ? W2 : W3;
        unsigned short* out = Wt + (size_t)z * D_MODEL * D_MODEL;
        const int tx = tid & 31, ty = tid >> 5;
#pragma unroll
        for (int i = 0; i < 4; ++i)
            T[ty + 8 * i][tx] = W[(size_t)(k0 + ty + 8 * i) * D_MODEL + n0 + tx];
        __syncthreads();
#pragma unroll
        for (int i = 0; i < 4; ++i)
            out[(size_t)(n0 + ty + 8 * i) * D_MODEL + k0 + tx] = f2bf(T[tx][ty + 8 * i]);
    }
}

// ---------------------------------------------------------------------------
// Fused QKV GEMM: 128x192 tile, 8-barrier-per-tile phase rhythm.
// (Round-9 verified.) Grid 32x16 = 512 blocks = 2 blocks/CU, 512 thr.
// ---------------------------------------------------------------------------
__global__ __launch_bounds__(512, 2) void qkv_mfma(const unsigned short* __restrict__ A,
                                                   const unsigned short* __restrict__ Wt,
                                                   unsigned short* __restrict__ q,
                                                   unsigned short* __restrict__ k,
                                                   unsigned short* __restrict__ vt) {
    __shared__ unsigned short SM[40960];  // 80 KB
    const int tid = threadIdx.x;
    const int wave = tid >> 6, lane = tid & 63;
    const int quad = lane >> 4, l16 = lane & 15;
    const int wm = wave >> 2, wn = wave & 3;

    // XCD-chunked block swizzle (512 % 8 == 0 -> bijective)
    const int bid = blockIdx.x;
    const int swz = (bid & 7) * 64 + (bid >> 3);
    const int by = swz >> 4, bx = swz & 15;
    const int m0 = by * 128;
    const int c0 = bx * 192;  // column base within [3072]
    const unsigned short* Bz = Wt;  // Wt viewed as one [3072][1024]

    // ---- staging descriptors (source chunk pre-swizzled) ----
    const unsigned short* aptr;
    {
        const int s = tid, r = s >> 2;
        const int cg = (s & 3) ^ ((r + (r >> 2)) & 3);
        aptr = A + (size_t)(m0 + r) * D_MODEL + cg * 8;
    }
    const unsigned short* bptr[2];
#pragma unroll
    for (int j = 0; j < 2; ++j) {
        const int s = j * 512 + tid;
        const int r = s >> 2;
        const int cg = (s & 3) ^ ((r + (r >> 2)) & 3);
        const int rb = (r < 192) ? r : 191;  // j=1 used only by tid<256
        bptr[j] = Bz + (size_t)(c0 + rb) * D_MODEL + cg * 8;
    }
    const int ldsA0 = wave * 512;                 // ushort units
    const int ldsB0 = wave * 512, ldsB1 = 4096 + wave * 512;

    // ---- fragment read offsets (swizzled; key matches staging) ----
    const int key = (l16 + (l16 >> 2)) & 3;
    const int chunk = quad ^ key;
    int aoff[4], boff[3];
#pragma unroll
    for (int mt = 0; mt < 4; ++mt)
        aoff[mt] = ((wm * 64 + mt * 16 + l16) * 4 + chunk) * 8;
#pragma unroll
    for (int nt = 0; nt < 3; ++nt)
        boff[nt] = ((wn * 48 + nt * 16 + l16) * 4 + chunk) * 8;

    f32x4 acc[4][3];
#pragma unroll
    for (int mt = 0; mt < 4; ++mt)
#pragma unroll
        for (int nt = 0; nt < 3; ++nt)
            acc[mt][nt] = (f32x4){0.f, 0.f, 0.f, 0.f};

    auto stageA = [&](int d, int ks, int T) {
        const int base = d * 20480 + ks * 4096;
        async16(SM + base + ldsA0, aptr + T * 64 + ks * 32);
    };
    auto stageB = [&](int d, int ks, int T) {
        const int base = d * 20480 + 8192 + ks * 6144;
        async16(SM + base + ldsB0, bptr[0] + T * 64 + ks * 32);
        if (wave < 4)
            async16(SM + base + ldsB1, bptr[1] + T * 64 + ks * 32);
    };
    auto dsA = [&](bf16x8* af, int mh, int d, int ks) {
        const int base = d * 20480 + ks * 4096;
#pragma unroll
        for (int i = 0; i < 2; ++i)
            af[i] = *(const bf16x8*)&SM[base + aoff[mh * 2 + i]];
    };
    auto dsB = [&](bf16x8* bf, int d, int ks) {
        const int base = d * 20480 + 8192 + ks * 6144;
#pragma unroll
        for (int i = 0; i < 3; ++i)
            bf[i] = *(const bf16x8*)&SM[base + boff[i]];
    };
    auto mfma6 = [&](bf16x8* af, bf16x8* bf, int mh) {
        __builtin_amdgcn_s_setprio(1);
#pragma unroll
        for (int i = 0; i < 2; ++i)
#pragma unroll
            for (int nt = 0; nt < 3; ++nt)
                acc[mh * 2 + i][nt] = __builtin_amdgcn_mfma_f32_16x16x32_bf16(
                    af[i], bf[nt], acc[mh * 2 + i][nt], 0, 0, 0);
        __builtin_amdgcn_s_setprio(0);
    };
    auto waitc = [&](bool nx) {
        if (nx) {
            if (wave < 4) asm volatile("s_waitcnt vmcnt(3)" ::: "memory");
            else          asm volatile("s_waitcnt vmcnt(2)" ::: "memory");
        } else {
            asm volatile("s_waitcnt vmcnt(0)" ::: "memory");
        }
    };

    // ---- prologue: stage tile 0 (A0,B0,A1,B1), retire A0+B0, sync ----
    stageA(0, 0, 0);
    stageB(0, 0, 0);
    stageA(0, 1, 0);
    stageB(0, 1, 0);
    waitc(true);
    BAR();

    const int NT = D_MODEL / 64;  // 16
    for (int T = 0; T < NT; ++T) {
        const int d = T & 1, dn = d ^ 1;
        const bool nx = (T + 1 < NT);
        bf16x8 af[2], bf[3];
        // ph1: reads (mh0,ks0); stage A-half0(T+1); BAR; MFMA; BAR
        dsA(af, 0, d, 0);
        dsB(bf, d, 0);
        if (nx) stageA(dn, 0, T + 1);
        __builtin_amdgcn_sched_barrier(0);
        BAR();
        mfma6(af, bf, 0);
        BAR();
        // ph2: reads (mh1,ks0) reuse bf; stage B-half0(T+1); gate A1,B1(T)
        dsA(af, 1, d, 0);
        if (nx) stageB(dn, 0, T + 1);
        waitc(nx);
        __builtin_amdgcn_sched_barrier(0);
        BAR();
        mfma6(af, bf, 1);
        BAR();
        // ph3: reads (mh0,ks1); stage A-half1(T+1); BAR; MFMA; BAR
        dsA(af, 0, d, 1);
        dsB(bf, d, 1);
        if (nx) stageA(dn, 1, T + 1);
        __builtin_amdgcn_sched_barrier(0);
        BAR();
        mfma6(af, bf, 0);
        BAR();
        // ph4: reads (mh1,ks1); stage B-half1(T+1); gate A0,B0(T+1)
        dsA(af, 1, d, 1);
        if (nx) stageB(dn, 1, T + 1);
        waitc(nx);
        __builtin_amdgcn_sched_barrier(0);
        BAR();
        mfma6(af, bf, 1);
        BAR();
    }

    // ---- epilogue: 3 x 64-col groups; QK path or V^T path per group ----
    __syncthreads();
    const int bb = m0 >> 11, tok0 = m0 & (SEQ - 1);
#pragma unroll 1
    for (int G = 0; G < 3; ++G) {
        if (G) __syncthreads();
        const int gcol = c0 + G * 64;
        const int zg = gcol >> 10;
        const int hg = (gcol >> 6) & 15;
        if (zg < 2) {
            const float sc = (zg == 0) ? 0.18033688011112042f : 1.0f;  // 0.125*log2(e)
            unsigned short* dst = (zg == 0) ? q : k;
            // stage [128 tok][64 d]
#pragma unroll
            for (int nt = 0; nt < 3; ++nt) {
                const int colb = wn * 48 + nt * 16;
                if ((colb >> 6) == G) {
                    const int cl = colb - G * 64 + l16;
#pragma unroll
                    for (int mt = 0; mt < 4; ++mt)
#pragma unroll
                        for (int reg = 0; reg < 4; ++reg) {
                            const int rr = wm * 64 + mt * 16 + quad * 4 + reg;
                            SM[rr * 64 + cl] = f2bf(acc[mt][nt][reg] * sc);
                        }
                }
            }
            __syncthreads();
#pragma unroll
            for (int it = 0; it < 2; ++it) {
                const int g = it * 512 + tid;
                const int r = g >> 3, c8 = g & 7;
                uint4 val = *(const uint4*)&SM[r * 64 + c8 * 8];
                *(uint4*)(dst + (((size_t)bb * NHEAD + hg) * SEQ + tok0 + r) * HD +
                          c8 * 8) = val;
            }
        } else {
            // V^T: stage [64 d][128 tok + pad 8]
#pragma unroll
            for (int nt = 0; nt < 3; ++nt) {
                const int colb = wn * 48 + nt * 16;
                if ((colb >> 6) == G) {
                    const int dl = colb - G * 64 + l16;
#pragma unroll
                    for (int mt = 0; mt < 4; ++mt) {
                        const int m = wm * 64 + mt * 16 + quad * 4;
                        uint2 w;
                        w.x = pk2bf(acc[mt][nt][0], acc[mt][nt][1]);
                        w.y = pk2bf(acc[mt][nt][2], acc[mt][nt][3]);
                        *(uint2*)&SM[dl * 136 + m] = w;
                    }
                }
            }
            __syncthreads();
#pragma unroll
            for (int it = 0; it < 2; ++it) {
                const int g = it * 512 + tid;
                const int dd = g >> 4, t8 = (g & 15) * 8;
                uint4 val = *(const uint4*)&SM[dd * 136 + t8];
                *(uint4*)(vt + (((size_t)bb * NHEAD + hg) * HD + dd) * SEQ + tok0 +
                          t8) = val;
            }
        }
    }
}

// ---------------------------------------------------------------------------
// bf16 MFMA GEMM (output projection only): 64x128 tile, BK=64, 4 waves.
// Grid (8,64) = 512 blocks = 2 blocks/CU (round-8 verified win).
// ---------------------------------------------------------------------------
__global__ __launch_bounds__(256) void gemm_out(const unsigned short* __restrict__ A,
                                                const unsigned short* __restrict__ Bw,
                                                float* __restrict__ outf) {
    __shared__ unsigned short SM[12288];  // As = [0,4096), Bs = [4096,12288)
    const int tid = threadIdx.x;
    const int m0 = blockIdx.y * 64, n0 = blockIdx.x * 128;
    const int wave = tid >> 6, lane = tid & 63;
    const int quad = lane >> 4, l16 = lane & 15;
    const int wm = wave & 1, wn = wave >> 1;  // wave tile: 32 rows x 64 cols

    f32x4 acc[2][4];
#pragma unroll
    for (int mt = 0; mt < 2; ++mt)
#pragma unroll
        for (int nt = 0; nt < 4; ++nt)
            acc[mt][nt] = (f32x4){0.f, 0.f, 0.f, 0.f};

    for (int k0 = 0; k0 < D_MODEL; k0 += 64) {
        __syncthreads();
        // A: 64 rows -> 512 chunks (2/thread); B: 128 rows -> 1024 (4/thread)
#pragma unroll
        for (int i = 0; i < 2; ++i) {
            const int c = i * 256 + tid;
            const int r = c >> 3, cc = (c & 7) * 8;
            const int cbase = i * 256 + wave * 64;  // wave-uniform chunk base
            async16(SM + cbase * 8, A + (size_t)(m0 + r) * D_MODEL + k0 + cc);
        }
#pragma unroll
        for (int i = 0; i < 4; ++i) {
            const int c = i * 256 + tid;
            const int r = c >> 3, cc = (c & 7) * 8;
            const int cbase = i * 256 + wave * 64;
            async16(SM + 4096 + cbase * 8, Bw + (size_t)(n0 + r) * D_MODEL + k0 + cc);
        }
        __syncthreads();
#pragma unroll
        for (int ks = 0; ks < 2; ++ks) {
            bf16x8 af[2], bfr[4];
#pragma unroll
            for (int mt = 0; mt < 2; ++mt)
                af[mt] = *(const bf16x8*)&SM[(wm * 32 + mt * 16 + l16) * 64 + ks * 32 + quad * 8];
#pragma unroll
            for (int nt = 0; nt < 4; ++nt)
                bfr[nt] = *(const bf16x8*)&SM[4096 + (wn * 64 + nt * 16 + l16) * 64 + ks * 32 + quad * 8];
#pragma unroll
            for (int mt = 0; mt < 2; ++mt)
#pragma unroll
                for (int nt = 0; nt < 4; ++nt)
                    acc[mt][nt] = __builtin_amdgcn_mfma_f32_16x16x32_bf16(
                        af[mt], bfr[nt], acc[mt][nt], 0, 0, 0);
        }
    }

#pragma unroll
    for (int mt = 0; mt < 2; ++mt)
#pragma unroll
        for (int nt = 0; nt < 4; ++nt)
#pragma unroll
            for (int reg = 0; reg < 4; ++reg) {
                const int m = m0 + wm * 32 + mt * 16 + quad * 4 + reg;
                const int n = n0 + wn * 64 + nt * 16 + l16;
                outf[(size_t)m * D_MODEL + n] = acc[mt][nt][reg];
            }
}

// ---------------------------------------------------------------------------
// MFMA flash attention (causal), Q-SPLIT (round-10 verified structure) +
// COMPLEMENTARY p-MAPPING for per-CU balance.
// Each of 4 waves owns 16 q-rows; K/V block-shared via global_load_lds
// double buffers (XOR-swizzled); one barrier+vmcnt(0) per kt.
// Grid (16,32,2) = 1024 blocks = 4 blocks/CU. Round-10's p=31-y mapping
// made per-CU totals 96-4*y0 iteration-units (round-robin puts ids i and
// i+256 = y and y+16 on the same CU) -> huge tail. New mapping:
//   y<16: p = 31-y ; y>=16: p = y-16
// pairs y with y+16 complementarily: (32-y0)+(y0+1) = 33 iters -> EVERY
// CU gets exactly 66 units regardless of round-robin phase. Bijective
// over p in [0,32) per (b,h).
// ---------------------------------------------------------------------------
__global__ __launch_bounds__(256, 4) void attn_mfma(const unsigned short* __restrict__ Q,
                                                    const unsigned short* __restrict__ K,
                                                    const unsigned short* __restrict__ VT,
                                                    unsigned short* __restrict__ ctx) {
    // LDS (ushorts): K dbuf [0,4096)+[4096,8192); V dbuf [8192,12288)+
    // [12288,16384); P [16384,20480) = 4 waves x 1024 (16 q x 64 k).
    __shared__ unsigned short SM[20480];  // 40 KB
    const int tid = threadIdx.x;
    const int wave = tid >> 6, lane = tid & 63;
    const int quad = lane >> 4, l16 = lane & 15;
    const int h = blockIdx.x, b = blockIdx.z;
    const int y = blockIdx.y;
    const int p = (y < 16) ? (31 - y) : (y - 16);  // complementary pairs
    const int row0 = p * 64;
    const int qrow = row0 + wave * 16 + l16;  // this lane's q-row
    const unsigned short* Qp = Q + ((size_t)b * NHEAD + h) * SEQ * HD;
    const unsigned short* Kp = K + ((size_t)b * NHEAD + h) * SEQ * HD;
    const unsigned short* Vp = VT + ((size_t)b * NHEAD + h) * HD * SEQ;
    unsigned short* Pw = SM + 16384 + wave * 1024;
    const int sw8 = l16 & 7;  // swizzle key (row & 7)

    // ---- staging descriptors: chunk c = j*256+tid covers LDS row r=c>>3,
    //      slot s=c&7; source holds global slot s^(r&7) (pre-swizzle) ----
    const unsigned short* kptr[2];
    const unsigned short* vptr[2];
    int ldsoff[2];
#pragma unroll
    for (int j = 0; j < 2; ++j) {
        const int c = j * 256 + tid;
        const int r = c >> 3, s = c & 7;
        const int sg = (s ^ (r & 7)) * 8;
        kptr[j] = Kp + (size_t)r * HD + sg;   // + kt*64*HD per tile
        vptr[j] = Vp + (size_t)r * SEQ + sg;  // + kt*64 per tile
        ldsoff[j] = (j * 256 + wave * 64) * 8;  // wave-uniform chunk base
    }
    auto stageKV = [&](int d, int kt) {
        const int kb = d * 4096, vb = 8192 + d * 4096;
#pragma unroll
        for (int j = 0; j < 2; ++j) {
            async16(SM + kb + ldsoff[j], kptr[j] + (size_t)kt * 64 * HD);
            async16(SM + vb + ldsoff[j], vptr[j] + kt * 64);
        }
    };

    // ---- Q fragment (one 16-row block per wave) ----
    bf16x8 bQ[2];
#pragma unroll
    for (int ks = 0; ks < 2; ++ks)
        bQ[ks] = *(const bf16x8*)(Qp + (size_t)qrow * HD + ks * 32 + quad * 8);

    f32x4 o[4];  // O^T accumulators: [d-tile]; lane value (d=nt*16+quad*4+reg, q=l16)
    float ps = 0.f;
#pragma unroll
    for (int nt = 0; nt < 4; ++nt)
        o[nt] = (f32x4){0.f, 0.f, 0.f, 0.f};

    // ---- prologue: stage tile 0 (vmcnt also covers the bQ loads) ----
    stageKV(0, 0);
    asm volatile("s_waitcnt vmcnt(0)" ::: "memory");
    BAR();

    for (int kt = 0; kt <= p; ++kt) {
        const int cur = kt & 1;
        const int kbase = cur * 4096, vbase = 8192 + cur * 4096;

        // ---- aK from shared K tile (swizzled ds_read_b128, 2-way free) ----
        bf16x8 aK[4][2];
#pragma unroll
        for (int mt = 0; mt < 4; ++mt)
#pragma unroll
            for (int ks = 0; ks < 2; ++ks)
                aK[mt][ks] = *(const bf16x8*)&SM[kbase + (mt * 16 + l16) * 64 +
                                                 (((ks * 4 + quad)) ^ sw8) * 8];

        // ---- issue next tile's staging early (lands under softmax+PV) ----
        if (kt < p) stageKV(cur ^ 1, kt + 1);

        // ---- S^T = K Q^T (m = k-row, n = q-row) ----
        f32x4 sT[4];
        __builtin_amdgcn_s_setprio(1);
#pragma unroll
        for (int mt = 0; mt < 4; ++mt) {
            sT[mt] = __builtin_amdgcn_mfma_f32_16x16x32_bf16(
                aK[mt][0], bQ[0], (f32x4){0.f, 0.f, 0.f, 0.f}, 0, 0, 0);
            sT[mt] = __builtin_amdgcn_mfma_f32_16x16x32_bf16(
                aK[mt][1], bQ[1], sT[mt], 0, 0, 0);
        }
        __builtin_amdgcn_s_setprio(0);

        // ---- exp2 + causal mask (diag tile only) + swizzled P write ----
        const bool diag = (kt == p);
#pragma unroll
        for (int mt = 0; mt < 4; ++mt) {
            float pv[4];
#pragma unroll
            for (int reg = 0; reg < 4; ++reg)
                pv[reg] = __builtin_amdgcn_exp2f(sT[mt][reg]);
            if (diag) {
                const int kb = kt * 64 + mt * 16 + quad * 4;
#pragma unroll
                for (int reg = 0; reg < 4; ++reg)
                    pv[reg] = (kb + reg > qrow) ? 0.f : pv[reg];
            }
            ps += (pv[0] + pv[1]) + (pv[2] + pv[3]);
            uint2 w;
            w.x = pk2bf(pv[0], pv[1]);
            w.y = pk2bf(pv[2], pv[3]);
            const int gph = ((mt * 2 + (quad >> 1)) ^ sw8);
            *(uint2*)&Pw[l16 * 64 + gph * 8 + (quad & 1) * 4] = w;
        }

        // ---- P back in B-layout (wave-private; same-wave DS order) ----
        bf16x8 bP[2];
#pragma unroll
        for (int ks = 0; ks < 2; ++ks)
            bP[ks] = *(const bf16x8*)&Pw[l16 * 64 + ((ks * 4 + quad) ^ sw8) * 8];

        // ---- aV from shared V tile + O^T += V^T P^T ----
        bf16x8 aV[4][2];
#pragma unroll
        for (int nt = 0; nt < 4; ++nt)
#pragma unroll
            for (int ks = 0; ks < 2; ++ks)
                aV[nt][ks] = *(const bf16x8*)&SM[vbase + (nt * 16 + l16) * 64 +
                                                 (((ks * 4 + quad)) ^ sw8) * 8];
        __builtin_amdgcn_s_setprio(1);
#pragma unroll
        for (int nt = 0; nt < 4; ++nt) {
            o[nt] = __builtin_amdgcn_mfma_f32_16x16x32_bf16(
                aV[nt][0], bP[0], o[nt], 0, 0, 0);
            o[nt] = __builtin_amdgcn_mfma_f32_16x16x32_bf16(
                aV[nt][1], bP[1], o[nt], 0, 0, 0);
        }
        __builtin_amdgcn_s_setprio(0);

        // ---- next tile staged + all waves done with cur ----
        asm volatile("s_waitcnt vmcnt(0)" ::: "memory");
        BAR();
    }

    // ---- row-sum reduce across quads (q lives in l16; partials in quads) --
    ps += __shfl_xor(ps, 16);
    ps += __shfl_xor(ps, 32);
    const float inv = 1.f / ps;

    // ---- direct store (no cross-wave combine: each wave owns its rows) ----
#pragma unroll
    for (int nt = 0; nt < 4; ++nt) {
        const int col = h * HD + nt * 16 + quad * 4;
        uint2 w;
        w.x = pk2bf(o[nt][0] * inv, o[nt][1] * inv);
        w.y = pk2bf(o[nt][2] * inv, o[nt][3] * inv);
        *(uint2*)(ctx + ((size_t)b * SEQ + qrow) * D_MODEL + col) = w;
    }
}

extern "C" void kernel_launch(void* const* d_in, const int* in_sizes, int n_in,
                              void* d_out, int out_size, void* d_ws, size_t ws_size,
                              hipStream_t stream) {
    const float* x  = (const float*)d_in[0];
    const float* Wq = (const float*)d_in[1];
    const float* Wk = (const float*)d_in[2];
    const float* Wv = (const float*)d_in[3];
    const float* Wo = (const float*)d_in[4];
    float* out = (float*)d_out;

    unsigned short* ws = (unsigned short*)d_ws;
    const size_t T = (size_t)MTOT * D_MODEL;  // 4,194,304 elements
    unsigned short* xb  = ws;                 // [4096,1024] bf16
    unsigned short* Wt  = ws + T;             // 4 x [1024,1024] bf16 (W^T)
    unsigned short* q   = ws + 2 * T;         // [B,H,N,64]  (pre-scaled)
    unsigned short* k   = ws + 3 * T;         // [B,H,N,64]
    unsigned short* vt  = ws + 4 * T;         // [B,H,64,N]
    unsigned short* ctx = ws + 5 * T;         // [4096,1024]

    prep<<<dim3(8192), dim3(256), 0, stream>>>(x, xb, Wq, Wk, Wv, Wo, Wt);

    qkv_mfma<<<dim3(512), dim3(512), 0, stream>>>(xb, Wt, q, k, vt);

    attn_mfma<<<dim3(NHEAD, 32, BATCH), dim3(256), 0, stream>>>(q, k, vt, ctx);

    gemm_out<<<dim3(8, 64), dim3(256), 0, stream>>>(ctx, Wt + 3 * (size_t)D_MODEL * D_MODEL, out);
}